// Round 10
// baseline (279.869 us; speedup 1.0000x reference)
//
#include <hip/hip_runtime.h>
#include <math.h>

// Problem constants (MAB_50921132261692)
#define Bx  4
#define NQx 2048
#define NKx 2048
#define Dx  512
#define Hx  8

typedef __attribute__((ext_vector_type(8))) __bf16 bf16x8;
typedef __attribute__((ext_vector_type(4))) float f32x4;
typedef __attribute__((ext_vector_type(16))) float f32x16;

typedef const __attribute__((address_space(1))) unsigned int* gas_ptr;
typedef __attribute__((address_space(3))) unsigned int* lds_ptr;

__device__ __forceinline__ void gload16(const void* g, void* l){
  __builtin_amdgcn_global_load_lds((gas_ptr)g, (lds_ptr)l, 16, 0, 0);
}

__device__ __forceinline__ unsigned short f2bf(float f){
  union { float f; unsigned int u; } v; v.f = f;
  unsigned int r = (v.u + 0x7FFFu + ((v.u >> 16) & 1u)) >> 16;
  return (unsigned short)r;
}
__device__ __forceinline__ float bf2f(unsigned short u){
  union { unsigned int u; float f; } v; v.u = ((unsigned int)u) << 16; return v.f;
}
__device__ __forceinline__ unsigned int cvtpk_bf16(float a, float b){
  unsigned int d;
  asm("v_cvt_pk_bf16_f32 %0, %1, %2" : "=v"(d) : "v"(a), "v"(b));
  return d;
}
__device__ __forceinline__ void plane32_swap(unsigned int& a, unsigned int& b){
  asm("v_permlane32_swap_b32 %0, %1" : "+v"(a), "+v"(b));
}
__device__ __forceinline__ float fexp2(float x){           // D = 2^x
  float d; asm("v_exp_f32 %0, %1" : "=v"(d) : "v"(x)); return d;
}
__device__ __forceinline__ float fmax3(float a, float b, float c){
  float d; asm("v_max3_f32 %0, %1, %2, %3" : "=v"(d) : "v"(a), "v"(b), "v"(c)); return d;
}

// ---------------------------------------------------------------------------
// Transpose + convert 5 weights [512][512] f32 -> Wt bf16 [z][N=512][K=512].
// ---------------------------------------------------------------------------
__global__ __launch_bounds__(256) void mab_wt(
    const float* __restrict__ Wq, const float* __restrict__ Wk, const float* __restrict__ Wv,
    const float* __restrict__ W0, const float* __restrict__ W1,
    unsigned short* __restrict__ Wt)
{
  __shared__ unsigned short T[64][72];
  const int z = blockIdx.z;
  const float* W = (z==0)?Wq:(z==1)?Wk:(z==2)?Wv:(z==3)?W0:W1;
  unsigned short* O = Wt + (size_t)z*512*512;
  const int k0 = blockIdx.x*64, n0 = blockIdx.y*64;
  const int tid = threadIdx.x;
  #pragma unroll
  for (int i=0;i<4;++i){
    int id = tid + i*256;          // 1024 = 64 rows x 16 float4
    int r = id>>4, c4 = id&15;
    float4 v = *(const float4*)(W + (size_t)(k0+r)*512 + n0 + c4*4);
    ushort4 o; o.x=f2bf(v.x); o.y=f2bf(v.y); o.z=f2bf(v.z); o.w=f2bf(v.w);
    *(ushort4*)&T[r][c4*4] = o;
  }
  __syncthreads();
  #pragma unroll
  for (int i=0;i<2;++i){
    int id = tid + i*256;          // 512 = 64 out-rows x 8 chunks
    int c = id>>3, r8 = id&7;
    union { unsigned short u[8]; uint4 v; } o;
    #pragma unroll
    for (int j=0;j<8;++j) o.u[j] = T[r8*8+j][c];
    *(uint4*)(O + (size_t)(n0+c)*512 + k0 + r8*8) = o.v;
  }
}

// ---------------------------------------------------------------------------
// Transpose Vp bf16 [B*NK][512] -> Vpt [B][512][NK] (d-major per batch).
// ---------------------------------------------------------------------------
__global__ __launch_bounds__(256) void mab_vt(
    const unsigned short* __restrict__ Vp, unsigned short* __restrict__ Vpt)
{
  __shared__ unsigned short T[64][72];
  const int r0 = blockIdx.x*64;   // k within batch
  const int c0 = blockIdx.y*64;   // d
  const int b  = blockIdx.z;
  const int tid = threadIdx.x;
  #pragma unroll
  for (int i=0;i<2;++i){
    int id = tid + i*256;          // 512 = 64 rows x 8 chunks(8 bf16)
    int r = id>>3, c8 = id&7;
    *(uint4*)&T[r][c8*8] = *(const uint4*)(Vp + (size_t)(b*NKx + r0+r)*512 + c0 + c8*8);
  }
  __syncthreads();
  #pragma unroll
  for (int i=0;i<2;++i){
    int id = tid + i*256;
    int c = id>>3, r8 = id&7;
    union { unsigned short u[8]; uint4 v; } o;
    #pragma unroll
    for (int j=0;j<8;++j) o.u[j] = T[r8*8+j][c];
    *(uint4*)(Vpt + ((size_t)(b*512) + c0 + c)*NKx + r0 + r8*8) = o.v;
  }
}

// ---------------------------------------------------------------------------
// QKV projection GEMM with fused f32->bf16 A conversion.
// ---------------------------------------------------------------------------
__global__ __launch_bounds__(256) void mab_gemm_proj(
    const float* __restrict__ Qf, const float* __restrict__ Kf,
    const unsigned short* __restrict__ Wt,
    const float* __restrict__ bq, const float* __restrict__ bk, const float* __restrict__ bv,
    unsigned short* __restrict__ Cb, float kscale)
{
  __shared__ unsigned short As[128][64];
  __shared__ unsigned short Bs[128][64];
  const int z = blockIdx.z;
  const float* A = (z==0) ? Qf : Kf;
  const unsigned short* W = Wt + (size_t)z*512*512;
  const float* bias = (z==0)?bq:((z==1)?bk:bv);
  const float sc = (z==1) ? kscale : 1.0f;
  const int m0 = blockIdx.y*128, n0 = blockIdx.x*128;
  const int tid = threadIdx.x, w = tid>>6, lane = tid&63, g = lane>>4, q16 = lane&15;
  const int wr = w>>1, wc = w&1;

  f32x4 acc[4][4];
  #pragma unroll
  for (int m=0;m<4;++m)
    #pragma unroll
    for (int n=0;n<4;++n) acc[m][n] = (f32x4){0.f,0.f,0.f,0.f};

  float4 areg[8];
  #pragma unroll
  for (int i=0;i<8;++i){
    int id = i*256 + tid, row = id>>4, qc = id&15;
    areg[i] = *(const float4*)(A + (size_t)(m0+row)*512 + qc*4);
  }

  for (int k0 = 0; k0 < 512; k0 += 64){
    __syncthreads();
    #pragma unroll
    for (int i=0;i<8;++i){
      int id = i*256 + tid, row = id>>4, qc = id&15;
      unsigned int lo = cvtpk_bf16(areg[i].x, areg[i].y);
      unsigned int hi = cvtpk_bf16(areg[i].z, areg[i].w);
      unsigned int* dst = (unsigned int*)((char*)&As[0][0] + row*128
                          + ((qc>>1) ^ (row&7))*16 + (qc&1)*8);
      dst[0] = lo; dst[1] = hi;
    }
    #pragma unroll
    for (int i=0;i<4;++i){
      int o   = (w*4 + i)*1024 + lane*16;
      int row = o >> 7;
      int c   = (o >> 4) & 7;
      int cs  = c ^ (row & 7);
      gload16(W + (size_t)(n0+row)*512 + k0 + cs*8, (char*)&Bs[0][0] + (w*4+i)*1024);
    }
    __syncthreads();
    if (k0 + 64 < 512){
      #pragma unroll
      for (int i=0;i<8;++i){
        int id = i*256 + tid, row = id>>4, qc = id&15;
        areg[i] = *(const float4*)(A + (size_t)(m0+row)*512 + (k0+64) + qc*4);
      }
    }
    #pragma unroll
    for (int ks=0;ks<2;++ks){
      bf16x8 af[4], bfr[4];
      #pragma unroll
      for (int m=0;m<4;++m){
        int row = wr*64 + m*16 + q16;
        int c   = (ks*4 + g) ^ (row & 7);
        af[m] = *(const bf16x8*)((const char*)&As[0][0] + row*128 + c*16);
      }
      #pragma unroll
      for (int n=0;n<4;++n){
        int row = wc*64 + n*16 + q16;
        int c   = (ks*4 + g) ^ (row & 7);
        bfr[n] = *(const bf16x8*)((const char*)&Bs[0][0] + row*128 + c*16);
      }
      #pragma unroll
      for (int m=0;m<4;++m)
        #pragma unroll
        for (int n=0;n<4;++n)
          acc[m][n] = __builtin_amdgcn_mfma_f32_16x16x32_bf16(af[m], bfr[n], acc[m][n], 0,0,0);
    }
  }

  const size_t ZS = (size_t)8192*512;
  #pragma unroll
  for (int m=0;m<4;++m){
    const int rowl = wr*64 + m*16 + g*4;
    #pragma unroll
    for (int n=0;n<4;++n){
      const int col = n0 + wc*64 + n*16 + q16;
      const float bv2 = bias[col];
      #pragma unroll
      for (int r=0;r<4;++r){
        float v = (acc[m][n][r] + bv2) * sc;
        Cb[(size_t)z*ZS + (size_t)(m0 + rowl + r)*512 + col] = f2bf(v);
      }
    }
  }
}

// ---------------------------------------------------------------------------
// bf16-A MFMA GEMM for the MLP: C = op(A @ W^T + bias) (+res)
// ---------------------------------------------------------------------------
__global__ __launch_bounds__(256) void mab_gemm_mfma(
    const unsigned short* __restrict__ A, const unsigned short* __restrict__ W,
    const float* __restrict__ bias, const float* __restrict__ res,
    unsigned short* __restrict__ Cb, float* __restrict__ Cf, int relu)
{
  __shared__ unsigned short As[128][64];
  __shared__ unsigned short Bs[128][64];
  const int m0 = blockIdx.y*128, n0 = blockIdx.x*128;
  const int tid = threadIdx.x, w = tid>>6, lane = tid&63, g = lane>>4, q16 = lane&15;
  const int wr = w>>1, wc = w&1;

  f32x4 acc[4][4];
  #pragma unroll
  for (int m=0;m<4;++m)
    #pragma unroll
    for (int n=0;n<4;++n) acc[m][n] = (f32x4){0.f,0.f,0.f,0.f};

  for (int k0 = 0; k0 < 512; k0 += 64){
    __syncthreads();
    #pragma unroll
    for (int i=0;i<4;++i){
      int o   = (w*4 + i)*1024 + lane*16;
      int row = o >> 7;
      int c   = (o >> 4) & 7;
      int cs  = c ^ (row & 7);
      gload16(A + (size_t)(m0+row)*512 + k0 + cs*8, (char*)&As[0][0] + (w*4+i)*1024);
      gload16(W + (size_t)(n0+row)*512 + k0 + cs*8, (char*)&Bs[0][0] + (w*4+i)*1024);
    }
    __syncthreads();
    #pragma unroll
    for (int ks=0;ks<2;++ks){
      bf16x8 af[4], bfr[4];
      #pragma unroll
      for (int m=0;m<4;++m){
        int row = wr*64 + m*16 + q16;
        int c   = (ks*4 + g) ^ (row & 7);
        af[m] = *(const bf16x8*)((const char*)&As[0][0] + row*128 + c*16);
      }
      #pragma unroll
      for (int n=0;n<4;++n){
        int row = wc*64 + n*16 + q16;
        int c   = (ks*4 + g) ^ (row & 7);
        bfr[n] = *(const bf16x8*)((const char*)&Bs[0][0] + row*128 + c*16);
      }
      #pragma unroll
      for (int m=0;m<4;++m)
        #pragma unroll
        for (int n=0;n<4;++n)
          acc[m][n] = __builtin_amdgcn_mfma_f32_16x16x32_bf16(af[m], bfr[n], acc[m][n], 0,0,0);
    }
  }

  #pragma unroll
  for (int m=0;m<4;++m){
    const int rowl = wr*64 + m*16 + g*4;
    #pragma unroll
    for (int n=0;n<4;++n){
      const int col = n0 + wc*64 + n*16 + q16;
      const float bv = bias[col];
      #pragma unroll
      for (int r=0;r<4;++r){
        float v = acc[m][n][r] + bv;
        if (relu) v = fmaxf(v, 0.f);
        size_t off = (size_t)(m0 + rowl + r)*512 + col;
        if (res) v += res[off];
        if (Cb) Cb[off] = f2bf(v);
        if (Cf) Cf[off] = v;
      }
    }
  }
}

// ---------------------------------------------------------------------------
// MFMA flash attention, 32x32 swapped-operand, exp2 domain, K-SPLIT x2 at
// FULL KVBLK=64 (R3 per-tile body). Grid (NQ/128, H, B)=512 blocks x 8 waves.
// Wave = (q-group 0..3) x (k-parity 0..1): q-rows qg*32..+32, k tiles
// t*128 + kg*64 (16 tiles). Per-parity K/V double-buffers (64KB LDS total)
// -> 2 blocks/CU x 8 waves = 4 waves/SIMD (2x R3 occupancy, same per-tile
// overhead ratio). Q frags + residual from global (L2-hot). End merge of
// (m,l,a,acc) across parities via aliased LDS; each parity writes one 32-d
// half of X. Kp pre-scaled by log2e/sqrt(512). Vpt d-major [B][512][NK].
// X = Qh + O/l + (akp/l)*vp   (pre-LayerNorm), f32.
// ---------------------------------------------------------------------------
__global__ __launch_bounds__(512, 4) void mab_attn4(
    const unsigned short* __restrict__ Qp, const unsigned short* __restrict__ Kp,
    const unsigned short* __restrict__ Vpt,
    const float* __restrict__ Kpos, const float* __restrict__ kp, const float* __restrict__ vp,
    float* __restrict__ X)
{
  __shared__ __align__(16) char pool[65536];
  // per parity kg at kg*32768: K dbuf 2x8192 then V dbuf 2x8192.
  // merge phase aliases pool as float[512][20] (40KB).

  const int q0 = blockIdx.x*128;
  const int h  = blockIdx.y;
  const int b  = blockIdx.z;
  const int tid = threadIdx.x, w = tid>>6, lane = tid&63;
  const int q32 = lane & 31, hi = lane >> 5;
  const int qg = w & 3;                 // q-group
  const int kg = w >> 2;                // k-parity group
  const int qrow = qg*32 + q32;

  char* Kbase = pool + kg*32768;
  char* Vbase = pool + kg*32768 + 16384;

  const unsigned short* Qg = Qp + ((size_t)(b*NQx + q0))*Dx + h*64;
  const unsigned short* Kg = Kp + ((size_t)b*NKx)*Dx + h*64;
  const unsigned short* Vg = Vpt + ((size_t)(b*512) + h*64)*NKx;
  const float* KProw = Kpos + (size_t)b*NQx*NKx + (size_t)(q0 + qrow)*NKx;

  const int sr = lane>>3;        // staging row 0..7
  const int sc = lane&7;         // staging chunk 0..7

  // ---- prologue: stage this parity's tile 0 ----
  {
    const int k0g = kg*64;
    #pragma unroll
    for (int i=0;i<2;++i){
      int r  = qg*16 + i*8 + sr;          // row 0..63 (k' for K, d for V)
      int cs = sc ^ (r & 7);
      gload16(Kg + (size_t)(k0g + r)*Dx + cs*8, Kbase + qg*2048 + i*1024);
      gload16(Vg + (size_t)r*NKx + k0g + cs*8, Vbase + qg*2048 + i*1024);
    }
  }

  // Q frags + residual source from global (L2-resident)
  const unsigned short* Qrowp = Qg + (size_t)qrow*Dx;
  bf16x8 qf[4];
  #pragma unroll
  for (int ds=0; ds<4; ++ds)
    qf[ds] = *(const bf16x8*)(Qrowp + ds*16 + hi*8);

  // qkp = (Qh . kp) * log2e for own q-row
  float qkp = 0.f;
  #pragma unroll
  for (int ds=0; ds<4; ++ds){
    union { bf16x8 v; unsigned short u[8]; } qa; qa.v = qf[ds];
    #pragma unroll
    for (int j=0;j<8;++j)
      qkp = fmaf(bf2f(qa.u[j]), kp[ds*16 + hi*8 + j], qkp);
  }
  qkp += __shfl_xor(qkp, 32);
  qkp *= 1.4426950408889634f;

  float m_i = -1e30f, l_i = 0.f, a_i = 0.f;
  f32x16 accT[2];
  #pragma unroll
  for (int db=0; db<2; ++db)
    #pragma unroll
    for (int r=0;r<16;++r) accT[db][r] = 0.f;

  __syncthreads();

  // ---- main loop: 16 tiles of 64 k (this parity) ----
  for (int t = 0; t < 16; ++t){
    const int cur = t & 1;
    const int k0g = t*128 + kg*64;

    // Kpos for this tile (32 f32/lane)
    f32x4 kq[2][4];
    #pragma unroll
    for (int n=0;n<2;++n)
      #pragma unroll
      for (int a=0;a<4;++a)
        kq[n][a] = *(const f32x4*)(KProw + k0g + n*32 + a*8 + hi*4);

    // stage next tile of this parity into the other buffer
    if (t < 15){
      const int k1 = k0g + 128;
      #pragma unroll
      for (int i=0;i<2;++i){
        int r  = qg*16 + i*8 + sr;
        int cs = sc ^ (r & 7);
        gload16(Kg + (size_t)(k1 + r)*Dx + cs*8,
                Kbase + (cur^1)*8192 + qg*2048 + i*1024);
        gload16(Vg + (size_t)r*NKx + k1 + cs*8,
                Vbase + (cur^1)*8192 + qg*2048 + i*1024);
      }
    }
    __builtin_amdgcn_sched_barrier(0);

    // S^T = K . Q^T : rows k' (reg-mapped), cols q (lane&31)
    f32x16 sT[2];
    __builtin_amdgcn_s_setprio(1);
    #pragma unroll
    for (int n=0;n<2;++n){
      f32x16 c;
      #pragma unroll
      for (int r=0;r<16;++r) c[r] = 0.f;
      #pragma unroll
      for (int ds=0; ds<4; ++ds){
        int row = n*32 + q32;
        int cc  = (ds*2 + hi) ^ (q32 & 7);
        bf16x8 kf = *(const bf16x8*)(Kbase + cur*8192 + row*128 + cc*16);
        c = __builtin_amdgcn_mfma_f32_32x32x16_bf16(kf, qf[ds], c, 0,0,0);
      }
      sT[n] = c;
    }
    __builtin_amdgcn_s_setprio(0);

    // + Kpos * qkp (log2 domain); k' = n*32 + (r&3) + 8*(r>>2) + 4*hi
    #pragma unroll
    for (int n=0;n<2;++n)
      #pragma unroll
      for (int r=0;r<16;++r)
        sT[n][r] = fmaf(kq[n][r>>2][r&3], qkp, sT[n][r]);

    // tree max via v_max3
    float m0a = fmax3(sT[0][0], sT[0][1], sT[0][2]);
    float m0b = fmax3(sT[0][3], sT[0][4], sT[0][5]);
    float m0c = fmax3(sT[0][6], sT[0][7], sT[0][8]);
    float m0d = fmax3(sT[0][9], sT[0][10], sT[0][11]);
    float m0e = fmax3(sT[0][12], sT[0][13], sT[0][14]);
    float m1a = fmax3(sT[1][0], sT[1][1], sT[1][2]);
    float m1b = fmax3(sT[1][3], sT[1][4], sT[1][5]);
    float m1c = fmax3(sT[1][6], sT[1][7], sT[1][8]);
    float m1d = fmax3(sT[1][9], sT[1][10], sT[1][11]);
    float m1e = fmax3(sT[1][12], sT[1][13], sT[1][14]);
    float rm = fmax3(fmax3(m0a, m0b, m0c), fmax3(m0d, m0e, sT[0][15]),
                     fmax3(fmax3(m1a, m1b, m1c), fmax3(m1d, m1e, sT[1][15]), m_i));
    rm = fmaxf(rm, __shfl_xor(rm, 32));

    if (!__all(rm <= m_i + 11.544f)){      // 2^11.544 = e^8 bound
      float al = fexp2(m_i - rm);
      m_i = rm;
      l_i *= al; a_i *= al;
      #pragma unroll
      for (int db=0; db<2; ++db)
        #pragma unroll
        for (int r=0;r<16;++r) accT[db][r] *= al;
    }

    float ps = 0.f, pk = 0.f;
    #pragma unroll
    for (int n=0;n<2;++n)
      #pragma unroll
      for (int r=0;r<16;++r){
        float p = fexp2(sT[n][r] - m_i);
        sT[n][r] = p;
        ps += p;
        pk = fmaf(p, kq[n][r>>2][r&3], pk);
      }
    ps += __shfl_xor(ps, 32);
    pk += __shfl_xor(pk, 32);
    l_i += ps; a_i += pk;

    // pack P to bf16 frags in-register (cvt_pk + permlane32_swap)
    union PW { unsigned int u[4]; bf16x8 v; } pa[4];
    #pragma unroll
    for (int n=0;n<2;++n){
      unsigned int w0 = cvtpk_bf16(sT[n][0],  sT[n][1]);
      unsigned int w1 = cvtpk_bf16(sT[n][2],  sT[n][3]);
      unsigned int w2 = cvtpk_bf16(sT[n][4],  sT[n][5]);
      unsigned int w3 = cvtpk_bf16(sT[n][6],  sT[n][7]);
      unsigned int w4 = cvtpk_bf16(sT[n][8],  sT[n][9]);
      unsigned int w5 = cvtpk_bf16(sT[n][10], sT[n][11]);
      unsigned int w6 = cvtpk_bf16(sT[n][12], sT[n][13]);
      unsigned int w7 = cvtpk_bf16(sT[n][14], sT[n][15]);
      plane32_swap(w0, w2);
      plane32_swap(w1, w3);
      plane32_swap(w4, w6);
      plane32_swap(w5, w7);
      pa[n*2+0].u[0]=w0; pa[n*2+0].u[1]=w1; pa[n*2+0].u[2]=w2; pa[n*2+0].u[3]=w3;
      pa[n*2+1].u[0]=w4; pa[n*2+1].u[1]=w5; pa[n*2+1].u[2]=w6; pa[n*2+1].u[3]=w7;
    }

    // O^T += V . P : rows d (reg-mapped), cols q (lane&31)
    __builtin_amdgcn_s_setprio(1);
    #pragma unroll
    for (int st=0; st<4; ++st){
      #pragma unroll
      for (int db=0; db<2; ++db){
        int row = db*32 + q32;
        int cc  = (st*2 + hi) ^ (q32 & 7);
        bf16x8 vf = *(const bf16x8*)(Vbase + cur*8192 + row*128 + cc*16);
        accT[db] = __builtin_amdgcn_mfma_f32_32x32x16_bf16(vf, pa[st].v, accT[db], 0,0,0);
      }
    }
    __builtin_amdgcn_s_setprio(0);

    __syncthreads();
  }

  // ---- merge the two k-parities; each parity writes one 32-d half ----
  float* mp = (float*)pool;
  {
    int slot = w*64 + lane;
    float* ms = mp + slot*20;
    int send = 1 - kg;                 // kg0 sends d[32:64), kg1 sends d[0:32)
    #pragma unroll
    for (int r=0;r<16;++r) ms[r] = accT[send][r];
    ms[16] = m_i; ms[17] = l_i; ms[18] = a_i;
  }
  __syncthreads();
  {
    int pslot = (w^4)*64 + lane;       // partner wave (other parity), same lane
    const float* pp = mp + pslot*20;
    float pm = pp[16], pl = pp[17], pav = pp[18];
    float mM = fmaxf(m_i, pm);
    float alS = fexp2(m_i - mM), alP = fexp2(pm - mM);
    float lM = fmaf(l_i, alS, pl*alP);
    float aM = fmaf(a_i, alS, pav*alP);
    float inv = 1.0f / lM;
    float aw  = aM * inv;
    float* Xrow = X + ((size_t)(b*NQx + q0 + qrow))*Dx + h*64;
    #pragma unroll
    for (int a2=0; a2<4; ++a2){
      int d0 = kg*32 + a2*8 + hi*4;
      f32x4 vpv = *(const f32x4*)(vp + d0);
      ushort4 qh = *(const ushort4*)(Qrowp + d0);
      float4 o;
      o.x = fmaf(fmaf(accT[kg][a2*4+0], alS, pp[a2*4+0]*alP), inv, bf2f(qh.x) + aw*vpv[0]);
      o.y = fmaf(fmaf(accT[kg][a2*4+1], alS, pp[a2*4+1]*alP), inv, bf2f(qh.y) + aw*vpv[1]);
      o.z = fmaf(fmaf(accT[kg][a2*4+2], alS, pp[a2*4+2]*alP), inv, bf2f(qh.z) + aw*vpv[2]);
      o.w = fmaf(fmaf(accT[kg][a2*4+3], alS, pp[a2*4+3]*alP), inv, bf2f(qh.w) + aw*vpv[3]);
      *(float4*)(Xrow + d0) = o;
    }
  }
}

// ---------------------------------------------------------------------------
// Row LayerNorm over 512; optional secondary bf16 output.
// ---------------------------------------------------------------------------
__global__ __launch_bounds__(256) void mab_ln2(
    const float* __restrict__ Xin, const float* __restrict__ g,
    const float* __restrict__ be, float* __restrict__ Yf, unsigned short* __restrict__ Yb)
{
  const int row = blockIdx.x;
  const int tid = threadIdx.x;
  const float* x = Xin + (size_t)row*Dx;
  float2 v = *(const float2*)(x + tid*2);
  float s  = v.x + v.y;
  float sq = fmaf(v.x,v.x, v.y*v.y);
  #pragma unroll
  for (int m=1; m<64; m<<=1){ s += __shfl_xor(s,m); sq += __shfl_xor(sq,m); }
  __shared__ float red[2][4];
  const int wid = tid>>6, lane = tid&63;
  if (lane==0){ red[0][wid]=s; red[1][wid]=sq; }
  __syncthreads();
  s  = red[0][0]+red[0][1]+red[0][2]+red[0][3];
  sq = red[1][0]+red[1][1]+red[1][2]+red[1][3];
  float mean = s*(1.0f/Dx);
  float var  = sq*(1.0f/Dx) - mean*mean;
  float rstd = rsqrtf(var + 1e-5f);
  float2 gg = *(const float2*)(g  + tid*2);
  float2 bb = *(const float2*)(be + tid*2);
  float2 o;
  o.x = (v.x-mean)*rstd*gg.x + bb.x;
  o.y = (v.y-mean)*rstd*gg.y + bb.y;
  if (Yf) *(float2*)(Yf + (size_t)row*Dx + tid*2) = o;
  if (Yb){
    ushort2 ob; ob.x = f2bf(o.x); ob.y = f2bf(o.y);
    *(ushort2*)(Yb + (size_t)row*Dx + tid*2) = ob;
  }
}

// ---------------------------------------------------------------------------
extern "C" void kernel_launch(void* const* d_in, const int* in_sizes, int n_in,
                              void* d_out, int out_size, void* d_ws, size_t ws_size,
                              hipStream_t stream)
{
  const float* Q    = (const float*)d_in[0];
  const float* K    = (const float*)d_in[1];
  const float* Kpos = (const float*)d_in[2];
  const float* Wq   = (const float*)d_in[3];
  const float* bq   = (const float*)d_in[4];
  const float* Wk   = (const float*)d_in[5];
  const float* bk   = (const float*)d_in[6];
  const float* Wv   = (const float*)d_in[7];
  const float* bv   = (const float*)d_in[8];
  const float* kp   = (const float*)d_in[9];
  const float* vp   = (const float*)d_in[10];
  const float* W0   = (const float*)d_in[11];
  const float* b0   = (const float*)d_in[12];
  const float* W1   = (const float*)d_in[13];
  const float* b1   = (const float*)d_in[14];
  const float* g0   = (const float*)d_in[15];
  const float* be0  = (const float*)d_in[16];
  const float* g1   = (const float*)d_in[17];
  const float* be1  = (const float*)d_in[18];
  float* out = (float*)d_out;
  char* wsb  = (char*)d_ws;

  const size_t MB = 1024*1024;
  unsigned short* Qp  = (unsigned short*)(wsb);          // 8 MiB bf16 [8192][512]
  unsigned short* Kp  = (unsigned short*)(wsb + 8*MB);   // pre-scaled (log2e/sqrt512)
  unsigned short* Vp  = (unsigned short*)(wsb + 16*MB);
  float*          O0  = (float*)         (wsb + 24*MB);  // 16 MiB f32
  unsigned short* Vpt = (unsigned short*)(wsb + 40*MB);  // 8 MiB
  unsigned short* O0b = (unsigned short*)(wsb + 48*MB);  // 8 MiB
  unsigned short* Wt  = (unsigned short*)(wsb + 56*MB);  // 2.5 MiB [5][512][512]
  unsigned short* T1  = Vp;                              // reuse after vt

  const float kscale = 0.044194173824159216f * 1.4426950408889634f; // log2e/sqrt(512)

  // weight transposes (Wq,Wk,Wv,W0,W1)
  mab_wt<<<dim3(8,8,5), 256, 0, stream>>>(Wq, Wk, Wv, W0, W1, Wt);
  // fused Q/K/V projections from f32 inputs (z=0,1,2)
  mab_gemm_proj<<<dim3(4,64,3), 256, 0, stream>>>(Q, K, Wt, bq, bk, bv, Qp, kscale);
  // V transpose to d-major
  mab_vt<<<dim3(32,8,4), 256, 0, stream>>>(Vp, Vpt);
  // fused attention (32x32 swapped, k-split x2 at KVBLK=64, 8 waves)
  mab_attn4<<<dim3(16,8,4), 512, 0, stream>>>(Qp, Kp, Vpt, Kpos, kp, vp, out);
  // LN0 -> O0 (f32) + O0b (bf16)
  mab_ln2<<<8192, 256, 0, stream>>>(out, g0, be0, O0, O0b);
  // T1 = relu(O0 @ W0 + b0)  (bf16 out)
  mab_gemm_mfma<<<dim3(4,64,1), 256, 0, stream>>>(
      O0b, Wt + (size_t)3*512*512, b0, nullptr, T1, nullptr, 1);
  // out = O0 + relu(T1 @ W1 + b1)  (f32 out)
  mab_gemm_mfma<<<dim3(4,64,1), 256, 0, stream>>>(
      T1, Wt + (size_t)4*512*512, b1, O0, nullptr, out, 1);
  // final LN in-place
  mab_ln2<<<8192, 256, 0, stream>>>(out, g1, be1, out, nullptr);
}

// Round 11
// 257.222 us; speedup vs baseline: 1.0880x; 1.0880x over previous
//
#include <hip/hip_runtime.h>
#include <math.h>

// Problem constants (MAB_50921132261692)
#define Bx  4
#define NQx 2048
#define NKx 2048
#define Dx  512
#define Hx  8

typedef __attribute__((ext_vector_type(8))) __bf16 bf16x8;
typedef __attribute__((ext_vector_type(4))) float f32x4;
typedef __attribute__((ext_vector_type(16))) float f32x16;

typedef const __attribute__((address_space(1))) unsigned int* gas_ptr;
typedef __attribute__((address_space(3))) unsigned int* lds_ptr;

__device__ __forceinline__ void gload16(const void* g, void* l){
  __builtin_amdgcn_global_load_lds((gas_ptr)g, (lds_ptr)l, 16, 0, 0);
}

__device__ __forceinline__ unsigned short f2bf(float f){
  union { float f; unsigned int u; } v; v.f = f;
  unsigned int r = (v.u + 0x7FFFu + ((v.u >> 16) & 1u)) >> 16;
  return (unsigned short)r;
}
__device__ __forceinline__ float bf2f(unsigned short u){
  union { unsigned int u; float f; } v; v.u = ((unsigned int)u) << 16; return v.f;
}
__device__ __forceinline__ unsigned int cvtpk_bf16(float a, float b){
  unsigned int d;
  asm("v_cvt_pk_bf16_f32 %0, %1, %2" : "=v"(d) : "v"(a), "v"(b));
  return d;
}
__device__ __forceinline__ void plane32_swap(unsigned int& a, unsigned int& b){
  asm("v_permlane32_swap_b32 %0, %1" : "+v"(a), "+v"(b));
}
__device__ __forceinline__ float fexp2(float x){           // D = 2^x
  float d; asm("v_exp_f32 %0, %1" : "=v"(d) : "v"(x)); return d;
}
__device__ __forceinline__ float fmax3(float a, float b, float c){
  float d; asm("v_max3_f32 %0, %1, %2, %3" : "=v"(d) : "v"(a), "v"(b), "v"(c)); return d;
}

// ---------------------------------------------------------------------------
// Transpose + convert 5 weights [512][512] f32 -> Wt bf16 [z][N=512][K=512].
// ---------------------------------------------------------------------------
__global__ __launch_bounds__(256) void mab_wt(
    const float* __restrict__ Wq, const float* __restrict__ Wk, const float* __restrict__ Wv,
    const float* __restrict__ W0, const float* __restrict__ W1,
    unsigned short* __restrict__ Wt)
{
  __shared__ unsigned short T[64][72];
  const int z = blockIdx.z;
  const float* W = (z==0)?Wq:(z==1)?Wk:(z==2)?Wv:(z==3)?W0:W1;
  unsigned short* O = Wt + (size_t)z*512*512;
  const int k0 = blockIdx.x*64, n0 = blockIdx.y*64;
  const int tid = threadIdx.x;
  #pragma unroll
  for (int i=0;i<4;++i){
    int id = tid + i*256;          // 1024 = 64 rows x 16 float4
    int r = id>>4, c4 = id&15;
    float4 v = *(const float4*)(W + (size_t)(k0+r)*512 + n0 + c4*4);
    ushort4 o; o.x=f2bf(v.x); o.y=f2bf(v.y); o.z=f2bf(v.z); o.w=f2bf(v.w);
    *(ushort4*)&T[r][c4*4] = o;
  }
  __syncthreads();
  #pragma unroll
  for (int i=0;i<2;++i){
    int id = tid + i*256;          // 512 = 64 out-rows x 8 chunks
    int c = id>>3, r8 = id&7;
    union { unsigned short u[8]; uint4 v; } o;
    #pragma unroll
    for (int j=0;j<8;++j) o.u[j] = T[r8*8+j][c];
    *(uint4*)(O + (size_t)(n0+c)*512 + k0 + r8*8) = o.v;
  }
}

// ---------------------------------------------------------------------------
// Transpose Vp bf16 [B*NK][512] -> Vpt [B][512][NK] (d-major per batch).
// ---------------------------------------------------------------------------
__global__ __launch_bounds__(256) void mab_vt(
    const unsigned short* __restrict__ Vp, unsigned short* __restrict__ Vpt)
{
  __shared__ unsigned short T[64][72];
  const int r0 = blockIdx.x*64;   // k within batch
  const int c0 = blockIdx.y*64;   // d
  const int b  = blockIdx.z;
  const int tid = threadIdx.x;
  #pragma unroll
  for (int i=0;i<2;++i){
    int id = tid + i*256;          // 512 = 64 rows x 8 chunks(8 bf16)
    int r = id>>3, c8 = id&7;
    *(uint4*)&T[r][c8*8] = *(const uint4*)(Vp + (size_t)(b*NKx + r0+r)*512 + c0 + c8*8);
  }
  __syncthreads();
  #pragma unroll
  for (int i=0;i<2;++i){
    int id = tid + i*256;
    int c = id>>3, r8 = id&7;
    union { unsigned short u[8]; uint4 v; } o;
    #pragma unroll
    for (int j=0;j<8;++j) o.u[j] = T[r8*8+j][c];
    *(uint4*)(Vpt + ((size_t)(b*512) + c0 + c)*NKx + r0 + r8*8) = o.v;
  }
}

// ---------------------------------------------------------------------------
// QKV projection GEMM with fused f32->bf16 A conversion.
// ---------------------------------------------------------------------------
__global__ __launch_bounds__(256) void mab_gemm_proj(
    const float* __restrict__ Qf, const float* __restrict__ Kf,
    const unsigned short* __restrict__ Wt,
    const float* __restrict__ bq, const float* __restrict__ bk, const float* __restrict__ bv,
    unsigned short* __restrict__ Cb, float kscale)
{
  __shared__ unsigned short As[128][64];
  __shared__ unsigned short Bs[128][64];
  const int z = blockIdx.z;
  const float* A = (z==0) ? Qf : Kf;
  const unsigned short* W = Wt + (size_t)z*512*512;
  const float* bias = (z==0)?bq:((z==1)?bk:bv);
  const float sc = (z==1) ? kscale : 1.0f;
  const int m0 = blockIdx.y*128, n0 = blockIdx.x*128;
  const int tid = threadIdx.x, w = tid>>6, lane = tid&63, g = lane>>4, q16 = lane&15;
  const int wr = w>>1, wc = w&1;

  f32x4 acc[4][4];
  #pragma unroll
  for (int m=0;m<4;++m)
    #pragma unroll
    for (int n=0;n<4;++n) acc[m][n] = (f32x4){0.f,0.f,0.f,0.f};

  float4 areg[8];
  #pragma unroll
  for (int i=0;i<8;++i){
    int id = i*256 + tid, row = id>>4, qc = id&15;
    areg[i] = *(const float4*)(A + (size_t)(m0+row)*512 + qc*4);
  }

  for (int k0 = 0; k0 < 512; k0 += 64){
    __syncthreads();
    #pragma unroll
    for (int i=0;i<8;++i){
      int id = i*256 + tid, row = id>>4, qc = id&15;
      unsigned int lo = cvtpk_bf16(areg[i].x, areg[i].y);
      unsigned int hi = cvtpk_bf16(areg[i].z, areg[i].w);
      unsigned int* dst = (unsigned int*)((char*)&As[0][0] + row*128
                          + ((qc>>1) ^ (row&7))*16 + (qc&1)*8);
      dst[0] = lo; dst[1] = hi;
    }
    #pragma unroll
    for (int i=0;i<4;++i){
      int o   = (w*4 + i)*1024 + lane*16;
      int row = o >> 7;
      int c   = (o >> 4) & 7;
      int cs  = c ^ (row & 7);
      gload16(W + (size_t)(n0+row)*512 + k0 + cs*8, (char*)&Bs[0][0] + (w*4+i)*1024);
    }
    __syncthreads();
    if (k0 + 64 < 512){
      #pragma unroll
      for (int i=0;i<8;++i){
        int id = i*256 + tid, row = id>>4, qc = id&15;
        areg[i] = *(const float4*)(A + (size_t)(m0+row)*512 + (k0+64) + qc*4);
      }
    }
    #pragma unroll
    for (int ks=0;ks<2;++ks){
      bf16x8 af[4], bfr[4];
      #pragma unroll
      for (int m=0;m<4;++m){
        int row = wr*64 + m*16 + q16;
        int c   = (ks*4 + g) ^ (row & 7);
        af[m] = *(const bf16x8*)((const char*)&As[0][0] + row*128 + c*16);
      }
      #pragma unroll
      for (int n=0;n<4;++n){
        int row = wc*64 + n*16 + q16;
        int c   = (ks*4 + g) ^ (row & 7);
        bfr[n] = *(const bf16x8*)((const char*)&Bs[0][0] + row*128 + c*16);
      }
      #pragma unroll
      for (int m=0;m<4;++m)
        #pragma unroll
        for (int n=0;n<4;++n)
          acc[m][n] = __builtin_amdgcn_mfma_f32_16x16x32_bf16(af[m], bfr[n], acc[m][n], 0,0,0);
    }
  }

  const size_t ZS = (size_t)8192*512;
  #pragma unroll
  for (int m=0;m<4;++m){
    const int rowl = wr*64 + m*16 + g*4;
    #pragma unroll
    for (int n=0;n<4;++n){
      const int col = n0 + wc*64 + n*16 + q16;
      const float bv2 = bias[col];
      #pragma unroll
      for (int r=0;r<4;++r){
        float v = (acc[m][n][r] + bv2) * sc;
        Cb[(size_t)z*ZS + (size_t)(m0 + rowl + r)*512 + col] = f2bf(v);
      }
    }
  }
}

// ---------------------------------------------------------------------------
// bf16-A MFMA GEMM for the MLP: C = op(A @ W^T + bias) (+res)
// ---------------------------------------------------------------------------
__global__ __launch_bounds__(256) void mab_gemm_mfma(
    const unsigned short* __restrict__ A, const unsigned short* __restrict__ W,
    const float* __restrict__ bias, const float* __restrict__ res,
    unsigned short* __restrict__ Cb, float* __restrict__ Cf, int relu)
{
  __shared__ unsigned short As[128][64];
  __shared__ unsigned short Bs[128][64];
  const int m0 = blockIdx.y*128, n0 = blockIdx.x*128;
  const int tid = threadIdx.x, w = tid>>6, lane = tid&63, g = lane>>4, q16 = lane&15;
  const int wr = w>>1, wc = w&1;

  f32x4 acc[4][4];
  #pragma unroll
  for (int m=0;m<4;++m)
    #pragma unroll
    for (int n=0;n<4;++n) acc[m][n] = (f32x4){0.f,0.f,0.f,0.f};

  for (int k0 = 0; k0 < 512; k0 += 64){
    __syncthreads();
    #pragma unroll
    for (int i=0;i<4;++i){
      int o   = (w*4 + i)*1024 + lane*16;
      int row = o >> 7;
      int c   = (o >> 4) & 7;
      int cs  = c ^ (row & 7);
      gload16(A + (size_t)(m0+row)*512 + k0 + cs*8, (char*)&As[0][0] + (w*4+i)*1024);
      gload16(W + (size_t)(n0+row)*512 + k0 + cs*8, (char*)&Bs[0][0] + (w*4+i)*1024);
    }
    __syncthreads();
    #pragma unroll
    for (int ks=0;ks<2;++ks){
      bf16x8 af[4], bfr[4];
      #pragma unroll
      for (int m=0;m<4;++m){
        int row = wr*64 + m*16 + q16;
        int c   = (ks*4 + g) ^ (row & 7);
        af[m] = *(const bf16x8*)((const char*)&As[0][0] + row*128 + c*16);
      }
      #pragma unroll
      for (int n=0;n<4;++n){
        int row = wc*64 + n*16 + q16;
        int c   = (ks*4 + g) ^ (row & 7);
        bfr[n] = *(const bf16x8*)((const char*)&Bs[0][0] + row*128 + c*16);
      }
      #pragma unroll
      for (int m=0;m<4;++m)
        #pragma unroll
        for (int n=0;n<4;++n)
          acc[m][n] = __builtin_amdgcn_mfma_f32_16x16x32_bf16(af[m], bfr[n], acc[m][n], 0,0,0);
    }
  }

  #pragma unroll
  for (int m=0;m<4;++m){
    const int rowl = wr*64 + m*16 + g*4;
    #pragma unroll
    for (int n=0;n<4;++n){
      const int col = n0 + wc*64 + n*16 + q16;
      const float bv = bias[col];
      #pragma unroll
      for (int r=0;r<4;++r){
        float v = acc[m][n][r] + bv;
        if (relu) v = fmaxf(v, 0.f);
        size_t off = (size_t)(m0 + rowl + r)*512 + col;
        if (res) v += res[off];
        if (Cb) Cb[off] = f2bf(v);
        if (Cf) Cf[off] = v;
      }
    }
  }
}

// ---------------------------------------------------------------------------
// MFMA flash attention v5: ALL-HEADS-PER-BLOCK, Kpos shared via LDS.
// Grid (B=4, NQ/32=64) = 256 blocks x 8 waves (512 thr). Wave w = head w,
// q-rows q0..q0+31 (SAME rows for all waves -> the 32x64 Kpos tile is
// staged ONCE per block into LDS (XOR-swizzled dbuf, 16KB) instead of being
// re-read per head: Kpos global traffic 536MB -> 67MB. K/V fragments load
// DIRECTLY global->registers (L2-resident; K prefetched one tile ahead,
// V issued at tile start) -- no K/V LDS, no staging barriers beyond the
// one per-tile Kpos dbuf barrier. Per-tile softmax body identical to R3.
// Occupancy grid-pinned at 2 waves/SIMD -> launch_bounds(512,2) = 256 VGPR
// budget, no spills (R10 lesson). Kp pre-scaled by log2e/sqrt(512).
// Vpt d-major [B][512][NK]. X = Qh + O/l + (akp/l)*vp (pre-LN), f32.
// ---------------------------------------------------------------------------
__global__ __launch_bounds__(512, 2) void mab_attn5(
    const unsigned short* __restrict__ Qp, const unsigned short* __restrict__ Kp,
    const unsigned short* __restrict__ Vpt,
    const float* __restrict__ Kpos, const float* __restrict__ kp, const float* __restrict__ vp,
    float* __restrict__ X)
{
  __shared__ __align__(16) float KQ[2][2048];   // [buf][32 q x 64 k], XOR-swizzled

  const int b  = blockIdx.x;
  const int q0 = blockIdx.y*32;
  const int tid = threadIdx.x, w = tid>>6, lane = tid&63;
  const int q32 = lane & 31, hi = lane >> 5;
  const int h = w;

  const unsigned short* Qg = Qp + ((size_t)(b*NQx + q0))*Dx + h*64;
  const unsigned short* Kg = Kp + ((size_t)b*NKx)*Dx + h*64;
  const unsigned short* Vg = Vpt + ((size_t)(b*512) + h*64)*NKx;
  const float* KPg = Kpos + (size_t)b*NQx*NKx + (size_t)q0*NKx;  // [32][2048]

  // Kpos staging geometry: 512 lanes cover 32 rows x 16 f32x4 chunks
  const int prow = tid>>4;             // 0..31
  const int pc4  = tid&15;             // chunk 0..15
  const int pchunk = pc4 ^ (prow & 7); // XOR swizzle (write side)

  // Q frags from global (L2-resident)
  const unsigned short* Qrowp = Qg + (size_t)q32*Dx;
  bf16x8 qf[4];
  #pragma unroll
  for (int ds=0; ds<4; ++ds)
    qf[ds] = *(const bf16x8*)(Qrowp + ds*16 + hi*8);

  // qkp = (Qh . kp) * log2e for own q-row
  float qkp = 0.f;
  #pragma unroll
  for (int ds=0; ds<4; ++ds){
    union { bf16x8 v; unsigned short u[8]; } qa; qa.v = qf[ds];
    #pragma unroll
    for (int j=0;j<8;++j)
      qkp = fmaf(bf2f(qa.u[j]), kp[ds*16 + hi*8 + j], qkp);
  }
  qkp += __shfl_xor(qkp, 32);
  qkp *= 1.4426950408889634f;

  float m_i = -1e30f, l_i = 0.f, a_i = 0.f;
  f32x16 accT[2];
  #pragma unroll
  for (int db=0; db<2; ++db)
    #pragma unroll
    for (int r=0;r<16;++r) accT[db][r] = 0.f;

  // ---- prologue: stage Kpos tile 0; load K frags tile 0 ----
  {
    float4 kv0 = *(const float4*)(KPg + (size_t)prow*NKx + pc4*4);
    *(float4*)((char*)&KQ[0][0] + prow*256 + pchunk*16) = kv0;
  }
  bf16x8 kfA[2][4], kfB[2][4];
  #pragma unroll
  for (int n=0;n<2;++n)
    #pragma unroll
    for (int ds=0; ds<4; ++ds)
      kfA[n][ds] = *(const bf16x8*)(Kg + (size_t)(n*32 + q32)*Dx + ds*16 + hi*8);
  __syncthreads();

  const int NT = NKx/64;   // 32

  auto body = [&](int t, bf16x8 (&kfC)[2][4], bf16x8 (&kfN)[2][4]){
    const int k0 = t*64;
    const int kn = (t+1 < NT) ? (k0 + 64) : k0;

    // issue next-tile K frag loads (prefetch into the other named set)
    #pragma unroll
    for (int n=0;n<2;++n)
      #pragma unroll
      for (int ds=0; ds<4; ++ds)
        kfN[n][ds] = *(const bf16x8*)(Kg + (size_t)(kn + n*32 + q32)*Dx + ds*16 + hi*8);
    // issue this-tile V frag loads (consumed at PV, latency covered by QK^T+softmax)
    bf16x8 vf[4][2];
    #pragma unroll
    for (int st=0; st<4; ++st)
      #pragma unroll
      for (int db=0; db<2; ++db)
        vf[st][db] = *(const bf16x8*)(Vg + (size_t)(db*32 + q32)*NKx + k0 + st*16 + hi*8);
    // issue next-tile Kpos load (written to LDS at end of body)
    float4 knv = *(const float4*)(KPg + (size_t)prow*NKx + kn + pc4*4);
    __builtin_amdgcn_sched_barrier(0);

    // S^T = K . Q^T (log2 domain)
    f32x16 sT[2];
    __builtin_amdgcn_s_setprio(1);
    #pragma unroll
    for (int n=0;n<2;++n){
      f32x16 c;
      #pragma unroll
      for (int r=0;r<16;++r) c[r] = 0.f;
      #pragma unroll
      for (int ds=0; ds<4; ++ds)
        c = __builtin_amdgcn_mfma_f32_32x32x16_bf16(kfC[n][ds], qf[ds], c, 0,0,0);
      sT[n] = c;
    }
    __builtin_amdgcn_s_setprio(0);

    // kq from shared Kpos LDS (swizzled read, same involution as write)
    f32x4 kq[2][4];
    #pragma unroll
    for (int n=0;n<2;++n)
      #pragma unroll
      for (int a=0;a<4;++a){
        int chunk = (n*8 + a*2 + hi) ^ (q32 & 7);
        kq[n][a] = *(const f32x4*)((const char*)&KQ[t&1][0] + q32*256 + chunk*16);
      }

    // + Kpos * qkp (log2 domain); k' = n*32 + (r&3) + 8*(r>>2) + 4*hi
    #pragma unroll
    for (int n=0;n<2;++n)
      #pragma unroll
      for (int r=0;r<16;++r)
        sT[n][r] = fmaf(kq[n][r>>2][r&3], qkp, sT[n][r]);

    // tree max via v_max3
    float m0a = fmax3(sT[0][0], sT[0][1], sT[0][2]);
    float m0b = fmax3(sT[0][3], sT[0][4], sT[0][5]);
    float m0c = fmax3(sT[0][6], sT[0][7], sT[0][8]);
    float m0d = fmax3(sT[0][9], sT[0][10], sT[0][11]);
    float m0e = fmax3(sT[0][12], sT[0][13], sT[0][14]);
    float m1a = fmax3(sT[1][0], sT[1][1], sT[1][2]);
    float m1b = fmax3(sT[1][3], sT[1][4], sT[1][5]);
    float m1c = fmax3(sT[1][6], sT[1][7], sT[1][8]);
    float m1d = fmax3(sT[1][9], sT[1][10], sT[1][11]);
    float m1e = fmax3(sT[1][12], sT[1][13], sT[1][14]);
    float rm = fmax3(fmax3(m0a, m0b, m0c), fmax3(m0d, m0e, sT[0][15]),
                     fmax3(fmax3(m1a, m1b, m1c), fmax3(m1d, m1e, sT[1][15]), m_i));
    rm = fmaxf(rm, __shfl_xor(rm, 32));

    if (!__all(rm <= m_i + 11.544f)){      // 2^11.544 = e^8 bound
      float al = fexp2(m_i - rm);
      m_i = rm;
      l_i *= al; a_i *= al;
      #pragma unroll
      for (int db=0; db<2; ++db)
        #pragma unroll
        for (int r=0;r<16;++r) accT[db][r] *= al;
    }

    float ps = 0.f, pk = 0.f;
    #pragma unroll
    for (int n=0;n<2;++n)
      #pragma unroll
      for (int r=0;r<16;++r){
        float p = fexp2(sT[n][r] - m_i);
        sT[n][r] = p;
        ps += p;
        pk = fmaf(p, kq[n][r>>2][r&3], pk);
      }
    ps += __shfl_xor(ps, 32);
    pk += __shfl_xor(pk, 32);
    l_i += ps; a_i += pk;

    // pack P to bf16 frags in-register (cvt_pk + permlane32_swap)
    union PW { unsigned int u[4]; bf16x8 v; } pa[4];
    #pragma unroll
    for (int n=0;n<2;++n){
      unsigned int w0 = cvtpk_bf16(sT[n][0],  sT[n][1]);
      unsigned int w1 = cvtpk_bf16(sT[n][2],  sT[n][3]);
      unsigned int w2 = cvtpk_bf16(sT[n][4],  sT[n][5]);
      unsigned int w3 = cvtpk_bf16(sT[n][6],  sT[n][7]);
      unsigned int w4 = cvtpk_bf16(sT[n][8],  sT[n][9]);
      unsigned int w5 = cvtpk_bf16(sT[n][10], sT[n][11]);
      unsigned int w6 = cvtpk_bf16(sT[n][12], sT[n][13]);
      unsigned int w7 = cvtpk_bf16(sT[n][14], sT[n][15]);
      plane32_swap(w0, w2);
      plane32_swap(w1, w3);
      plane32_swap(w4, w6);
      plane32_swap(w5, w7);
      pa[n*2+0].u[0]=w0; pa[n*2+0].u[1]=w1; pa[n*2+0].u[2]=w2; pa[n*2+0].u[3]=w3;
      pa[n*2+1].u[0]=w4; pa[n*2+1].u[1]=w5; pa[n*2+1].u[2]=w6; pa[n*2+1].u[3]=w7;
    }

    // O^T += V . P (V frags straight from registers)
    __builtin_amdgcn_s_setprio(1);
    #pragma unroll
    for (int st=0; st<4; ++st){
      #pragma unroll
      for (int db=0; db<2; ++db)
        accT[db] = __builtin_amdgcn_mfma_f32_32x32x16_bf16(vf[st][db], pa[st].v, accT[db], 0,0,0);
    }
    __builtin_amdgcn_s_setprio(0);

    // write next-tile Kpos into the other LDS buffer (read next iteration)
    *(float4*)((char*)&KQ[(t+1)&1][0] + prow*256 + pchunk*16) = knv;
    __syncthreads();
  };

  for (int t = 0; t < NT; t += 2){
    body(t,   kfA, kfB);
    body(t+1, kfB, kfA);
  }

  // epilogue: X = Qh + O/l + (akp/l)*vp ; d = db*32 + 8a + 4hi + c
  float inv = 1.0f / l_i;
  float aw  = a_i * inv;
  float* Xrow = X + ((size_t)(b*NQx + q0 + q32))*Dx + h*64;
  #pragma unroll
  for (int db=0; db<2; ++db){
    #pragma unroll
    for (int a2=0; a2<4; ++a2){
      int d0 = db*32 + a2*8 + hi*4;
      f32x4 vpv = *(const f32x4*)(vp + d0);
      ushort4 qh = *(const ushort4*)(Qrowp + d0);
      float4 o;
      o.x = fmaf(accT[db][a2*4+0], inv, bf2f(qh.x) + aw*vpv[0]);
      o.y = fmaf(accT[db][a2*4+1], inv, bf2f(qh.y) + aw*vpv[1]);
      o.z = fmaf(accT[db][a2*4+2], inv, bf2f(qh.z) + aw*vpv[2]);
      o.w = fmaf(accT[db][a2*4+3], inv, bf2f(qh.w) + aw*vpv[3]);
      *(float4*)(Xrow + d0) = o;
    }
  }
}

// ---------------------------------------------------------------------------
// Row LayerNorm over 512; optional secondary bf16 output.
// ---------------------------------------------------------------------------
__global__ __launch_bounds__(256) void mab_ln2(
    const float* __restrict__ Xin, const float* __restrict__ g,
    const float* __restrict__ be, float* __restrict__ Yf, unsigned short* __restrict__ Yb)
{
  const int row = blockIdx.x;
  const int tid = threadIdx.x;
  const float* x = Xin + (size_t)row*Dx;
  float2 v = *(const float2*)(x + tid*2);
  float s  = v.x + v.y;
  float sq = fmaf(v.x,v.x, v.y*v.y);
  #pragma unroll
  for (int m=1; m<64; m<<=1){ s += __shfl_xor(s,m); sq += __shfl_xor(sq,m); }
  __shared__ float red[2][4];
  const int wid = tid>>6, lane = tid&63;
  if (lane==0){ red[0][wid]=s; red[1][wid]=sq; }
  __syncthreads();
  s  = red[0][0]+red[0][1]+red[0][2]+red[0][3];
  sq = red[1][0]+red[1][1]+red[1][2]+red[1][3];
  float mean = s*(1.0f/Dx);
  float var  = sq*(1.0f/Dx) - mean*mean;
  float rstd = rsqrtf(var + 1e-5f);
  float2 gg = *(const float2*)(g  + tid*2);
  float2 bb = *(const float2*)(be + tid*2);
  float2 o;
  o.x = (v.x-mean)*rstd*gg.x + bb.x;
  o.y = (v.y-mean)*rstd*gg.y + bb.y;
  if (Yf) *(float2*)(Yf + (size_t)row*Dx + tid*2) = o;
  if (Yb){
    ushort2 ob; ob.x = f2bf(o.x); ob.y = f2bf(o.y);
    *(ushort2*)(Yb + (size_t)row*Dx + tid*2) = ob;
  }
}

// ---------------------------------------------------------------------------
extern "C" void kernel_launch(void* const* d_in, const int* in_sizes, int n_in,
                              void* d_out, int out_size, void* d_ws, size_t ws_size,
                              hipStream_t stream)
{
  const float* Q    = (const float*)d_in[0];
  const float* K    = (const float*)d_in[1];
  const float* Kpos = (const float*)d_in[2];
  const float* Wq   = (const float*)d_in[3];
  const float* bq   = (const float*)d_in[4];
  const float* Wk   = (const float*)d_in[5];
  const float* bk   = (const float*)d_in[6];
  const float* Wv   = (const float*)d_in[7];
  const float* bv   = (const float*)d_in[8];
  const float* kp   = (const float*)d_in[9];
  const float* vp   = (const float*)d_in[10];
  const float* W0   = (const float*)d_in[11];
  const float* b0   = (const float*)d_in[12];
  const float* W1   = (const float*)d_in[13];
  const float* b1   = (const float*)d_in[14];
  const float* g0   = (const float*)d_in[15];
  const float* be0  = (const float*)d_in[16];
  const float* g1   = (const float*)d_in[17];
  const float* be1  = (const float*)d_in[18];
  float* out = (float*)d_out;
  char* wsb  = (char*)d_ws;

  const size_t MB = 1024*1024;
  unsigned short* Qp  = (unsigned short*)(wsb);          // 8 MiB bf16 [8192][512]
  unsigned short* Kp  = (unsigned short*)(wsb + 8*MB);   // pre-scaled (log2e/sqrt512)
  unsigned short* Vp  = (unsigned short*)(wsb + 16*MB);
  float*          O0  = (float*)         (wsb + 24*MB);  // 16 MiB f32
  unsigned short* Vpt = (unsigned short*)(wsb + 40*MB);  // 8 MiB
  unsigned short* O0b = (unsigned short*)(wsb + 48*MB);  // 8 MiB
  unsigned short* Wt  = (unsigned short*)(wsb + 56*MB);  // 2.5 MiB [5][512][512]
  unsigned short* T1  = Vp;                              // reuse after vt

  const float kscale = 0.044194173824159216f * 1.4426950408889634f; // log2e/sqrt(512)

  // weight transposes (Wq,Wk,Wv,W0,W1)
  mab_wt<<<dim3(8,8,5), 256, 0, stream>>>(Wq, Wk, Wv, W0, W1, Wt);
  // fused Q/K/V projections from f32 inputs (z=0,1,2)
  mab_gemm_proj<<<dim3(4,64,3), 256, 0, stream>>>(Q, K, Wt, bq, bk, bv, Qp, kscale);
  // V transpose to d-major
  mab_vt<<<dim3(32,8,4), 256, 0, stream>>>(Vp, Vpt);
  // fused attention v5 (all-heads block, shared Kpos, reg-direct K/V)
  mab_attn5<<<dim3(4,64), 512, 0, stream>>>(Qp, Kp, Vpt, Kpos, kp, vp, out);
  // LN0 -> O0 (f32) + O0b (bf16)
  mab_ln2<<<8192, 256, 0, stream>>>(out, g0, be0, O0, O0b);
  // T1 = relu(O0 @ W0 + b0)  (bf16 out)
  mab_gemm_mfma<<<dim3(4,64,1), 256, 0, stream>>>(
      O0b, Wt + (size_t)3*512*512, b0, nullptr, T1, nullptr, 1);
  // out = O0 + relu(T1 @ W1 + b1)  (f32 out)
  mab_gemm_mfma<<<dim3(4,64,1), 256, 0, stream>>>(
      T1, Wt + (size_t)4*512*512, b1, O0, nullptr, out, 1);
  // final LN in-place
  mab_ln2<<<8192, 256, 0, stream>>>(out, g1, be1, out, nullptr);
}

// Round 12
// 254.026 us; speedup vs baseline: 1.1017x; 1.0126x over previous
//
#include <hip/hip_runtime.h>
#include <math.h>

// Problem constants (MAB_50921132261692)
#define Bx  4
#define NQx 2048
#define NKx 2048
#define Dx  512
#define Hx  8

typedef __attribute__((ext_vector_type(8))) __bf16 bf16x8;
typedef __attribute__((ext_vector_type(4))) float f32x4;
typedef __attribute__((ext_vector_type(16))) float f32x16;

typedef const __attribute__((address_space(1))) unsigned int* gas_ptr;
typedef __attribute__((address_space(3))) unsigned int* lds_ptr;

__device__ __forceinline__ void gload16(const void* g, void* l){
  __builtin_amdgcn_global_load_lds((gas_ptr)g, (lds_ptr)l, 16, 0, 0);
}

__device__ __forceinline__ unsigned short f2bf(float f){
  union { float f; unsigned int u; } v; v.f = f;
  unsigned int r = (v.u + 0x7FFFu + ((v.u >> 16) & 1u)) >> 16;
  return (unsigned short)r;
}
__device__ __forceinline__ float bf2f(unsigned short u){
  union { unsigned int u; float f; } v; v.u = ((unsigned int)u) << 16; return v.f;
}
__device__ __forceinline__ unsigned int cvtpk_bf16(float a, float b){
  unsigned int d;
  asm("v_cvt_pk_bf16_f32 %0, %1, %2" : "=v"(d) : "v"(a), "v"(b));
  return d;
}
__device__ __forceinline__ void plane32_swap(unsigned int& a, unsigned int& b){
  asm("v_permlane32_swap_b32 %0, %1" : "+v"(a), "+v"(b));
}
__device__ __forceinline__ float fexp2(float x){           // D = 2^x
  float d; asm("v_exp_f32 %0, %1" : "=v"(d) : "v"(x)); return d;
}
__device__ __forceinline__ float fmax3(float a, float b, float c){
  float d; asm("v_max3_f32 %0, %1, %2, %3" : "=v"(d) : "v"(a), "v"(b), "v"(c)); return d;
}

// ---------------------------------------------------------------------------
// Transpose + convert 5 weights [512][512] f32 -> Wt bf16 [z][N=512][K=512].
// ---------------------------------------------------------------------------
__global__ __launch_bounds__(256) void mab_wt(
    const float* __restrict__ Wq, const float* __restrict__ Wk, const float* __restrict__ Wv,
    const float* __restrict__ W0, const float* __restrict__ W1,
    unsigned short* __restrict__ Wt)
{
  __shared__ unsigned short T[64][72];
  const int z = blockIdx.z;
  const float* W = (z==0)?Wq:(z==1)?Wk:(z==2)?Wv:(z==3)?W0:W1;
  unsigned short* O = Wt + (size_t)z*512*512;
  const int k0 = blockIdx.x*64, n0 = blockIdx.y*64;
  const int tid = threadIdx.x;
  #pragma unroll
  for (int i=0;i<4;++i){
    int id = tid + i*256;          // 1024 = 64 rows x 16 float4
    int r = id>>4, c4 = id&15;
    float4 v = *(const float4*)(W + (size_t)(k0+r)*512 + n0 + c4*4);
    ushort4 o; o.x=f2bf(v.x); o.y=f2bf(v.y); o.z=f2bf(v.z); o.w=f2bf(v.w);
    *(ushort4*)&T[r][c4*4] = o;
  }
  __syncthreads();
  #pragma unroll
  for (int i=0;i<2;++i){
    int id = tid + i*256;          // 512 = 64 out-rows x 8 chunks
    int c = id>>3, r8 = id&7;
    union { unsigned short u[8]; uint4 v; } o;
    #pragma unroll
    for (int j=0;j<8;++j) o.u[j] = T[r8*8+j][c];
    *(uint4*)(O + (size_t)(n0+c)*512 + k0 + r8*8) = o.v;
  }
}

// ---------------------------------------------------------------------------
// Transpose Vp bf16 [B*NK][512] -> Vpt [B][512][NK] (d-major per batch).
// ---------------------------------------------------------------------------
__global__ __launch_bounds__(256) void mab_vt(
    const unsigned short* __restrict__ Vp, unsigned short* __restrict__ Vpt)
{
  __shared__ unsigned short T[64][72];
  const int r0 = blockIdx.x*64;   // k within batch
  const int c0 = blockIdx.y*64;   // d
  const int b  = blockIdx.z;
  const int tid = threadIdx.x;
  #pragma unroll
  for (int i=0;i<2;++i){
    int id = tid + i*256;          // 512 = 64 rows x 8 chunks(8 bf16)
    int r = id>>3, c8 = id&7;
    *(uint4*)&T[r][c8*8] = *(const uint4*)(Vp + (size_t)(b*NKx + r0+r)*512 + c0 + c8*8);
  }
  __syncthreads();
  #pragma unroll
  for (int i=0;i<2;++i){
    int id = tid + i*256;
    int c = id>>3, r8 = id&7;
    union { unsigned short u[8]; uint4 v; } o;
    #pragma unroll
    for (int j=0;j<8;++j) o.u[j] = T[r8*8+j][c];
    *(uint4*)(Vpt + ((size_t)(b*512) + c0 + c)*NKx + r0 + r8*8) = o.v;
  }
}

// ---------------------------------------------------------------------------
// QKV projection GEMM with fused f32->bf16 A conversion.
// ---------------------------------------------------------------------------
__global__ __launch_bounds__(256) void mab_gemm_proj(
    const float* __restrict__ Qf, const float* __restrict__ Kf,
    const unsigned short* __restrict__ Wt,
    const float* __restrict__ bq, const float* __restrict__ bk, const float* __restrict__ bv,
    unsigned short* __restrict__ Cb, float kscale)
{
  __shared__ unsigned short As[128][64];
  __shared__ unsigned short Bs[128][64];
  const int z = blockIdx.z;
  const float* A = (z==0) ? Qf : Kf;
  const unsigned short* W = Wt + (size_t)z*512*512;
  const float* bias = (z==0)?bq:((z==1)?bk:bv);
  const float sc = (z==1) ? kscale : 1.0f;
  const int m0 = blockIdx.y*128, n0 = blockIdx.x*128;
  const int tid = threadIdx.x, w = tid>>6, lane = tid&63, g = lane>>4, q16 = lane&15;
  const int wr = w>>1, wc = w&1;

  f32x4 acc[4][4];
  #pragma unroll
  for (int m=0;m<4;++m)
    #pragma unroll
    for (int n=0;n<4;++n) acc[m][n] = (f32x4){0.f,0.f,0.f,0.f};

  float4 areg[8];
  #pragma unroll
  for (int i=0;i<8;++i){
    int id = i*256 + tid, row = id>>4, qc = id&15;
    areg[i] = *(const float4*)(A + (size_t)(m0+row)*512 + qc*4);
  }

  for (int k0 = 0; k0 < 512; k0 += 64){
    __syncthreads();
    #pragma unroll
    for (int i=0;i<8;++i){
      int id = i*256 + tid, row = id>>4, qc = id&15;
      unsigned int lo = cvtpk_bf16(areg[i].x, areg[i].y);
      unsigned int hi = cvtpk_bf16(areg[i].z, areg[i].w);
      unsigned int* dst = (unsigned int*)((char*)&As[0][0] + row*128
                          + ((qc>>1) ^ (row&7))*16 + (qc&1)*8);
      dst[0] = lo; dst[1] = hi;
    }
    #pragma unroll
    for (int i=0;i<4;++i){
      int o   = (w*4 + i)*1024 + lane*16;
      int row = o >> 7;
      int c   = (o >> 4) & 7;
      int cs  = c ^ (row & 7);
      gload16(W + (size_t)(n0+row)*512 + k0 + cs*8, (char*)&Bs[0][0] + (w*4+i)*1024);
    }
    __syncthreads();
    if (k0 + 64 < 512){
      #pragma unroll
      for (int i=0;i<8;++i){
        int id = i*256 + tid, row = id>>4, qc = id&15;
        areg[i] = *(const float4*)(A + (size_t)(m0+row)*512 + (k0+64) + qc*4);
      }
    }
    #pragma unroll
    for (int ks=0;ks<2;++ks){
      bf16x8 af[4], bfr[4];
      #pragma unroll
      for (int m=0;m<4;++m){
        int row = wr*64 + m*16 + q16;
        int c   = (ks*4 + g) ^ (row & 7);
        af[m] = *(const bf16x8*)((const char*)&As[0][0] + row*128 + c*16);
      }
      #pragma unroll
      for (int n=0;n<4;++n){
        int row = wc*64 + n*16 + q16;
        int c   = (ks*4 + g) ^ (row & 7);
        bfr[n] = *(const bf16x8*)((const char*)&Bs[0][0] + row*128 + c*16);
      }
      #pragma unroll
      for (int m=0;m<4;++m)
        #pragma unroll
        for (int n=0;n<4;++n)
          acc[m][n] = __builtin_amdgcn_mfma_f32_16x16x32_bf16(af[m], bfr[n], acc[m][n], 0,0,0);
    }
  }

  const size_t ZS = (size_t)8192*512;
  #pragma unroll
  for (int m=0;m<4;++m){
    const int rowl = wr*64 + m*16 + g*4;
    #pragma unroll
    for (int n=0;n<4;++n){
      const int col = n0 + wc*64 + n*16 + q16;
      const float bv2 = bias[col];
      #pragma unroll
      for (int r=0;r<4;++r){
        float v = (acc[m][n][r] + bv2) * sc;
        Cb[(size_t)z*ZS + (size_t)(m0 + rowl + r)*512 + col] = f2bf(v);
      }
    }
  }
}

// ---------------------------------------------------------------------------
// bf16-A MFMA GEMM for the MLP: C = op(A @ W^T + bias) (+ bf16 res)
// ---------------------------------------------------------------------------
__global__ __launch_bounds__(256) void mab_gemm_mfma(
    const unsigned short* __restrict__ A, const unsigned short* __restrict__ W,
    const float* __restrict__ bias, const unsigned short* __restrict__ resb,
    unsigned short* __restrict__ Cb, float* __restrict__ Cf, int relu)
{
  __shared__ unsigned short As[128][64];
  __shared__ unsigned short Bs[128][64];
  const int m0 = blockIdx.y*128, n0 = blockIdx.x*128;
  const int tid = threadIdx.x, w = tid>>6, lane = tid&63, g = lane>>4, q16 = lane&15;
  const int wr = w>>1, wc = w&1;

  f32x4 acc[4][4];
  #pragma unroll
  for (int m=0;m<4;++m)
    #pragma unroll
    for (int n=0;n<4;++n) acc[m][n] = (f32x4){0.f,0.f,0.f,0.f};

  for (int k0 = 0; k0 < 512; k0 += 64){
    __syncthreads();
    #pragma unroll
    for (int i=0;i<4;++i){
      int o   = (w*4 + i)*1024 + lane*16;
      int row = o >> 7;
      int c   = (o >> 4) & 7;
      int cs  = c ^ (row & 7);
      gload16(A + (size_t)(m0+row)*512 + k0 + cs*8, (char*)&As[0][0] + (w*4+i)*1024);
      gload16(W + (size_t)(n0+row)*512 + k0 + cs*8, (char*)&Bs[0][0] + (w*4+i)*1024);
    }
    __syncthreads();
    #pragma unroll
    for (int ks=0;ks<2;++ks){
      bf16x8 af[4], bfr[4];
      #pragma unroll
      for (int m=0;m<4;++m){
        int row = wr*64 + m*16 + q16;
        int c   = (ks*4 + g) ^ (row & 7);
        af[m] = *(const bf16x8*)((const char*)&As[0][0] + row*128 + c*16);
      }
      #pragma unroll
      for (int n=0;n<4;++n){
        int row = wc*64 + n*16 + q16;
        int c   = (ks*4 + g) ^ (row & 7);
        bfr[n] = *(const bf16x8*)((const char*)&Bs[0][0] + row*128 + c*16);
      }
      #pragma unroll
      for (int m=0;m<4;++m)
        #pragma unroll
        for (int n=0;n<4;++n)
          acc[m][n] = __builtin_amdgcn_mfma_f32_16x16x32_bf16(af[m], bfr[n], acc[m][n], 0,0,0);
    }
  }

  #pragma unroll
  for (int m=0;m<4;++m){
    const int rowl = wr*64 + m*16 + g*4;
    #pragma unroll
    for (int n=0;n<4;++n){
      const int col = n0 + wc*64 + n*16 + q16;
      const float bv = bias[col];
      #pragma unroll
      for (int r=0;r<4;++r){
        float v = acc[m][n][r] + bv;
        if (relu) v = fmaxf(v, 0.f);
        size_t off = (size_t)(m0 + rowl + r)*512 + col;
        if (resb) v += bf2f(resb[off]);
        if (Cb) Cb[off] = f2bf(v);
        if (Cf) Cf[off] = v;
      }
    }
  }
}

// ---------------------------------------------------------------------------
// MFMA flash attention v6: R3 body, K-SPLIT ACROSS BLOCKS.
// Grid (NQ/128, H, B*2) = 1024 blocks x 4 waves. zz = blockIdx.z&1 selects the
// k-half [zz*1024, zz*1024+1024) (16 tiles of 64). Per-wave per-tile body is
// R3's verbatim (KVBLK=64, LDS dbuf K/V via global_load_lds + XOR swizzle,
// exp2 domain, defer-max, in-register P). Q frags direct from global (no Qs
// LDS) -> LDS 32KB -> 4 blocks/CU; launch_bounds(256,4) caps VGPR at 128
// (R3 body = 108, no spill) -> 16 waves/CU = 4 waves/SIMD (2x R3 TLP).
// Epilogue writes RAW partials: O' bf16 (un-normalized, exp2-relative to the
// block's running m) + (m,l,a) per q-row. Merge is exact (all partials are
// self-consistent w.r.t. their own m). Kp pre-scaled by log2e/sqrt(512).
// ---------------------------------------------------------------------------
__global__ __launch_bounds__(256, 4) void mab_attn6(
    const unsigned short* __restrict__ Qp, const unsigned short* __restrict__ Kp,
    const unsigned short* __restrict__ Vpt,
    const float* __restrict__ Kpos, const float* __restrict__ kp,
    unsigned short* __restrict__ OP, float4* __restrict__ MLA)
{
  __shared__ unsigned short Kb[2][64][64];   // [k'][d], swizzled chunks
  __shared__ unsigned short Vb[2][64][64];   // [d][k'], swizzled chunks

  const int q0 = blockIdx.x*128;
  const int h  = blockIdx.y;
  const int b  = blockIdx.z >> 1;
  const int zz = blockIdx.z & 1;
  const int tid = threadIdx.x, w = tid>>6, lane = tid&63;
  const int q32 = lane & 31, hi = lane >> 5;
  const int kbase = zz*1024;

  const unsigned short* Kg = Kp + ((size_t)b*NKx)*Dx + h*64;
  const unsigned short* Vg = Vpt + ((size_t)(b*512) + h*64)*NKx;
  const float* KProw = Kpos + (size_t)b*NQx*NKx + (size_t)(q0 + w*32 + q32)*NKx;

  const int sr = lane>>3;        // staging row 0..7
  const int sc = lane&7;         // staging chunk 0..7

  // prologue: stage K/V tile 0 of this k-half
  #pragma unroll
  for (int i=0;i<2;++i){
    int r  = w*16 + i*8 + sr;
    int cs = sc ^ (r & 7);
    gload16(Kg + (size_t)(kbase + r)*Dx + cs*8, (char*)&Kb[0][0][0] + w*2048 + i*1024);
    gload16(Vg + (size_t)r*NKx + kbase + cs*8, (char*)&Vb[0][0][0] + w*2048 + i*1024);
  }

  // Q frags direct from global (L2-resident)
  const unsigned short* Qrowp = Qp + ((size_t)(b*NQx + q0 + w*32 + q32))*Dx + h*64;
  bf16x8 qf[4];
  #pragma unroll
  for (int ds=0; ds<4; ++ds)
    qf[ds] = *(const bf16x8*)(Qrowp + ds*16 + hi*8);

  // qkp = (Qh . kp) * log2e for own q-row
  float qkp = 0.f;
  #pragma unroll
  for (int ds=0; ds<4; ++ds){
    union { bf16x8 v; unsigned short u[8]; } qa; qa.v = qf[ds];
    #pragma unroll
    for (int j=0;j<8;++j)
      qkp = fmaf(bf2f(qa.u[j]), kp[ds*16 + hi*8 + j], qkp);
  }
  qkp += __shfl_xor(qkp, 32);
  qkp *= 1.4426950408889634f;

  float m_i = -1e30f, l_i = 0.f, a_i = 0.f;
  f32x16 accT[2];
  #pragma unroll
  for (int db=0; db<2; ++db)
    #pragma unroll
    for (int r=0;r<16;++r) accT[db][r] = 0.f;

  __syncthreads();   // full drain once (prologue only)

  for (int t = 0; t < 16; ++t){
    const int cur = t & 1;
    const int k0 = kbase + t*64;

    // Kpos for this tile
    f32x4 kq[2][4];
    #pragma unroll
    for (int n=0;n<2;++n)
      #pragma unroll
      for (int a=0;a<4;++a)
        kq[n][a] = *(const f32x4*)(KProw + k0 + n*32 + a*8 + hi*4);

    // prefetch next K/V tile into the other buffer
    if (t+1 < 16){
      const int k1 = k0 + 64;
      #pragma unroll
      for (int i=0;i<2;++i){
        int r  = w*16 + i*8 + sr;
        int cs = sc ^ (r & 7);
        gload16(Kg + (size_t)(k1 + r)*Dx + cs*8,
                (char*)&Kb[cur^1][0][0] + w*2048 + i*1024);
        gload16(Vg + (size_t)r*NKx + k1 + cs*8,
                (char*)&Vb[cur^1][0][0] + w*2048 + i*1024);
      }
    }
    __builtin_amdgcn_sched_barrier(0);

    // S^T = K . Q^T (log2 domain; Kp pre-scaled by log2e/sqrt(512))
    f32x16 sT[2];
    __builtin_amdgcn_s_setprio(1);
    #pragma unroll
    for (int n=0;n<2;++n){
      f32x16 c;
      #pragma unroll
      for (int r=0;r<16;++r) c[r] = 0.f;
      #pragma unroll
      for (int ds=0; ds<4; ++ds){
        int row = n*32 + q32;
        int cc  = (ds*2 + hi) ^ (q32 & 7);
        bf16x8 kf = *(const bf16x8*)((const char*)&Kb[cur][0][0] + row*128 + cc*16);
        c = __builtin_amdgcn_mfma_f32_32x32x16_bf16(kf, qf[ds], c, 0,0,0);
      }
      sT[n] = c;
    }
    __builtin_amdgcn_s_setprio(0);

    // + Kpos * qkp (log2 domain); k' = n*32 + (r&3) + 8*(r>>2) + 4*hi
    #pragma unroll
    for (int n=0;n<2;++n)
      #pragma unroll
      for (int r=0;r<16;++r)
        sT[n][r] = fmaf(kq[n][r>>2][r&3], qkp, sT[n][r]);

    // tree max via v_max3
    float m0a = fmax3(sT[0][0], sT[0][1], sT[0][2]);
    float m0b = fmax3(sT[0][3], sT[0][4], sT[0][5]);
    float m0c = fmax3(sT[0][6], sT[0][7], sT[0][8]);
    float m0d = fmax3(sT[0][9], sT[0][10], sT[0][11]);
    float m0e = fmax3(sT[0][12], sT[0][13], sT[0][14]);
    float m1a = fmax3(sT[1][0], sT[1][1], sT[1][2]);
    float m1b = fmax3(sT[1][3], sT[1][4], sT[1][5]);
    float m1c = fmax3(sT[1][6], sT[1][7], sT[1][8]);
    float m1d = fmax3(sT[1][9], sT[1][10], sT[1][11]);
    float m1e = fmax3(sT[1][12], sT[1][13], sT[1][14]);
    float rm = fmax3(fmax3(m0a, m0b, m0c), fmax3(m0d, m0e, sT[0][15]),
                     fmax3(fmax3(m1a, m1b, m1c), fmax3(m1d, m1e, sT[1][15]), m_i));
    rm = fmaxf(rm, __shfl_xor(rm, 32));

    if (!__all(rm <= m_i + 11.544f)){      // 2^11.544 = e^8 bound
      float al = fexp2(m_i - rm);
      m_i = rm;
      l_i *= al; a_i *= al;
      #pragma unroll
      for (int db=0; db<2; ++db)
        #pragma unroll
        for (int r=0;r<16;++r) accT[db][r] *= al;
    }

    float ps = 0.f, pk = 0.f;
    #pragma unroll
    for (int n=0;n<2;++n)
      #pragma unroll
      for (int r=0;r<16;++r){
        float p = fexp2(sT[n][r] - m_i);
        sT[n][r] = p;
        ps += p;
        pk = fmaf(p, kq[n][r>>2][r&3], pk);
      }
    ps += __shfl_xor(ps, 32);
    pk += __shfl_xor(pk, 32);
    l_i += ps; a_i += pk;

    // pack P to bf16 frags in-register (cvt_pk + permlane32_swap)
    union PW { unsigned int u[4]; bf16x8 v; } pa[4];
    #pragma unroll
    for (int n=0;n<2;++n){
      unsigned int w0 = cvtpk_bf16(sT[n][0],  sT[n][1]);
      unsigned int w1 = cvtpk_bf16(sT[n][2],  sT[n][3]);
      unsigned int w2 = cvtpk_bf16(sT[n][4],  sT[n][5]);
      unsigned int w3 = cvtpk_bf16(sT[n][6],  sT[n][7]);
      unsigned int w4 = cvtpk_bf16(sT[n][8],  sT[n][9]);
      unsigned int w5 = cvtpk_bf16(sT[n][10], sT[n][11]);
      unsigned int w6 = cvtpk_bf16(sT[n][12], sT[n][13]);
      unsigned int w7 = cvtpk_bf16(sT[n][14], sT[n][15]);
      plane32_swap(w0, w2);
      plane32_swap(w1, w3);
      plane32_swap(w4, w6);
      plane32_swap(w5, w7);
      pa[n*2+0].u[0]=w0; pa[n*2+0].u[1]=w1; pa[n*2+0].u[2]=w2; pa[n*2+0].u[3]=w3;
      pa[n*2+1].u[0]=w4; pa[n*2+1].u[1]=w5; pa[n*2+1].u[2]=w6; pa[n*2+1].u[3]=w7;
    }

    // O^T += V . P
    __builtin_amdgcn_s_setprio(1);
    #pragma unroll
    for (int st=0; st<4; ++st){
      #pragma unroll
      for (int db=0; db<2; ++db){
        int row = db*32 + q32;
        int cc  = (st*2 + hi) ^ (q32 & 7);
        bf16x8 vf = *(const bf16x8*)((const char*)&Vb[cur][0][0] + row*128 + cc*16);
        accT[db] = __builtin_amdgcn_mfma_f32_32x32x16_bf16(vf, pa[st].v, accT[db], 0,0,0);
      }
    }
    __builtin_amdgcn_s_setprio(0);

    __syncthreads();
  }

  // epilogue: write RAW partials (no normalization, no residual)
  const size_t rowg = (size_t)(b*NQx + q0 + w*32 + q32);
  unsigned short* Orow = OP + (size_t)zz*(8192*512) + rowg*Dx + h*64;
  #pragma unroll
  for (int db=0; db<2; ++db){
    #pragma unroll
    for (int a2=0; a2<4; ++a2){
      int d0 = db*32 + a2*8 + hi*4;
      uint2 pk2;
      pk2.x = cvtpk_bf16(accT[db][a2*4+0], accT[db][a2*4+1]);
      pk2.y = cvtpk_bf16(accT[db][a2*4+2], accT[db][a2*4+3]);
      *(uint2*)(Orow + d0) = pk2;
    }
  }
  if (hi == 0){
    float4 mla; mla.x = m_i; mla.y = l_i; mla.z = a_i; mla.w = 0.f;
    MLA[(size_t)zz*65536 + rowg*8 + h] = mla;
  }
}

// ---------------------------------------------------------------------------
// Merge the two k-half partials + attention residual (Qh, vp) + LayerNorm0.
// One block per row (8192). Writes bf16 O0b (MLP input AND residual).
// ---------------------------------------------------------------------------
__global__ __launch_bounds__(256) void mab_merge_ln(
    const unsigned short* __restrict__ OP, const float4* __restrict__ MLA,
    const unsigned short* __restrict__ Qp, const float* __restrict__ vp,
    const float* __restrict__ g, const float* __restrict__ be,
    unsigned short* __restrict__ Yb)
{
  const int row = blockIdx.x;
  const int tid = threadIdx.x;
  const int h = tid >> 5;                     // d = tid*2 -> head = d/64
  const size_t R = (size_t)8192*512;

  float4 A0 = MLA[(size_t)row*8 + h];
  float4 A1 = MLA[65536 + (size_t)row*8 + h];
  float mM  = fmaxf(A0.x, A1.x);
  float al0 = fexp2(A0.x - mM), al1 = fexp2(A1.x - mM);
  float l   = fmaf(al0, A0.y, al1*A1.y);
  float inv = 1.0f / l;
  float aw  = fmaf(al0, A0.z, al1*A1.z) * inv;

  const int d = tid*2;
  ushort2 o0 = *(const ushort2*)(OP + (size_t)row*Dx + d);
  ushort2 o1 = *(const ushort2*)(OP + R + (size_t)row*Dx + d);
  ushort2 qh = *(const ushort2*)(Qp + (size_t)row*Dx + d);
  float2 vv  = *(const float2*)(vp + (d & 63));
  float2 v;
  v.x = fmaf(fmaf(al0, bf2f(o0.x), al1*bf2f(o1.x)), inv, bf2f(qh.x) + aw*vv.x);
  v.y = fmaf(fmaf(al0, bf2f(o0.y), al1*bf2f(o1.y)), inv, bf2f(qh.y) + aw*vv.y);

  // LayerNorm over 512
  float s  = v.x + v.y;
  float sq = fmaf(v.x,v.x, v.y*v.y);
  #pragma unroll
  for (int m=1; m<64; m<<=1){ s += __shfl_xor(s,m); sq += __shfl_xor(sq,m); }
  __shared__ float red[2][4];
  const int wid = tid>>6, lane = tid&63;
  if (lane==0){ red[0][wid]=s; red[1][wid]=sq; }
  __syncthreads();
  s  = red[0][0]+red[0][1]+red[0][2]+red[0][3];
  sq = red[1][0]+red[1][1]+red[1][2]+red[1][3];
  float mean = s*(1.0f/Dx);
  float var  = sq*(1.0f/Dx) - mean*mean;
  float rstd = rsqrtf(var + 1e-5f);
  float2 gg = *(const float2*)(g  + d);
  float2 bb = *(const float2*)(be + d);
  ushort2 ob;
  ob.x = f2bf((v.x-mean)*rstd*gg.x + bb.x);
  ob.y = f2bf((v.y-mean)*rstd*gg.y + bb.y);
  *(ushort2*)(Yb + (size_t)row*Dx + d) = ob;
}

// ---------------------------------------------------------------------------
// Row LayerNorm over 512 (final), f32 in/out.
// ---------------------------------------------------------------------------
__global__ __launch_bounds__(256) void mab_ln2(
    const float* __restrict__ Xin, const float* __restrict__ g,
    const float* __restrict__ be, float* __restrict__ Yf)
{
  const int row = blockIdx.x;
  const int tid = threadIdx.x;
  const float* x = Xin + (size_t)row*Dx;
  float2 v = *(const float2*)(x + tid*2);
  float s  = v.x + v.y;
  float sq = fmaf(v.x,v.x, v.y*v.y);
  #pragma unroll
  for (int m=1; m<64; m<<=1){ s += __shfl_xor(s,m); sq += __shfl_xor(sq,m); }
  __shared__ float red[2][4];
  const int wid = tid>>6, lane = tid&63;
  if (lane==0){ red[0][wid]=s; red[1][wid]=sq; }
  __syncthreads();
  s  = red[0][0]+red[0][1]+red[0][2]+red[0][3];
  sq = red[1][0]+red[1][1]+red[1][2]+red[1][3];
  float mean = s*(1.0f/Dx);
  float var  = sq*(1.0f/Dx) - mean*mean;
  float rstd = rsqrtf(var + 1e-5f);
  float2 gg = *(const float2*)(g  + tid*2);
  float2 bb = *(const float2*)(be + tid*2);
  float2 o;
  o.x = (v.x-mean)*rstd*gg.x + bb.x;
  o.y = (v.y-mean)*rstd*gg.y + bb.y;
  *(float2*)(Yf + (size_t)row*Dx + tid*2) = o;
}

// ---------------------------------------------------------------------------
extern "C" void kernel_launch(void* const* d_in, const int* in_sizes, int n_in,
                              void* d_out, int out_size, void* d_ws, size_t ws_size,
                              hipStream_t stream)
{
  const float* Q    = (const float*)d_in[0];
  const float* K    = (const float*)d_in[1];
  const float* Kpos = (const float*)d_in[2];
  const float* Wq   = (const float*)d_in[3];
  const float* bq   = (const float*)d_in[4];
  const float* Wk   = (const float*)d_in[5];
  const float* bk   = (const float*)d_in[6];
  const float* Wv   = (const float*)d_in[7];
  const float* bv   = (const float*)d_in[8];
  const float* kp   = (const float*)d_in[9];
  const float* vp   = (const float*)d_in[10];
  const float* W0   = (const float*)d_in[11];
  const float* b0   = (const float*)d_in[12];
  const float* W1   = (const float*)d_in[13];
  const float* b1   = (const float*)d_in[14];
  const float* g0   = (const float*)d_in[15];
  const float* be0  = (const float*)d_in[16];
  const float* g1   = (const float*)d_in[17];
  const float* be1  = (const float*)d_in[18];
  float* out = (float*)d_out;
  char* wsb  = (char*)d_ws;

  const size_t MB = 1024*1024;
  unsigned short* Qp  = (unsigned short*)(wsb);          // 8 MiB bf16 [8192][512]
  unsigned short* Kp  = (unsigned short*)(wsb + 8*MB);   // pre-scaled (log2e/sqrt512)
  unsigned short* Vp  = (unsigned short*)(wsb + 16*MB);  // -> T1 after vt
  unsigned short* Vpt = (unsigned short*)(wsb + 24*MB);  // 8 MiB -> O0b after attn
  unsigned short* OP  = (unsigned short*)(wsb + 32*MB);  // 16 MiB (2 partials, bf16)
  float4*         MLA = (float4*)        (wsb + 48*MB);  // 2 MiB [2][8192][8] f32x4
  unsigned short* Wt  = (unsigned short*)(wsb + 50*MB);  // 2.5 MiB [5][512][512]
  unsigned short* O0b = Vpt;                             // reuse (attn done)
  unsigned short* T1  = Vp;                              // reuse (vt done)

  const float kscale = 0.044194173824159216f * 1.4426950408889634f; // log2e/sqrt(512)

  // weight transposes (Wq,Wk,Wv,W0,W1)
  mab_wt<<<dim3(8,8,5), 256, 0, stream>>>(Wq, Wk, Wv, W0, W1, Wt);
  // fused Q/K/V projections from f32 inputs (z=0,1,2)
  mab_gemm_proj<<<dim3(4,64,3), 256, 0, stream>>>(Q, K, Wt, bq, bk, bv, Qp, kscale);
  // V transpose to d-major
  mab_vt<<<dim3(32,8,4), 256, 0, stream>>>(Vp, Vpt);
  // fused attention v6 (k-split across blocks, 4 waves/SIMD), raw partials
  mab_attn6<<<dim3(16,8,8), 256, 0, stream>>>(Qp, Kp, Vpt, Kpos, kp, OP, MLA);
  // merge partials + residual + LN0 -> O0b (bf16)
  mab_merge_ln<<<8192, 256, 0, stream>>>(OP, MLA, Qp, vp, g0, be0, O0b);
  // T1 = relu(O0b @ W0 + b0)  (bf16 out)
  mab_gemm_mfma<<<dim3(4,64,1), 256, 0, stream>>>(
      O0b, Wt + (size_t)3*512*512, b0, nullptr, T1, nullptr, 1);
  // out = O0b + relu(T1 @ W1 + b1)  (f32 out)
  mab_gemm_mfma<<<dim3(4,64,1), 256, 0, stream>>>(
      T1, Wt + (size_t)4*512*512, b1, O0b, nullptr, out, 1);
  // final LN in-place
  mab_ln2<<<8192, 256, 0, stream>>>(out, g1, be1, out);
}

// Round 13
// 207.217 us; speedup vs baseline: 1.3506x; 1.2259x over previous
//
#include <hip/hip_runtime.h>
#include <math.h>

// Problem constants (MAB_50921132261692)
#define Bx  4
#define NQx 2048
#define NKx 2048
#define Dx  512
#define Hx  8

typedef __attribute__((ext_vector_type(8))) __bf16 bf16x8;
typedef __attribute__((ext_vector_type(4))) float f32x4;
typedef __attribute__((ext_vector_type(16))) float f32x16;

typedef const __attribute__((address_space(1))) unsigned int* gas_ptr;
typedef __attribute__((address_space(3))) unsigned int* lds_ptr;

__device__ __forceinline__ void gload16(const void* g, void* l){
  __builtin_amdgcn_global_load_lds((gas_ptr)g, (lds_ptr)l, 16, 0, 0);
}

__device__ __forceinline__ unsigned short f2bf(float f){
  union { float f; unsigned int u; } v; v.f = f;
  unsigned int r = (v.u + 0x7FFFu + ((v.u >> 16) & 1u)) >> 16;
  return (unsigned short)r;
}
__device__ __forceinline__ float bf2f(unsigned short u){
  union { unsigned int u; float f; } v; v.u = ((unsigned int)u) << 16; return v.f;
}
__device__ __forceinline__ unsigned int cvtpk_bf16(float a, float b){
  unsigned int d;
  asm("v_cvt_pk_bf16_f32 %0, %1, %2" : "=v"(d) : "v"(a), "v"(b));
  return d;
}
__device__ __forceinline__ void plane32_swap(unsigned int& a, unsigned int& b){
  asm("v_permlane32_swap_b32 %0, %1" : "+v"(a), "+v"(b));
}
__device__ __forceinline__ float fexp2(float x){           // D = 2^x
  float d; asm("v_exp_f32 %0, %1" : "=v"(d) : "v"(x)); return d;
}
__device__ __forceinline__ float fmax3(float a, float b, float c){
  float d; asm("v_max3_f32 %0, %1, %2, %3" : "=v"(d) : "v"(a), "v"(b), "v"(c)); return d;
}

// ---------------------------------------------------------------------------
// Transpose + convert 5 weights [512][512] f32 -> Wt bf16 [z][N=512][K=512].
// ---------------------------------------------------------------------------
__global__ __launch_bounds__(256) void mab_wt(
    const float* __restrict__ Wq, const float* __restrict__ Wk, const float* __restrict__ Wv,
    const float* __restrict__ W0, const float* __restrict__ W1,
    unsigned short* __restrict__ Wt)
{
  __shared__ unsigned short T[64][72];
  const int z = blockIdx.z;
  const float* W = (z==0)?Wq:(z==1)?Wk:(z==2)?Wv:(z==3)?W0:W1;
  unsigned short* O = Wt + (size_t)z*512*512;
  const int k0 = blockIdx.x*64, n0 = blockIdx.y*64;
  const int tid = threadIdx.x;
  #pragma unroll
  for (int i=0;i<4;++i){
    int id = tid + i*256;          // 1024 = 64 rows x 16 float4
    int r = id>>4, c4 = id&15;
    float4 v = *(const float4*)(W + (size_t)(k0+r)*512 + n0 + c4*4);
    ushort4 o; o.x=f2bf(v.x); o.y=f2bf(v.y); o.z=f2bf(v.z); o.w=f2bf(v.w);
    *(ushort4*)&T[r][c4*4] = o;
  }
  __syncthreads();
  #pragma unroll
  for (int i=0;i<2;++i){
    int id = tid + i*256;          // 512 = 64 out-rows x 8 chunks
    int c = id>>3, r8 = id&7;
    union { unsigned short u[8]; uint4 v; } o;
    #pragma unroll
    for (int j=0;j<8;++j) o.u[j] = T[r8*8+j][c];
    *(uint4*)(O + (size_t)(n0+c)*512 + k0 + r8*8) = o.v;
  }
}

// ---------------------------------------------------------------------------
// Transpose Vp bf16 [B*NK][512] -> Vpt [B][512][NK] (d-major per batch).
// ---------------------------------------------------------------------------
__global__ __launch_bounds__(256) void mab_vt(
    const unsigned short* __restrict__ Vp, unsigned short* __restrict__ Vpt)
{
  __shared__ unsigned short T[64][72];
  const int r0 = blockIdx.x*64;   // k within batch
  const int c0 = blockIdx.y*64;   // d
  const int b  = blockIdx.z;
  const int tid = threadIdx.x;
  #pragma unroll
  for (int i=0;i<2;++i){
    int id = tid + i*256;          // 512 = 64 rows x 8 chunks(8 bf16)
    int r = id>>3, c8 = id&7;
    *(uint4*)&T[r][c8*8] = *(const uint4*)(Vp + (size_t)(b*NKx + r0+r)*512 + c0 + c8*8);
  }
  __syncthreads();
  #pragma unroll
  for (int i=0;i<2;++i){
    int id = tid + i*256;
    int c = id>>3, r8 = id&7;
    union { unsigned short u[8]; uint4 v; } o;
    #pragma unroll
    for (int j=0;j<8;++j) o.u[j] = T[r8*8+j][c];
    *(uint4*)(Vpt + ((size_t)(b*512) + c0 + c)*NKx + r0 + r8*8) = o.v;
  }
}

// ---------------------------------------------------------------------------
// QKV projection GEMM with fused f32->bf16 A conversion.
// ---------------------------------------------------------------------------
__global__ __launch_bounds__(256) void mab_gemm_proj(
    const float* __restrict__ Qf, const float* __restrict__ Kf,
    const unsigned short* __restrict__ Wt,
    const float* __restrict__ bq, const float* __restrict__ bk, const float* __restrict__ bv,
    unsigned short* __restrict__ Cb, float kscale)
{
  __shared__ unsigned short As[128][64];
  __shared__ unsigned short Bs[128][64];
  const int z = blockIdx.z;
  const float* A = (z==0) ? Qf : Kf;
  const unsigned short* W = Wt + (size_t)z*512*512;
  const float* bias = (z==0)?bq:((z==1)?bk:bv);
  const float sc = (z==1) ? kscale : 1.0f;
  const int m0 = blockIdx.y*128, n0 = blockIdx.x*128;
  const int tid = threadIdx.x, w = tid>>6, lane = tid&63, g = lane>>4, q16 = lane&15;
  const int wr = w>>1, wc = w&1;

  f32x4 acc[4][4];
  #pragma unroll
  for (int m=0;m<4;++m)
    #pragma unroll
    for (int n=0;n<4;++n) acc[m][n] = (f32x4){0.f,0.f,0.f,0.f};

  float4 areg[8];
  #pragma unroll
  for (int i=0;i<8;++i){
    int id = i*256 + tid, row = id>>4, qc = id&15;
    areg[i] = *(const float4*)(A + (size_t)(m0+row)*512 + qc*4);
  }

  for (int k0 = 0; k0 < 512; k0 += 64){
    __syncthreads();
    #pragma unroll
    for (int i=0;i<8;++i){
      int id = i*256 + tid, row = id>>4, qc = id&15;
      unsigned int lo = cvtpk_bf16(areg[i].x, areg[i].y);
      unsigned int hi = cvtpk_bf16(areg[i].z, areg[i].w);
      unsigned int* dst = (unsigned int*)((char*)&As[0][0] + row*128
                          + ((qc>>1) ^ (row&7))*16 + (qc&1)*8);
      dst[0] = lo; dst[1] = hi;
    }
    #pragma unroll
    for (int i=0;i<4;++i){
      int o   = (w*4 + i)*1024 + lane*16;
      int row = o >> 7;
      int c   = (o >> 4) & 7;
      int cs  = c ^ (row & 7);
      gload16(W + (size_t)(n0+row)*512 + k0 + cs*8, (char*)&Bs[0][0] + (w*4+i)*1024);
    }
    __syncthreads();
    if (k0 + 64 < 512){
      #pragma unroll
      for (int i=0;i<8;++i){
        int id = i*256 + tid, row = id>>4, qc = id&15;
        areg[i] = *(const float4*)(A + (size_t)(m0+row)*512 + (k0+64) + qc*4);
      }
    }
    #pragma unroll
    for (int ks=0;ks<2;++ks){
      bf16x8 af[4], bfr[4];
      #pragma unroll
      for (int m=0;m<4;++m){
        int row = wr*64 + m*16 + q16;
        int c   = (ks*4 + g) ^ (row & 7);
        af[m] = *(const bf16x8*)((const char*)&As[0][0] + row*128 + c*16);
      }
      #pragma unroll
      for (int n=0;n<4;++n){
        int row = wc*64 + n*16 + q16;
        int c   = (ks*4 + g) ^ (row & 7);
        bfr[n] = *(const bf16x8*)((const char*)&Bs[0][0] + row*128 + c*16);
      }
      #pragma unroll
      for (int m=0;m<4;++m)
        #pragma unroll
        for (int n=0;n<4;++n)
          acc[m][n] = __builtin_amdgcn_mfma_f32_16x16x32_bf16(af[m], bfr[n], acc[m][n], 0,0,0);
    }
  }

  const size_t ZS = (size_t)8192*512;
  #pragma unroll
  for (int m=0;m<4;++m){
    const int rowl = wr*64 + m*16 + g*4;
    #pragma unroll
    for (int n=0;n<4;++n){
      const int col = n0 + wc*64 + n*16 + q16;
      const float bv2 = bias[col];
      #pragma unroll
      for (int r=0;r<4;++r){
        float v = (acc[m][n][r] + bv2) * sc;
        Cb[(size_t)z*ZS + (size_t)(m0 + rowl + r)*512 + col] = f2bf(v);
      }
    }
  }
}

// ---------------------------------------------------------------------------
// bf16-A MFMA GEMM for the MLP: C = op(A @ W^T + bias) (+ bf16 res)
// ---------------------------------------------------------------------------
__global__ __launch_bounds__(256) void mab_gemm_mfma(
    const unsigned short* __restrict__ A, const unsigned short* __restrict__ W,
    const float* __restrict__ bias, const unsigned short* __restrict__ resb,
    unsigned short* __restrict__ Cb, float* __restrict__ Cf, int relu)
{
  __shared__ unsigned short As[128][64];
  __shared__ unsigned short Bs[128][64];
  const int m0 = blockIdx.y*128, n0 = blockIdx.x*128;
  const int tid = threadIdx.x, w = tid>>6, lane = tid&63, g = lane>>4, q16 = lane&15;
  const int wr = w>>1, wc = w&1;

  f32x4 acc[4][4];
  #pragma unroll
  for (int m=0;m<4;++m)
    #pragma unroll
    for (int n=0;n<4;++n) acc[m][n] = (f32x4){0.f,0.f,0.f,0.f};

  for (int k0 = 0; k0 < 512; k0 += 64){
    __syncthreads();
    #pragma unroll
    for (int i=0;i<4;++i){
      int o   = (w*4 + i)*1024 + lane*16;
      int row = o >> 7;
      int c   = (o >> 4) & 7;
      int cs  = c ^ (row & 7);
      gload16(A + (size_t)(m0+row)*512 + k0 + cs*8, (char*)&As[0][0] + (w*4+i)*1024);
      gload16(W + (size_t)(n0+row)*512 + k0 + cs*8, (char*)&Bs[0][0] + (w*4+i)*1024);
    }
    __syncthreads();
    #pragma unroll
    for (int ks=0;ks<2;++ks){
      bf16x8 af[4], bfr[4];
      #pragma unroll
      for (int m=0;m<4;++m){
        int row = wr*64 + m*16 + q16;
        int c   = (ks*4 + g) ^ (row & 7);
        af[m] = *(const bf16x8*)((const char*)&As[0][0] + row*128 + c*16);
      }
      #pragma unroll
      for (int n=0;n<4;++n){
        int row = wc*64 + n*16 + q16;
        int c   = (ks*4 + g) ^ (row & 7);
        bfr[n] = *(const bf16x8*)((const char*)&Bs[0][0] + row*128 + c*16);
      }
      #pragma unroll
      for (int m=0;m<4;++m)
        #pragma unroll
        for (int n=0;n<4;++n)
          acc[m][n] = __builtin_amdgcn_mfma_f32_16x16x32_bf16(af[m], bfr[n], acc[m][n], 0,0,0);
    }
  }

  #pragma unroll
  for (int m=0;m<4;++m){
    const int rowl = wr*64 + m*16 + g*4;
    #pragma unroll
    for (int n=0;n<4;++n){
      const int col = n0 + wc*64 + n*16 + q16;
      const float bv = bias[col];
      #pragma unroll
      for (int r=0;r<4;++r){
        float v = acc[m][n][r] + bv;
        if (relu) v = fmaxf(v, 0.f);
        size_t off = (size_t)(m0 + rowl + r)*512 + col;
        if (resb) v += bf2f(resb[off]);
        if (Cb) Cb[off] = f2bf(v);
        if (Cf) Cf[off] = v;
      }
    }
  }
}

// ---------------------------------------------------------------------------
// MFMA flash attention v7: ALL-HEADS-PER-BLOCK + LDS-staged K/V/Kpos.
// Grid (NQ/32=64, B=4) = 256 blocks x 8 waves (512 thr); wave w = head w,
// all waves share q-rows q0..q0+31. The 32x32 Kpos f32 tile is gload_lds-
// staged ONCE per block (waves 0-3) and read by all 8 waves from LDS ->
// Kpos L3-side traffic 536MB -> 67MB (the R3 floor's dominant stall).
// K/V per head staged via global_load_lds, KVBLK=32, double-buffered,
// XOR-swizzled (R9-verified mappings). LDS = 128KB K/V + 8KB Kpos = 136KB,
// 1 block/CU, 2 waves/SIMD. exp2 domain, defer-max, in-register P,
// tree-reduced ps/pk. Kp pre-scaled by log2e/sqrt(512).
// Vpt d-major [B][512][NK]. X = Qh + O/l + (akp/l)*vp (pre-LN), f32.
// ---------------------------------------------------------------------------
__global__ __launch_bounds__(512, 2) void mab_attn7(
    const unsigned short* __restrict__ Qp, const unsigned short* __restrict__ Kp,
    const unsigned short* __restrict__ Vpt,
    const float* __restrict__ Kpos, const float* __restrict__ kp, const float* __restrict__ vp,
    float* __restrict__ X)
{
  __shared__ __align__(16) char pool[139264];
  // [0,65536):      K per wave: w*8192 + buf*4096   (32 k x 64 d bf16, swz)
  // [65536,131072): V per wave: w*8192 + buf*4096   (64 d x 32 k bf16, swz)
  // [131072,139264): Kpos:      buf*4096            (32 q x 32 k f32, swz)

  const int qt = blockIdx.x;
  const int b  = blockIdx.y;
  const int q0 = qt*32;
  const int tid = threadIdx.x, w = tid>>6, lane = tid&63;
  const int q32 = lane & 31, hi = lane >> 5;
  const int h = w;

  char* Kbase = pool + w*8192;
  char* Vbase = pool + 65536 + w*8192;
  char* KQb   = pool + 131072;

  const unsigned short* Kg = Kp + ((size_t)b*NKx)*Dx + h*64;
  const unsigned short* Vg = Vpt + ((size_t)(b*512) + h*64)*NKx;
  const float* KPg = Kpos + (size_t)b*NQx*NKx + (size_t)q0*NKx;   // [32][2048]

  const int sr8 = lane>>3, sc8 = lane&7;   // K/Kpos staging: 8 rows x 8 chunks
  const int sr4 = lane>>2, sc4 = lane&3;   // V staging: 16 rows x 4 chunks

  // ---- prologue: stage tile 0 (buf 0) ----
  #pragma unroll
  for (int i=0;i<4;++i){
    int kr = i*8 + sr8, kcs = sc8 ^ (kr & 7);
    gload16(Kg + (size_t)kr*Dx + kcs*8, Kbase + i*1024);
    int vr = i*16 + sr4, vcs = sc4 ^ ((vr>>1) & 3);
    gload16(Vg + (size_t)vr*NKx + vcs*8, Vbase + i*1024);
  }
  if (w < 4){
    int pr = w*8 + sr8, pcs = sc8 ^ (pr & 7);
    gload16(KPg + (size_t)pr*NKx + pcs*4, KQb + w*1024);
  }

  // Q frags direct from global (L2-resident)
  const unsigned short* Qrowp = Qp + ((size_t)(b*NQx + q0 + q32))*Dx + h*64;
  bf16x8 qf[4];
  #pragma unroll
  for (int ds=0; ds<4; ++ds)
    qf[ds] = *(const bf16x8*)(Qrowp + ds*16 + hi*8);

  // qkp = (Qh . kp) * log2e for own q-row
  float qkp = 0.f;
  #pragma unroll
  for (int ds=0; ds<4; ++ds){
    union { bf16x8 v; unsigned short u[8]; } qa; qa.v = qf[ds];
    #pragma unroll
    for (int j=0;j<8;++j)
      qkp = fmaf(bf2f(qa.u[j]), kp[ds*16 + hi*8 + j], qkp);
  }
  qkp += __shfl_xor(qkp, 32);
  qkp *= 1.4426950408889634f;

  float m_i = -1e30f, l_i = 0.f, a_i = 0.f;
  f32x16 accT[2];
  #pragma unroll
  for (int db=0; db<2; ++db)
    #pragma unroll
    for (int r=0;r<16;++r) accT[db][r] = 0.f;

  __syncthreads();   // prologue staging complete

  // ---- main loop: 64 tiles of 32 k ----
  for (int t = 0; t < 64; ++t){
    const int cur = t & 1;
    const int k0 = t*32;

    // stage next tile into the other buffers
    if (t+1 < 64){
      const int k1 = k0 + 32;
      #pragma unroll
      for (int i=0;i<4;++i){
        int kr = i*8 + sr8, kcs = sc8 ^ (kr & 7);
        gload16(Kg + (size_t)(k1 + kr)*Dx + kcs*8, Kbase + (cur^1)*4096 + i*1024);
        int vr = i*16 + sr4, vcs = sc4 ^ ((vr>>1) & 3);
        gload16(Vg + (size_t)vr*NKx + k1 + vcs*8, Vbase + (cur^1)*4096 + i*1024);
      }
      if (w < 4){
        int pr = w*8 + sr8, pcs = sc8 ^ (pr & 7);
        gload16(KPg + (size_t)pr*NKx + k1 + pcs*4, KQb + (cur^1)*4096 + w*1024);
      }
    }
    __builtin_amdgcn_sched_barrier(0);

    // S^T = K . Q^T (log2 domain), single f32x16: k' = (r&3)+8*(r>>2)+4*hi
    f32x16 sT;
    #pragma unroll
    for (int r=0;r<16;++r) sT[r] = 0.f;
    __builtin_amdgcn_s_setprio(1);
    #pragma unroll
    for (int ds=0; ds<4; ++ds){
      int cc = (ds*2 + hi) ^ (q32 & 7);
      bf16x8 kf = *(const bf16x8*)(Kbase + cur*4096 + q32*128 + cc*16);
      sT = __builtin_amdgcn_mfma_f32_32x32x16_bf16(kf, qf[ds], sT, 0,0,0);
    }
    __builtin_amdgcn_s_setprio(0);

    // kq from shared Kpos LDS (swizzled read; same involution as staging)
    f32x4 kq[4];
    #pragma unroll
    for (int a=0;a<4;++a){
      int cc = (a*2 + hi) ^ (q32 & 7);
      kq[a] = *(const f32x4*)(KQb + cur*4096 + q32*128 + cc*16);
    }

    // + Kpos * qkp (log2 domain)
    #pragma unroll
    for (int r=0;r<16;++r)
      sT[r] = fmaf(kq[r>>2][r&3], qkp, sT[r]);

    // max tree via v_max3
    float t0 = fmax3(sT[0],  sT[1],  sT[2]);
    float t1 = fmax3(sT[3],  sT[4],  sT[5]);
    float t2 = fmax3(sT[6],  sT[7],  sT[8]);
    float t3 = fmax3(sT[9],  sT[10], sT[11]);
    float t4 = fmax3(sT[12], sT[13], sT[14]);
    float rm = fmax3(fmax3(t0, t1, t2), fmax3(t3, t4, sT[15]), m_i);
    rm = fmaxf(rm, __shfl_xor(rm, 32));

    if (!__all(rm <= m_i + 11.544f)){      // 2^11.544 = e^8 bound
      float al = fexp2(m_i - rm);
      m_i = rm;
      l_i *= al; a_i *= al;
      #pragma unroll
      for (int db=0; db<2; ++db)
        #pragma unroll
        for (int r=0;r<16;++r) accT[db][r] *= al;
    }

    // exp + tree-reduced row-sum and Kpos-weighted sum (4 parallel chains)
    float psq[4] = {0.f,0.f,0.f,0.f};
    float pkq[4] = {0.f,0.f,0.f,0.f};
    #pragma unroll
    for (int r=0;r<16;++r){
      float p = fexp2(sT[r] - m_i);
      sT[r] = p;
      psq[r&3] += p;
      pkq[r&3] = fmaf(p, kq[r>>2][r&3], pkq[r&3]);
    }
    float ps = (psq[0]+psq[1]) + (psq[2]+psq[3]);
    float pk = (pkq[0]+pkq[1]) + (pkq[2]+pkq[3]);
    ps += __shfl_xor(ps, 32);
    pk += __shfl_xor(pk, 32);
    l_i += ps; a_i += pk;

    // pack P to bf16 frags in-register (cvt_pk + permlane32_swap)
    union PW { unsigned int u[4]; bf16x8 v; } pa[2];
    {
      unsigned int w0 = cvtpk_bf16(sT[0],  sT[1]);
      unsigned int w1 = cvtpk_bf16(sT[2],  sT[3]);
      unsigned int w2 = cvtpk_bf16(sT[4],  sT[5]);
      unsigned int w3 = cvtpk_bf16(sT[6],  sT[7]);
      unsigned int w4 = cvtpk_bf16(sT[8],  sT[9]);
      unsigned int w5 = cvtpk_bf16(sT[10], sT[11]);
      unsigned int w6 = cvtpk_bf16(sT[12], sT[13]);
      unsigned int w7 = cvtpk_bf16(sT[14], sT[15]);
      plane32_swap(w0, w2);
      plane32_swap(w1, w3);
      plane32_swap(w4, w6);
      plane32_swap(w5, w7);
      pa[0].u[0]=w0; pa[0].u[1]=w1; pa[0].u[2]=w2; pa[0].u[3]=w3;
      pa[1].u[0]=w4; pa[1].u[1]=w5; pa[1].u[2]=w6; pa[1].u[3]=w7;
    }

    // O^T += V . P  (R9-verified V mapping for KVBLK=32)
    __builtin_amdgcn_s_setprio(1);
    #pragma unroll
    for (int c2=0; c2<2; ++c2){
      #pragma unroll
      for (int db=0; db<2; ++db){
        int row = db*32 + q32;
        int cc  = (c2*2 + hi) ^ ((row>>1) & 3);
        bf16x8 vf = *(const bf16x8*)(Vbase + cur*4096 + row*64 + cc*16);
        accT[db] = __builtin_amdgcn_mfma_f32_32x32x16_bf16(vf, pa[c2].v, accT[db], 0,0,0);
      }
    }
    __builtin_amdgcn_s_setprio(0);

    __syncthreads();
  }

  // epilogue: X = Qh + O/l + (akp/l)*vp ; d = db*32 + 8a + 4hi + c
  float inv = 1.0f / l_i;
  float aw  = a_i * inv;
  float* Xrow = X + ((size_t)(b*NQx + q0 + q32))*Dx + h*64;
  #pragma unroll
  for (int db=0; db<2; ++db){
    #pragma unroll
    for (int a2=0; a2<4; ++a2){
      int d0 = db*32 + a2*8 + hi*4;
      f32x4 vpv = *(const f32x4*)(vp + d0);
      ushort4 qh = *(const ushort4*)(Qrowp + d0);
      float4 o;
      o.x = fmaf(accT[db][a2*4+0], inv, bf2f(qh.x) + aw*vpv[0]);
      o.y = fmaf(accT[db][a2*4+1], inv, bf2f(qh.y) + aw*vpv[1]);
      o.z = fmaf(accT[db][a2*4+2], inv, bf2f(qh.z) + aw*vpv[2]);
      o.w = fmaf(accT[db][a2*4+3], inv, bf2f(qh.w) + aw*vpv[3]);
      *(float4*)(Xrow + d0) = o;
    }
  }
}

// ---------------------------------------------------------------------------
// Row LayerNorm over 512; optional f32 and/or bf16 outputs.
// ---------------------------------------------------------------------------
__global__ __launch_bounds__(256) void mab_ln2(
    const float* __restrict__ Xin, const float* __restrict__ g,
    const float* __restrict__ be, float* __restrict__ Yf, unsigned short* __restrict__ Yb)
{
  const int row = blockIdx.x;
  const int tid = threadIdx.x;
  const float* x = Xin + (size_t)row*Dx;
  float2 v = *(const float2*)(x + tid*2);
  float s  = v.x + v.y;
  float sq = fmaf(v.x,v.x, v.y*v.y);
  #pragma unroll
  for (int m=1; m<64; m<<=1){ s += __shfl_xor(s,m); sq += __shfl_xor(sq,m); }
  __shared__ float red[2][4];
  const int wid = tid>>6, lane = tid&63;
  if (lane==0){ red[0][wid]=s; red[1][wid]=sq; }
  __syncthreads();
  s  = red[0][0]+red[0][1]+red[0][2]+red[0][3];
  sq = red[1][0]+red[1][1]+red[1][2]+red[1][3];
  float mean = s*(1.0f/Dx);
  float var  = sq*(1.0f/Dx) - mean*mean;
  float rstd = rsqrtf(var + 1e-5f);
  float2 gg = *(const float2*)(g  + tid*2);
  float2 bb = *(const float2*)(be + tid*2);
  float2 o;
  o.x = (v.x-mean)*rstd*gg.x + bb.x;
  o.y = (v.y-mean)*rstd*gg.y + bb.y;
  if (Yf) *(float2*)(Yf + (size_t)row*Dx + tid*2) = o;
  if (Yb){
    ushort2 ob; ob.x = f2bf(o.x); ob.y = f2bf(o.y);
    *(ushort2*)(Yb + (size_t)row*Dx + tid*2) = ob;
  }
}

// ---------------------------------------------------------------------------
extern "C" void kernel_launch(void* const* d_in, const int* in_sizes, int n_in,
                              void* d_out, int out_size, void* d_ws, size_t ws_size,
                              hipStream_t stream)
{
  const float* Q    = (const float*)d_in[0];
  const float* K    = (const float*)d_in[1];
  const float* Kpos = (const float*)d_in[2];
  const float* Wq   = (const float*)d_in[3];
  const float* bq   = (const float*)d_in[4];
  const float* Wk   = (const float*)d_in[5];
  const float* bk   = (const float*)d_in[6];
  const float* Wv   = (const float*)d_in[7];
  const float* bv   = (const float*)d_in[8];
  const float* kp   = (const float*)d_in[9];
  const float* vp   = (const float*)d_in[10];
  const float* W0   = (const float*)d_in[11];
  const float* b0   = (const float*)d_in[12];
  const float* W1   = (const float*)d_in[13];
  const float* b1   = (const float*)d_in[14];
  const float* g0   = (const float*)d_in[15];
  const float* be0  = (const float*)d_in[16];
  const float* g1   = (const float*)d_in[17];
  const float* be1  = (const float*)d_in[18];
  float* out = (float*)d_out;
  char* wsb  = (char*)d_ws;

  const size_t MB = 1024*1024;
  unsigned short* Qp  = (unsigned short*)(wsb);          // 8 MiB bf16 [8192][512]
  unsigned short* Kp  = (unsigned short*)(wsb + 8*MB);   // pre-scaled (log2e/sqrt512)
  unsigned short* Vp  = (unsigned short*)(wsb + 16*MB);  // -> T1 after vt
  unsigned short* Vpt = (unsigned short*)(wsb + 24*MB);  // 8 MiB
  unsigned short* O0b = (unsigned short*)(wsb + 32*MB);  // 8 MiB bf16 post-LN0
  unsigned short* Wt  = (unsigned short*)(wsb + 40*MB);  // 2.5 MiB [5][512][512]
  unsigned short* T1  = Vp;                              // reuse (vt done)

  const float kscale = 0.044194173824159216f * 1.4426950408889634f; // log2e/sqrt(512)

  // weight transposes (Wq,Wk,Wv,W0,W1)
  mab_wt<<<dim3(8,8,5), 256, 0, stream>>>(Wq, Wk, Wv, W0, W1, Wt);
  // fused Q/K/V projections from f32 inputs (z=0,1,2)
  mab_gemm_proj<<<dim3(4,64,3), 256, 0, stream>>>(Q, K, Wt, bq, bk, bv, Qp, kscale);
  // V transpose to d-major
  mab_vt<<<dim3(32,8,4), 256, 0, stream>>>(Vp, Vpt);
  // fused attention v7 (all-heads block, LDS-shared Kpos, LDS-staged K/V)
  mab_attn7<<<dim3(64,4), 512, 0, stream>>>(Qp, Kp, Vpt, Kpos, kp, vp, out);
  // LN0 -> O0b (bf16 only; out still holds pre-LN X which is dead after this)
  mab_ln2<<<8192, 256, 0, stream>>>(out, g0, be0, nullptr, O0b);
  // T1 = relu(O0b @ W0 + b0)  (bf16 out)
  mab_gemm_mfma<<<dim3(4,64,1), 256, 0, stream>>>(
      O0b, Wt + (size_t)3*512*512, b0, nullptr, T1, nullptr, 1);
  // out = O0b + relu(T1 @ W1 + b1)  (f32 out)
  mab_gemm_mfma<<<dim3(4,64,1), 256, 0, stream>>>(
      T1, Wt + (size_t)4*512*512, b1, O0b, nullptr, out, 1);
  // final LN in-place
  mab_ln2<<<8192, 256, 0, stream>>>(out, g1, be1, out, nullptr);
}

// Round 14
// 196.135 us; speedup vs baseline: 1.4269x; 1.0565x over previous
//
#include <hip/hip_runtime.h>
#include <math.h>

// Problem constants (MAB_50921132261692)
#define Bx  4
#define NQx 2048
#define NKx 2048
#define Dx  512
#define Hx  8

typedef __attribute__((ext_vector_type(8))) __bf16 bf16x8;
typedef __attribute__((ext_vector_type(4))) float f32x4;
typedef __attribute__((ext_vector_type(16))) float f32x16;

typedef const __attribute__((address_space(1))) unsigned int* gas_ptr;
typedef __attribute__((address_space(3))) unsigned int* lds_ptr;

__device__ __forceinline__ void gload16(const void* g, void* l){
  __builtin_amdgcn_global_load_lds((gas_ptr)g, (lds_ptr)l, 16, 0, 0);
}

__device__ __forceinline__ unsigned short f2bf(float f){
  union { float f; unsigned int u; } v; v.f = f;
  unsigned int r = (v.u + 0x7FFFu + ((v.u >> 16) & 1u)) >> 16;
  return (unsigned short)r;
}
__device__ __forceinline__ float bf2f(unsigned short u){
  union { unsigned int u; float f; } v; v.u = ((unsigned int)u) << 16; return v.f;
}
__device__ __forceinline__ unsigned int cvtpk_bf16(float a, float b){
  unsigned int d;
  asm("v_cvt_pk_bf16_f32 %0, %1, %2" : "=v"(d) : "v"(a), "v"(b));
  return d;
}
__device__ __forceinline__ void plane32_swap(unsigned int& a, unsigned int& b){
  asm("v_permlane32_swap_b32 %0, %1" : "+v"(a), "+v"(b));
}
__device__ __forceinline__ float fexp2(float x){           // D = 2^x
  float d; asm("v_exp_f32 %0, %1" : "=v"(d) : "v"(x)); return d;
}
__device__ __forceinline__ float fmax3(float a, float b, float c){
  float d; asm("v_max3_f32 %0, %1, %2, %3" : "=v"(d) : "v"(a), "v"(b), "v"(c)); return d;
}

// ---------------------------------------------------------------------------
// Transpose + convert 5 weights [512][512] f32 -> Wt bf16 [z][N=512][K=512].
// ---------------------------------------------------------------------------
__global__ __launch_bounds__(256) void mab_wt(
    const float* __restrict__ Wq, const float* __restrict__ Wk, const float* __restrict__ Wv,
    const float* __restrict__ W0, const float* __restrict__ W1,
    unsigned short* __restrict__ Wt)
{
  __shared__ unsigned short T[64][72];
  const int z = blockIdx.z;
  const float* W = (z==0)?Wq:(z==1)?Wk:(z==2)?Wv:(z==3)?W0:W1;
  unsigned short* O = Wt + (size_t)z*512*512;
  const int k0 = blockIdx.x*64, n0 = blockIdx.y*64;
  const int tid = threadIdx.x;
  #pragma unroll
  for (int i=0;i<4;++i){
    int id = tid + i*256;          // 1024 = 64 rows x 16 float4
    int r = id>>4, c4 = id&15;
    float4 v = *(const float4*)(W + (size_t)(k0+r)*512 + n0 + c4*4);
    ushort4 o; o.x=f2bf(v.x); o.y=f2bf(v.y); o.z=f2bf(v.z); o.w=f2bf(v.w);
    *(ushort4*)&T[r][c4*4] = o;
  }
  __syncthreads();
  #pragma unroll
  for (int i=0;i<2;++i){
    int id = tid + i*256;          // 512 = 64 out-rows x 8 chunks
    int c = id>>3, r8 = id&7;
    union { unsigned short u[8]; uint4 v; } o;
    #pragma unroll
    for (int j=0;j<8;++j) o.u[j] = T[r8*8+j][c];
    *(uint4*)(O + (size_t)(n0+c)*512 + k0 + r8*8) = o.v;
  }
}

// ---------------------------------------------------------------------------
// Transpose Vp bf16 [B*NK][512] -> Vpt [B][512][NK] (d-major per batch).
// ---------------------------------------------------------------------------
__global__ __launch_bounds__(256) void mab_vt(
    const unsigned short* __restrict__ Vp, unsigned short* __restrict__ Vpt)
{
  __shared__ unsigned short T[64][72];
  const int r0 = blockIdx.x*64;   // k within batch
  const int c0 = blockIdx.y*64;   // d
  const int b  = blockIdx.z;
  const int tid = threadIdx.x;
  #pragma unroll
  for (int i=0;i<2;++i){
    int id = tid + i*256;          // 512 = 64 rows x 8 chunks(8 bf16)
    int r = id>>3, c8 = id&7;
    *(uint4*)&T[r][c8*8] = *(const uint4*)(Vp + (size_t)(b*NKx + r0+r)*512 + c0 + c8*8);
  }
  __syncthreads();
  #pragma unroll
  for (int i=0;i<2;++i){
    int id = tid + i*256;
    int c = id>>3, r8 = id&7;
    union { unsigned short u[8]; uint4 v; } o;
    #pragma unroll
    for (int j=0;j<8;++j) o.u[j] = T[r8*8+j][c];
    *(uint4*)(Vpt + ((size_t)(b*512) + c0 + c)*NKx + r0 + r8*8) = o.v;
  }
}

// ---------------------------------------------------------------------------
// QKV projection GEMM with fused f32->bf16 A conversion.
// ---------------------------------------------------------------------------
__global__ __launch_bounds__(256) void mab_gemm_proj(
    const float* __restrict__ Qf, const float* __restrict__ Kf,
    const unsigned short* __restrict__ Wt,
    const float* __restrict__ bq, const float* __restrict__ bk, const float* __restrict__ bv,
    unsigned short* __restrict__ Cb, float kscale)
{
  __shared__ unsigned short As[128][64];
  __shared__ unsigned short Bs[128][64];
  const int z = blockIdx.z;
  const float* A = (z==0) ? Qf : Kf;
  const unsigned short* W = Wt + (size_t)z*512*512;
  const float* bias = (z==0)?bq:((z==1)?bk:bv);
  const float sc = (z==1) ? kscale : 1.0f;
  const int m0 = blockIdx.y*128, n0 = blockIdx.x*128;
  const int tid = threadIdx.x, w = tid>>6, lane = tid&63, g = lane>>4, q16 = lane&15;
  const int wr = w>>1, wc = w&1;

  f32x4 acc[4][4];
  #pragma unroll
  for (int m=0;m<4;++m)
    #pragma unroll
    for (int n=0;n<4;++n) acc[m][n] = (f32x4){0.f,0.f,0.f,0.f};

  float4 areg[8];
  #pragma unroll
  for (int i=0;i<8;++i){
    int id = i*256 + tid, row = id>>4, qc = id&15;
    areg[i] = *(const float4*)(A + (size_t)(m0+row)*512 + qc*4);
  }

  for (int k0 = 0; k0 < 512; k0 += 64){
    __syncthreads();
    #pragma unroll
    for (int i=0;i<8;++i){
      int id = i*256 + tid, row = id>>4, qc = id&15;
      unsigned int lo = cvtpk_bf16(areg[i].x, areg[i].y);
      unsigned int hi = cvtpk_bf16(areg[i].z, areg[i].w);
      unsigned int* dst = (unsigned int*)((char*)&As[0][0] + row*128
                          + ((qc>>1) ^ (row&7))*16 + (qc&1)*8);
      dst[0] = lo; dst[1] = hi;
    }
    #pragma unroll
    for (int i=0;i<4;++i){
      int o   = (w*4 + i)*1024 + lane*16;
      int row = o >> 7;
      int c   = (o >> 4) & 7;
      int cs  = c ^ (row & 7);
      gload16(W + (size_t)(n0+row)*512 + k0 + cs*8, (char*)&Bs[0][0] + (w*4+i)*1024);
    }
    __syncthreads();
    if (k0 + 64 < 512){
      #pragma unroll
      for (int i=0;i<8;++i){
        int id = i*256 + tid, row = id>>4, qc = id&15;
        areg[i] = *(const float4*)(A + (size_t)(m0+row)*512 + (k0+64) + qc*4);
      }
    }
    #pragma unroll
    for (int ks=0;ks<2;++ks){
      bf16x8 af[4], bfr[4];
      #pragma unroll
      for (int m=0;m<4;++m){
        int row = wr*64 + m*16 + q16;
        int c   = (ks*4 + g) ^ (row & 7);
        af[m] = *(const bf16x8*)((const char*)&As[0][0] + row*128 + c*16);
      }
      #pragma unroll
      for (int n=0;n<4;++n){
        int row = wc*64 + n*16 + q16;
        int c   = (ks*4 + g) ^ (row & 7);
        bfr[n] = *(const bf16x8*)((const char*)&Bs[0][0] + row*128 + c*16);
      }
      #pragma unroll
      for (int m=0;m<4;++m)
        #pragma unroll
        for (int n=0;n<4;++n)
          acc[m][n] = __builtin_amdgcn_mfma_f32_16x16x32_bf16(af[m], bfr[n], acc[m][n], 0,0,0);
    }
  }

  const size_t ZS = (size_t)8192*512;
  #pragma unroll
  for (int m=0;m<4;++m){
    const int rowl = wr*64 + m*16 + g*4;
    #pragma unroll
    for (int n=0;n<4;++n){
      const int col = n0 + wc*64 + n*16 + q16;
      const float bv2 = bias[col];
      #pragma unroll
      for (int r=0;r<4;++r){
        float v = (acc[m][n][r] + bv2) * sc;
        Cb[(size_t)z*ZS + (size_t)(m0 + rowl + r)*512 + col] = f2bf(v);
      }
    }
  }
}

// ---------------------------------------------------------------------------
// bf16-A MFMA GEMM for the MLP: C = op(A @ W^T + bias) (+ bf16 res)
// ---------------------------------------------------------------------------
__global__ __launch_bounds__(256) void mab_gemm_mfma(
    const unsigned short* __restrict__ A, const unsigned short* __restrict__ W,
    const float* __restrict__ bias, const unsigned short* __restrict__ resb,
    unsigned short* __restrict__ Cb, float* __restrict__ Cf, int relu)
{
  __shared__ unsigned short As[128][64];
  __shared__ unsigned short Bs[128][64];
  const int m0 = blockIdx.y*128, n0 = blockIdx.x*128;
  const int tid = threadIdx.x, w = tid>>6, lane = tid&63, g = lane>>4, q16 = lane&15;
  const int wr = w>>1, wc = w&1;

  f32x4 acc[4][4];
  #pragma unroll
  for (int m=0;m<4;++m)
    #pragma unroll
    for (int n=0;n<4;++n) acc[m][n] = (f32x4){0.f,0.f,0.f,0.f};

  for (int k0 = 0; k0 < 512; k0 += 64){
    __syncthreads();
    #pragma unroll
    for (int i=0;i<4;++i){
      int o   = (w*4 + i)*1024 + lane*16;
      int row = o >> 7;
      int c   = (o >> 4) & 7;
      int cs  = c ^ (row & 7);
      gload16(A + (size_t)(m0+row)*512 + k0 + cs*8, (char*)&As[0][0] + (w*4+i)*1024);
      gload16(W + (size_t)(n0+row)*512 + k0 + cs*8, (char*)&Bs[0][0] + (w*4+i)*1024);
    }
    __syncthreads();
    #pragma unroll
    for (int ks=0;ks<2;++ks){
      bf16x8 af[4], bfr[4];
      #pragma unroll
      for (int m=0;m<4;++m){
        int row = wr*64 + m*16 + q16;
        int c   = (ks*4 + g) ^ (row & 7);
        af[m] = *(const bf16x8*)((const char*)&As[0][0] + row*128 + c*16);
      }
      #pragma unroll
      for (int n=0;n<4;++n){
        int row = wc*64 + n*16 + q16;
        int c   = (ks*4 + g) ^ (row & 7);
        bfr[n] = *(const bf16x8*)((const char*)&Bs[0][0] + row*128 + c*16);
      }
      #pragma unroll
      for (int m=0;m<4;++m)
        #pragma unroll
        for (int n=0;n<4;++n)
          acc[m][n] = __builtin_amdgcn_mfma_f32_16x16x32_bf16(af[m], bfr[n], acc[m][n], 0,0,0);
    }
  }

  #pragma unroll
  for (int m=0;m<4;++m){
    const int rowl = wr*64 + m*16 + g*4;
    #pragma unroll
    for (int n=0;n<4;++n){
      const int col = n0 + wc*64 + n*16 + q16;
      const float bv = bias[col];
      #pragma unroll
      for (int r=0;r<4;++r){
        float v = acc[m][n][r] + bv;
        if (relu) v = fmaxf(v, 0.f);
        size_t off = (size_t)(m0 + rowl + r)*512 + col;
        if (resb) v += bf2f(resb[off]);
        if (Cb) Cb[off] = f2bf(v);
        if (Cf) Cf[off] = v;
      }
    }
  }
}

// ---------------------------------------------------------------------------
// MFMA flash attention v8: v7 (all-heads block, LDS K/V/Kpos) + 1-DEEP
// SOFTWARE PIPELINE + FUSED LN0.
// Pipeline: iter t issues stage(t+1) and QK^T(t) (MFMA), then runs the
// softmax-finish + PV of tile t-1 (VALU/MFMA on独立 regs) — the compiler
// interleaves the independent VALU into the chained-MFMA stalls. V/Kpos of
// tile t are copied LDS->regs in iter t (also required: the other LDS half
// is re-staged next half-iter). Two register state sets (sT/kq/vf) rotate.
// Epilogue: residual + value-bias, then LN0 fused via cross-wave LDS reduce
// (block owns full 512-d rows); writes bf16 O0b directly.
// Kp pre-scaled by log2e/sqrt(512). Vpt d-major [B][512][NK].
// ---------------------------------------------------------------------------
__global__ __launch_bounds__(512, 2) void mab_attn8(
    const unsigned short* __restrict__ Qp, const unsigned short* __restrict__ Kp,
    const unsigned short* __restrict__ Vpt,
    const float* __restrict__ Kpos, const float* __restrict__ kp, const float* __restrict__ vp,
    const float* __restrict__ g0, const float* __restrict__ be0,
    unsigned short* __restrict__ O0b)
{
  __shared__ __align__(16) char pool[139264];
  // [0,65536):       K per wave: w*8192 + buf*4096  (32 k x 64 d bf16, swz)
  // [65536,131072):  V per wave: w*8192 + buf*4096  (64 d x 32 k bf16, swz)
  // [131072,139264): Kpos: buf*4096                 (32 q x 32 k f32, swz)
  // epilogue: pool[0..2KB) reused as float lnred[32][8][2]

  const int qt = blockIdx.x;
  const int b  = blockIdx.y;
  const int q0 = qt*32;
  const int tid = threadIdx.x, w = tid>>6, lane = tid&63;
  const int q32 = lane & 31, hi = lane >> 5;
  const int h = w;

  char* Kbase = pool + w*8192;
  char* Vbase = pool + 65536 + w*8192;
  char* KQb   = pool + 131072;

  const unsigned short* Kg = Kp + ((size_t)b*NKx)*Dx + h*64;
  const unsigned short* Vg = Vpt + ((size_t)(b*512) + h*64)*NKx;
  const float* KPg = Kpos + (size_t)b*NQx*NKx + (size_t)q0*NKx;   // [32][2048]

  const int sr8 = lane>>3, sc8 = lane&7;   // K/Kpos staging: 8 rows x 8 chunks
  const int sr4 = lane>>2, sc4 = lane&3;   // V staging: 16 rows x 4 chunks

  auto STAGE = [&](int t){
    if (t >= 64) return;
    const int buf = t & 1;
    const int k1 = t*32;
    #pragma unroll
    for (int i=0;i<4;++i){
      int kr = i*8 + sr8, kcs = sc8 ^ (kr & 7);
      gload16(Kg + (size_t)(k1 + kr)*Dx + kcs*8, Kbase + buf*4096 + i*1024);
      int vr = i*16 + sr4, vcs = sc4 ^ ((vr>>1) & 3);
      gload16(Vg + (size_t)vr*NKx + k1 + vcs*8, Vbase + buf*4096 + i*1024);
    }
    if (w < 4){
      int pr = w*8 + sr8, pcs = sc8 ^ (pr & 7);
      gload16(KPg + (size_t)pr*NKx + k1 + pcs*4, KQb + buf*4096 + w*1024);
    }
  };

  auto LOADREGS = [&](int buf, f32x4 (&kq)[4], bf16x8 (&vf)[2][2]){
    #pragma unroll
    for (int a=0;a<4;++a){
      int cc = (a*2 + hi) ^ (q32 & 7);
      kq[a] = *(const f32x4*)(KQb + buf*4096 + q32*128 + cc*16);
    }
    #pragma unroll
    for (int c2=0;c2<2;++c2)
      #pragma unroll
      for (int db=0;db<2;++db){
        int row = db*32 + q32;
        int cc  = (c2*2 + hi) ^ ((row>>1) & 3);
        vf[c2][db] = *(const bf16x8*)(Vbase + buf*4096 + row*64 + cc*16);
      }
  };

  // Q frags direct from global (L2-resident)
  const unsigned short* Qrowp = Qp + ((size_t)(b*NQx + q0 + q32))*Dx + h*64;
  bf16x8 qf[4];
  #pragma unroll
  for (int ds=0; ds<4; ++ds)
    qf[ds] = *(const bf16x8*)(Qrowp + ds*16 + hi*8);

  auto QKT = [&](int buf, f32x16& sT){
    #pragma unroll
    for (int r=0;r<16;++r) sT[r] = 0.f;
    #pragma unroll
    for (int ds=0; ds<4; ++ds){
      int cc = (ds*2 + hi) ^ (q32 & 7);
      bf16x8 kf = *(const bf16x8*)(Kbase + buf*4096 + q32*128 + cc*16);
      sT = __builtin_amdgcn_mfma_f32_32x32x16_bf16(kf, qf[ds], sT, 0,0,0);
    }
  };

  // qkp = (Qh . kp) * log2e for own q-row
  float qkp = 0.f;
  #pragma unroll
  for (int ds=0; ds<4; ++ds){
    union { bf16x8 v; unsigned short u[8]; } qa; qa.v = qf[ds];
    #pragma unroll
    for (int j=0;j<8;++j)
      qkp = fmaf(bf2f(qa.u[j]), kp[ds*16 + hi*8 + j], qkp);
  }
  qkp += __shfl_xor(qkp, 32);
  qkp *= 1.4426950408889634f;

  float m_i = -1e30f, l_i = 0.f, a_i = 0.f;
  f32x16 accT[2];
  #pragma unroll
  for (int db=0; db<2; ++db)
    #pragma unroll
    for (int r=0;r<16;++r) accT[db][r] = 0.f;

  auto FINISH = [&](f32x16& sT, f32x4 (&kq)[4], bf16x8 (&vf)[2][2]){
    // + Kpos * qkp (log2 domain); k' = (r&3) + 8*(r>>2) + 4*hi
    #pragma unroll
    for (int r=0;r<16;++r)
      sT[r] = fmaf(kq[r>>2][r&3], qkp, sT[r]);
    // max tree via v_max3
    float t0 = fmax3(sT[0],  sT[1],  sT[2]);
    float t1 = fmax3(sT[3],  sT[4],  sT[5]);
    float t2 = fmax3(sT[6],  sT[7],  sT[8]);
    float t3 = fmax3(sT[9],  sT[10], sT[11]);
    float t4 = fmax3(sT[12], sT[13], sT[14]);
    float rm = fmax3(fmax3(t0, t1, t2), fmax3(t3, t4, sT[15]), m_i);
    rm = fmaxf(rm, __shfl_xor(rm, 32));
    if (!__all(rm <= m_i + 11.544f)){      // 2^11.544 = e^8 bound
      float al = fexp2(m_i - rm);
      m_i = rm;
      l_i *= al; a_i *= al;
      #pragma unroll
      for (int db=0; db<2; ++db)
        #pragma unroll
        for (int r=0;r<16;++r) accT[db][r] *= al;
    }
    // exp + tree-reduced row-sum and Kpos-weighted sum
    float psq[4] = {0.f,0.f,0.f,0.f};
    float pkq[4] = {0.f,0.f,0.f,0.f};
    #pragma unroll
    for (int r=0;r<16;++r){
      float p = fexp2(sT[r] - m_i);
      sT[r] = p;
      psq[r&3] += p;
      pkq[r&3] = fmaf(p, kq[r>>2][r&3], pkq[r&3]);
    }
    float ps = (psq[0]+psq[1]) + (psq[2]+psq[3]);
    float pk = (pkq[0]+pkq[1]) + (pkq[2]+pkq[3]);
    ps += __shfl_xor(ps, 32);
    pk += __shfl_xor(pk, 32);
    l_i += ps; a_i += pk;
    // pack P to bf16 frags in-register (cvt_pk + permlane32_swap)
    union PW { unsigned int u[4]; bf16x8 v; } pa[2];
    {
      unsigned int w0 = cvtpk_bf16(sT[0],  sT[1]);
      unsigned int w1 = cvtpk_bf16(sT[2],  sT[3]);
      unsigned int w2 = cvtpk_bf16(sT[4],  sT[5]);
      unsigned int w3 = cvtpk_bf16(sT[6],  sT[7]);
      unsigned int w4 = cvtpk_bf16(sT[8],  sT[9]);
      unsigned int w5 = cvtpk_bf16(sT[10], sT[11]);
      unsigned int w6 = cvtpk_bf16(sT[12], sT[13]);
      unsigned int w7 = cvtpk_bf16(sT[14], sT[15]);
      plane32_swap(w0, w2);
      plane32_swap(w1, w3);
      plane32_swap(w4, w6);
      plane32_swap(w5, w7);
      pa[0].u[0]=w0; pa[0].u[1]=w1; pa[0].u[2]=w2; pa[0].u[3]=w3;
      pa[1].u[0]=w4; pa[1].u[1]=w5; pa[1].u[2]=w6; pa[1].u[3]=w7;
    }
    // O^T += V . P  (V frags already in registers)
    __builtin_amdgcn_s_setprio(1);
    #pragma unroll
    for (int c2=0; c2<2; ++c2){
      #pragma unroll
      for (int db=0; db<2; ++db)
        accT[db] = __builtin_amdgcn_mfma_f32_32x32x16_bf16(vf[c2][db], pa[c2].v, accT[db], 0,0,0);
    }
    __builtin_amdgcn_s_setprio(0);
  };

  // ---- prologue ----
  STAGE(0);
  __syncthreads();

  f32x16 sT0, sT1;
  f32x4 kq0[4], kq1[4];
  bf16x8 vf0[2][2], vf1[2][2];

  STAGE(1);
  __builtin_amdgcn_sched_barrier(0);
  LOADREGS(0, kq0, vf0);
  QKT(0, sT0);
  __syncthreads();

  // ---- pipelined main loop: 64 tiles of 32 k ----
  for (int t = 1; t < 64; t += 2){
    // first half: fill set1 (tile t, buf1); finish set0 (tile t-1)
    STAGE(t+1);
    __builtin_amdgcn_sched_barrier(0);
    LOADREGS(1, kq1, vf1);
    QKT(1, sT1);
    FINISH(sT0, kq0, vf0);
    __syncthreads();
    // second half: fill set0 (tile t+1, buf0); finish set1 (tile t)
    if (t+1 < 64){
      STAGE(t+2);
      __builtin_amdgcn_sched_barrier(0);
      LOADREGS(0, kq0, vf0);
      QKT(0, sT0);
    }
    FINISH(sT1, kq1, vf1);
    __syncthreads();
  }

  // ---- epilogue: residual + value-bias, then fused LN0 ----
  float inv = 1.0f / l_i;
  float aw  = a_i * inv;
  float s = 0.f, sq = 0.f;
  #pragma unroll
  for (int db=0; db<2; ++db){
    #pragma unroll
    for (int a2=0; a2<4; ++a2){
      int d0 = db*32 + a2*8 + hi*4;
      f32x4 vpv = *(const f32x4*)(vp + d0);
      ushort4 qh = *(const ushort4*)(Qrowp + d0);
      float o0 = fmaf(accT[db][a2*4+0], inv, bf2f(qh.x) + aw*vpv[0]);
      float o1 = fmaf(accT[db][a2*4+1], inv, bf2f(qh.y) + aw*vpv[1]);
      float o2 = fmaf(accT[db][a2*4+2], inv, bf2f(qh.z) + aw*vpv[2]);
      float o3 = fmaf(accT[db][a2*4+3], inv, bf2f(qh.w) + aw*vpv[3]);
      accT[db][a2*4+0]=o0; accT[db][a2*4+1]=o1;
      accT[db][a2*4+2]=o2; accT[db][a2*4+3]=o3;
      s += (o0+o1)+(o2+o3);
      sq = fmaf(o0,o0, fmaf(o1,o1, fmaf(o2,o2, fmaf(o3,o3, sq))));
    }
  }
  s  += __shfl_xor(s, 32);
  sq += __shfl_xor(sq, 32);
  float* lnred = (float*)pool;     // [32 q][8 h][2], K/V LDS dead after last barrier
  if (hi == 0){
    lnred[(q32*8 + w)*2 + 0] = s;
    lnred[(q32*8 + w)*2 + 1] = sq;
  }
  __syncthreads();
  float S = 0.f, SQ = 0.f;
  #pragma unroll
  for (int h2=0; h2<8; ++h2){
    S  += lnred[(q32*8 + h2)*2 + 0];
    SQ += lnred[(q32*8 + h2)*2 + 1];
  }
  float mean = S*(1.0f/512.0f);
  float var  = SQ*(1.0f/512.0f) - mean*mean;
  float rstd = rsqrtf(var + 1e-5f);
  unsigned short* Orow = O0b + ((size_t)(b*NQx + q0 + q32))*Dx + h*64;
  #pragma unroll
  for (int db=0; db<2; ++db){
    #pragma unroll
    for (int a2=0; a2<4; ++a2){
      int d0 = db*32 + a2*8 + hi*4;
      f32x4 gg = *(const f32x4*)(g0  + h*64 + d0);
      f32x4 bb = *(const f32x4*)(be0 + h*64 + d0);
      float y0 = (accT[db][a2*4+0]-mean)*rstd*gg[0] + bb[0];
      float y1 = (accT[db][a2*4+1]-mean)*rstd*gg[1] + bb[1];
      float y2 = (accT[db][a2*4+2]-mean)*rstd*gg[2] + bb[2];
      float y3 = (accT[db][a2*4+3]-mean)*rstd*gg[3] + bb[3];
      uint2 pk2;
      pk2.x = cvtpk_bf16(y0, y1);
      pk2.y = cvtpk_bf16(y2, y3);
      *(uint2*)(Orow + d0) = pk2;
    }
  }
}

// ---------------------------------------------------------------------------
// Row LayerNorm over 512 (final), f32 in/out.
// ---------------------------------------------------------------------------
__global__ __launch_bounds__(256) void mab_ln2(
    const float* __restrict__ Xin, const float* __restrict__ g,
    const float* __restrict__ be, float* __restrict__ Yf)
{
  const int row = blockIdx.x;
  const int tid = threadIdx.x;
  const float* x = Xin + (size_t)row*Dx;
  float2 v = *(const float2*)(x + tid*2);
  float s  = v.x + v.y;
  float sq = fmaf(v.x,v.x, v.y*v.y);
  #pragma unroll
  for (int m=1; m<64; m<<=1){ s += __shfl_xor(s,m); sq += __shfl_xor(sq,m); }
  __shared__ float red[2][4];
  const int wid = tid>>6, lane = tid&63;
  if (lane==0){ red[0][wid]=s; red[1][wid]=sq; }
  __syncthreads();
  s  = red[0][0]+red[0][1]+red[0][2]+red[0][3];
  sq = red[1][0]+red[1][1]+red[1][2]+red[1][3];
  float mean = s*(1.0f/Dx);
  float var  = sq*(1.0f/Dx) - mean*mean;
  float rstd = rsqrtf(var + 1e-5f);
  float2 gg = *(const float2*)(g  + tid*2);
  float2 bb = *(const float2*)(be + tid*2);
  float2 o;
  o.x = (v.x-mean)*rstd*gg.x + bb.x;
  o.y = (v.y-mean)*rstd*gg.y + bb.y;
  *(float2*)(Yf + (size_t)row*Dx + tid*2) = o;
}

// ---------------------------------------------------------------------------
extern "C" void kernel_launch(void* const* d_in, const int* in_sizes, int n_in,
                              void* d_out, int out_size, void* d_ws, size_t ws_size,
                              hipStream_t stream)
{
  const float* Q    = (const float*)d_in[0];
  const float* K    = (const float*)d_in[1];
  const float* Kpos = (const float*)d_in[2];
  const float* Wq   = (const float*)d_in[3];
  const float* bq   = (const float*)d_in[4];
  const float* Wk   = (const float*)d_in[5];
  const float* bk   = (const float*)d_in[6];
  const float* Wv   = (const float*)d_in[7];
  const float* bv   = (const float*)d_in[8];
  const float* kp   = (const float*)d_in[9];
  const float* vp   = (const float*)d_in[10];
  const float* W0   = (const float*)d_in[11];
  const float* b0   = (const float*)d_in[12];
  const float* W1   = (const float*)d_in[13];
  const float* b1   = (const float*)d_in[14];
  const float* g0   = (const float*)d_in[15];
  const float* be0  = (const float*)d_in[16];
  const float* g1   = (const float*)d_in[17];
  const float* be1  = (const float*)d_in[18];
  float* out = (float*)d_out;
  char* wsb  = (char*)d_ws;

  const size_t MB = 1024*1024;
  unsigned short* Qp  = (unsigned short*)(wsb);          // 8 MiB bf16 [8192][512]
  unsigned short* Kp  = (unsigned short*)(wsb + 8*MB);   // pre-scaled (log2e/sqrt512)
  unsigned short* Vp  = (unsigned short*)(wsb + 16*MB);  // -> T1 after vt
  unsigned short* Vpt = (unsigned short*)(wsb + 24*MB);  // 8 MiB
  unsigned short* O0b = (unsigned short*)(wsb + 32*MB);  // 8 MiB bf16 post-LN0
  unsigned short* Wt  = (unsigned short*)(wsb + 40*MB);  // 2.5 MiB [5][512][512]
  unsigned short* T1  = Vp;                              // reuse (vt done)

  const float kscale = 0.044194173824159216f * 1.4426950408889634f; // log2e/sqrt(512)

  // weight transposes (Wq,Wk,Wv,W0,W1)
  mab_wt<<<dim3(8,8,5), 256, 0, stream>>>(Wq, Wk, Wv, W0, W1, Wt);
  // fused Q/K/V projections from f32 inputs (z=0,1,2)
  mab_gemm_proj<<<dim3(4,64,3), 256, 0, stream>>>(Q, K, Wt, bq, bk, bv, Qp, kscale);
  // V transpose to d-major
  mab_vt<<<dim3(32,8,4), 256, 0, stream>>>(Vp, Vpt);
  // fused attention v8 (pipelined, all-heads block, fused LN0) -> O0b bf16
  mab_attn8<<<dim3(64,4), 512, 0, stream>>>(Qp, Kp, Vpt, Kpos, kp, vp, g0, be0, O0b);
  // T1 = relu(O0b @ W0 + b0)  (bf16 out)
  mab_gemm_mfma<<<dim3(4,64,1), 256, 0, stream>>>(
      O0b, Wt + (size_t)3*512*512, b0, nullptr, T1, nullptr, 1);
  // out = O0b + relu(T1 @ W1 + b1)  (f32 out)
  mab_gemm_mfma<<<dim3(4,64,1), 256, 0, stream>>>(
      T1, Wt + (size_t)4*512*512, b1, O0b, nullptr, out, 1);
  // final LN in-place
  mab_ln2<<<8192, 256, 0, stream>>>(out, g1, be1, out);
}

// Round 15
// 183.869 us; speedup vs baseline: 1.5221x; 1.0667x over previous
//
#include <hip/hip_runtime.h>
#include <math.h>

// Problem constants (MAB_50921132261692)
#define Bx  4
#define NQx 2048
#define NKx 2048
#define Dx  512
#define Hx  8

typedef __attribute__((ext_vector_type(8))) __bf16 bf16x8;
typedef __attribute__((ext_vector_type(4))) float f32x4;
typedef __attribute__((ext_vector_type(16))) float f32x16;

typedef const __attribute__((address_space(1))) unsigned int* gas_ptr;
typedef __attribute__((address_space(3))) unsigned int* lds_ptr;

__device__ __forceinline__ void gload16(const void* g, void* l){
  __builtin_amdgcn_global_load_lds((gas_ptr)g, (lds_ptr)l, 16, 0, 0);
}

__device__ __forceinline__ unsigned short f2bf(float f){
  union { float f; unsigned int u; } v; v.f = f;
  unsigned int r = (v.u + 0x7FFFu + ((v.u >> 16) & 1u)) >> 16;
  return (unsigned short)r;
}
__device__ __forceinline__ float bf2f(unsigned short u){
  union { unsigned int u; float f; } v; v.u = ((unsigned int)u) << 16; return v.f;
}
__device__ __forceinline__ unsigned int cvtpk_bf16(float a, float b){
  unsigned int d;
  asm("v_cvt_pk_bf16_f32 %0, %1, %2" : "=v"(d) : "v"(a), "v"(b));
  return d;
}
__device__ __forceinline__ void plane32_swap(unsigned int& a, unsigned int& b){
  asm("v_permlane32_swap_b32 %0, %1" : "+v"(a), "+v"(b));
}
__device__ __forceinline__ float fexp2(float x){           // D = 2^x
  float d; asm("v_exp_f32 %0, %1" : "=v"(d) : "v"(x)); return d;
}
__device__ __forceinline__ float fmax3(float a, float b, float c){
  float d; asm("v_max3_f32 %0, %1, %2, %3" : "=v"(d) : "v"(a), "v"(b), "v"(c)); return d;
}

// ---------------------------------------------------------------------------
// Transpose + convert 5 weights [512][512] f32 -> Wt bf16 [z][N=512][K=512].
// ---------------------------------------------------------------------------
__global__ __launch_bounds__(256) void mab_wt(
    const float* __restrict__ Wq, const float* __restrict__ Wk, const float* __restrict__ Wv,
    const float* __restrict__ W0, const float* __restrict__ W1,
    unsigned short* __restrict__ Wt)
{
  __shared__ unsigned short T[64][72];
  const int z = blockIdx.z;
  const float* W = (z==0)?Wq:(z==1)?Wk:(z==2)?Wv:(z==3)?W0:W1;
  unsigned short* O = Wt + (size_t)z*512*512;
  const int k0 = blockIdx.x*64, n0 = blockIdx.y*64;
  const int tid = threadIdx.x;
  #pragma unroll
  for (int i=0;i<4;++i){
    int id = tid + i*256;          // 1024 = 64 rows x 16 float4
    int r = id>>4, c4 = id&15;
    float4 v = *(const float4*)(W + (size_t)(k0+r)*512 + n0 + c4*4);
    ushort4 o; o.x=f2bf(v.x); o.y=f2bf(v.y); o.z=f2bf(v.z); o.w=f2bf(v.w);
    *(ushort4*)&T[r][c4*4] = o;
  }
  __syncthreads();
  #pragma unroll
  for (int i=0;i<2;++i){
    int id = tid + i*256;          // 512 = 64 out-rows x 8 chunks
    int c = id>>3, r8 = id&7;
    union { unsigned short u[8]; uint4 v; } o;
    #pragma unroll
    for (int j=0;j<8;++j) o.u[j] = T[r8*8+j][c];
    *(uint4*)(O + (size_t)(n0+c)*512 + k0 + r8*8) = o.v;
  }
}

// ---------------------------------------------------------------------------
// Transpose Vp bf16 [B*NK][512] -> Vpt [B][512][NK] (d-major per batch).
// ---------------------------------------------------------------------------
__global__ __launch_bounds__(256) void mab_vt(
    const unsigned short* __restrict__ Vp, unsigned short* __restrict__ Vpt)
{
  __shared__ unsigned short T[64][72];
  const int r0 = blockIdx.x*64;   // k within batch
  const int c0 = blockIdx.y*64;   // d
  const int b  = blockIdx.z;
  const int tid = threadIdx.x;
  #pragma unroll
  for (int i=0;i<2;++i){
    int id = tid + i*256;          // 512 = 64 rows x 8 chunks(8 bf16)
    int r = id>>3, c8 = id&7;
    *(uint4*)&T[r][c8*8] = *(const uint4*)(Vp + (size_t)(b*NKx + r0+r)*512 + c0 + c8*8);
  }
  __syncthreads();
  #pragma unroll
  for (int i=0;i<2;++i){
    int id = tid + i*256;
    int c = id>>3, r8 = id&7;
    union { unsigned short u[8]; uint4 v; } o;
    #pragma unroll
    for (int j=0;j<8;++j) o.u[j] = T[r8*8+j][c];
    *(uint4*)(Vpt + ((size_t)(b*512) + c0 + c)*NKx + r0 + r8*8) = o.v;
  }
}

// ---------------------------------------------------------------------------
// QKV projection GEMM with fused f32->bf16 A conversion. 128x128 tile.
// ---------------------------------------------------------------------------
__global__ __launch_bounds__(256) void mab_gemm_proj(
    const float* __restrict__ Qf, const float* __restrict__ Kf,
    const unsigned short* __restrict__ Wt,
    const float* __restrict__ bq, const float* __restrict__ bk, const float* __restrict__ bv,
    unsigned short* __restrict__ Cb, float kscale)
{
  __shared__ unsigned short As[128][64];
  __shared__ unsigned short Bs[128][64];
  const int z = blockIdx.z;
  const float* A = (z==0) ? Qf : Kf;
  const unsigned short* W = Wt + (size_t)z*512*512;
  const float* bias = (z==0)?bq:((z==1)?bk:bv);
  const float sc = (z==1) ? kscale : 1.0f;
  const int m0 = blockIdx.y*128, n0 = blockIdx.x*128;
  const int tid = threadIdx.x, w = tid>>6, lane = tid&63, g = lane>>4, q16 = lane&15;
  const int wr = w>>1, wc = w&1;

  f32x4 acc[4][4];
  #pragma unroll
  for (int m=0;m<4;++m)
    #pragma unroll
    for (int n=0;n<4;++n) acc[m][n] = (f32x4){0.f,0.f,0.f,0.f};

  float4 areg[8];
  #pragma unroll
  for (int i=0;i<8;++i){
    int id = i*256 + tid, row = id>>4, qc = id&15;
    areg[i] = *(const float4*)(A + (size_t)(m0+row)*512 + qc*4);
  }

  for (int k0 = 0; k0 < 512; k0 += 64){
    __syncthreads();
    #pragma unroll
    for (int i=0;i<8;++i){
      int id = i*256 + tid, row = id>>4, qc = id&15;
      unsigned int lo = cvtpk_bf16(areg[i].x, areg[i].y);
      unsigned int hi = cvtpk_bf16(areg[i].z, areg[i].w);
      unsigned int* dst = (unsigned int*)((char*)&As[0][0] + row*128
                          + ((qc>>1) ^ (row&7))*16 + (qc&1)*8);
      dst[0] = lo; dst[1] = hi;
    }
    #pragma unroll
    for (int i=0;i<4;++i){
      int o   = (w*4 + i)*1024 + lane*16;
      int row = o >> 7;
      int c   = (o >> 4) & 7;
      int cs  = c ^ (row & 7);
      gload16(W + (size_t)(n0+row)*512 + k0 + cs*8, (char*)&Bs[0][0] + (w*4+i)*1024);
    }
    __syncthreads();
    if (k0 + 64 < 512){
      #pragma unroll
      for (int i=0;i<8;++i){
        int id = i*256 + tid, row = id>>4, qc = id&15;
        areg[i] = *(const float4*)(A + (size_t)(m0+row)*512 + (k0+64) + qc*4);
      }
    }
    #pragma unroll
    for (int ks=0;ks<2;++ks){
      bf16x8 af[4], bfr[4];
      #pragma unroll
      for (int m=0;m<4;++m){
        int row = wr*64 + m*16 + q16;
        int c   = (ks*4 + g) ^ (row & 7);
        af[m] = *(const bf16x8*)((const char*)&As[0][0] + row*128 + c*16);
      }
      #pragma unroll
      for (int n=0;n<4;++n){
        int row = wc*64 + n*16 + q16;
        int c   = (ks*4 + g) ^ (row & 7);
        bfr[n] = *(const bf16x8*)((const char*)&Bs[0][0] + row*128 + c*16);
      }
      #pragma unroll
      for (int m=0;m<4;++m)
        #pragma unroll
        for (int n=0;n<4;++n)
          acc[m][n] = __builtin_amdgcn_mfma_f32_16x16x32_bf16(af[m], bfr[n], acc[m][n], 0,0,0);
    }
  }

  const size_t ZS = (size_t)8192*512;
  #pragma unroll
  for (int m=0;m<4;++m){
    const int rowl = wr*64 + m*16 + g*4;
    #pragma unroll
    for (int n=0;n<4;++n){
      const int col = n0 + wc*64 + n*16 + q16;
      const float bv2 = bias[col];
      #pragma unroll
      for (int r=0;r<4;++r){
        float v = (acc[m][n][r] + bv2) * sc;
        Cb[(size_t)z*ZS + (size_t)(m0 + rowl + r)*512 + col] = f2bf(v);
      }
    }
  }
}

// ---------------------------------------------------------------------------
// MLP GEMM, 64x64 tile (4 blocks/CU -> 4 waves/SIMD; the 128x128 version ran
// at 1 wave/SIMD on this N=512 shape and was latency-dead).
// C = op(A @ W^T + bias) (+ bf16 res), bf16 out.
// ---------------------------------------------------------------------------
__global__ __launch_bounds__(256) void mab_gemm_mlp(
    const unsigned short* __restrict__ A, const unsigned short* __restrict__ W,
    const float* __restrict__ bias, const unsigned short* __restrict__ resb,
    unsigned short* __restrict__ Cb, int relu)
{
  __shared__ unsigned short As[64][64];
  __shared__ unsigned short Bs[64][64];
  const int m0 = blockIdx.y*64, n0 = blockIdx.x*64;
  const int tid = threadIdx.x, w = tid>>6, lane = tid&63, g = lane>>4, q16 = lane&15;
  const int wr = w>>1, wc = w&1;

  f32x4 acc[2][2];
  #pragma unroll
  for (int m=0;m<2;++m)
    #pragma unroll
    for (int n=0;n<2;++n) acc[m][n] = (f32x4){0.f,0.f,0.f,0.f};

  for (int k0 = 0; k0 < 512; k0 += 64){
    __syncthreads();
    #pragma unroll
    for (int i=0;i<2;++i){
      int o   = w*2048 + i*1024 + lane*16;
      int row = o >> 7;
      int c   = (o >> 4) & 7;
      int cs  = c ^ (row & 7);
      gload16(A + (size_t)(m0+row)*512 + k0 + cs*8, (char*)&As[0][0] + w*2048 + i*1024);
      gload16(W + (size_t)(n0+row)*512 + k0 + cs*8, (char*)&Bs[0][0] + w*2048 + i*1024);
    }
    __syncthreads();
    #pragma unroll
    for (int ks=0;ks<2;++ks){
      bf16x8 af[2], bfr[2];
      #pragma unroll
      for (int m=0;m<2;++m){
        int row = wr*32 + m*16 + q16;
        int c   = (ks*4 + g) ^ (row & 7);
        af[m] = *(const bf16x8*)((const char*)&As[0][0] + row*128 + c*16);
      }
      #pragma unroll
      for (int n=0;n<2;++n){
        int row = wc*32 + n*16 + q16;
        int c   = (ks*4 + g) ^ (row & 7);
        bfr[n] = *(const bf16x8*)((const char*)&Bs[0][0] + row*128 + c*16);
      }
      #pragma unroll
      for (int m=0;m<2;++m)
        #pragma unroll
        for (int n=0;n<2;++n)
          acc[m][n] = __builtin_amdgcn_mfma_f32_16x16x32_bf16(af[m], bfr[n], acc[m][n], 0,0,0);
    }
  }

  #pragma unroll
  for (int m=0;m<2;++m){
    const int rowl = wr*32 + m*16 + g*4;
    #pragma unroll
    for (int n=0;n<2;++n){
      const int col = n0 + wc*32 + n*16 + q16;
      const float bv = bias[col];
      #pragma unroll
      for (int r=0;r<4;++r){
        float v = acc[m][n][r] + bv;
        if (relu) v = fmaxf(v, 0.f);
        size_t off = (size_t)(m0 + rowl + r)*512 + col;
        if (resb) v += bf2f(resb[off]);
        Cb[off] = f2bf(v);
      }
    }
  }
}

// ---------------------------------------------------------------------------
// MFMA flash attention v8 (R14, unchanged): all-heads block, LDS K/V/Kpos,
// 1-deep software pipeline, fused LN0 epilogue. -> O0b bf16.
// ---------------------------------------------------------------------------
__global__ __launch_bounds__(512, 2) void mab_attn8(
    const unsigned short* __restrict__ Qp, const unsigned short* __restrict__ Kp,
    const unsigned short* __restrict__ Vpt,
    const float* __restrict__ Kpos, const float* __restrict__ kp, const float* __restrict__ vp,
    const float* __restrict__ g0, const float* __restrict__ be0,
    unsigned short* __restrict__ O0b)
{
  __shared__ __align__(16) char pool[139264];
  const int qt = blockIdx.x;
  const int b  = blockIdx.y;
  const int q0 = qt*32;
  const int tid = threadIdx.x, w = tid>>6, lane = tid&63;
  const int q32 = lane & 31, hi = lane >> 5;
  const int h = w;

  char* Kbase = pool + w*8192;
  char* Vbase = pool + 65536 + w*8192;
  char* KQb   = pool + 131072;

  const unsigned short* Kg = Kp + ((size_t)b*NKx)*Dx + h*64;
  const unsigned short* Vg = Vpt + ((size_t)(b*512) + h*64)*NKx;
  const float* KPg = Kpos + (size_t)b*NQx*NKx + (size_t)q0*NKx;

  const int sr8 = lane>>3, sc8 = lane&7;
  const int sr4 = lane>>2, sc4 = lane&3;

  auto STAGE = [&](int t){
    if (t >= 64) return;
    const int buf = t & 1;
    const int k1 = t*32;
    #pragma unroll
    for (int i=0;i<4;++i){
      int kr = i*8 + sr8, kcs = sc8 ^ (kr & 7);
      gload16(Kg + (size_t)(k1 + kr)*Dx + kcs*8, Kbase + buf*4096 + i*1024);
      int vr = i*16 + sr4, vcs = sc4 ^ ((vr>>1) & 3);
      gload16(Vg + (size_t)vr*NKx + k1 + vcs*8, Vbase + buf*4096 + i*1024);
    }
    if (w < 4){
      int pr = w*8 + sr8, pcs = sc8 ^ (pr & 7);
      gload16(KPg + (size_t)pr*NKx + k1 + pcs*4, KQb + buf*4096 + w*1024);
    }
  };

  auto LOADREGS = [&](int buf, f32x4 (&kq)[4], bf16x8 (&vf)[2][2]){
    #pragma unroll
    for (int a=0;a<4;++a){
      int cc = (a*2 + hi) ^ (q32 & 7);
      kq[a] = *(const f32x4*)(KQb + buf*4096 + q32*128 + cc*16);
    }
    #pragma unroll
    for (int c2=0;c2<2;++c2)
      #pragma unroll
      for (int db=0;db<2;++db){
        int row = db*32 + q32;
        int cc  = (c2*2 + hi) ^ ((row>>1) & 3);
        vf[c2][db] = *(const bf16x8*)(Vbase + buf*4096 + row*64 + cc*16);
      }
  };

  const unsigned short* Qrowp = Qp + ((size_t)(b*NQx + q0 + q32))*Dx + h*64;
  bf16x8 qf[4];
  #pragma unroll
  for (int ds=0; ds<4; ++ds)
    qf[ds] = *(const bf16x8*)(Qrowp + ds*16 + hi*8);

  auto QKT = [&](int buf, f32x16& sT){
    #pragma unroll
    for (int r=0;r<16;++r) sT[r] = 0.f;
    #pragma unroll
    for (int ds=0; ds<4; ++ds){
      int cc = (ds*2 + hi) ^ (q32 & 7);
      bf16x8 kf = *(const bf16x8*)(Kbase + buf*4096 + q32*128 + cc*16);
      sT = __builtin_amdgcn_mfma_f32_32x32x16_bf16(kf, qf[ds], sT, 0,0,0);
    }
  };

  float qkp = 0.f;
  #pragma unroll
  for (int ds=0; ds<4; ++ds){
    union { bf16x8 v; unsigned short u[8]; } qa; qa.v = qf[ds];
    #pragma unroll
    for (int j=0;j<8;++j)
      qkp = fmaf(bf2f(qa.u[j]), kp[ds*16 + hi*8 + j], qkp);
  }
  qkp += __shfl_xor(qkp, 32);
  qkp *= 1.4426950408889634f;

  float m_i = -1e30f, l_i = 0.f, a_i = 0.f;
  f32x16 accT[2];
  #pragma unroll
  for (int db=0; db<2; ++db)
    #pragma unroll
    for (int r=0;r<16;++r) accT[db][r] = 0.f;

  auto FINISH = [&](f32x16& sT, f32x4 (&kq)[4], bf16x8 (&vf)[2][2]){
    #pragma unroll
    for (int r=0;r<16;++r)
      sT[r] = fmaf(kq[r>>2][r&3], qkp, sT[r]);
    float t0 = fmax3(sT[0],  sT[1],  sT[2]);
    float t1 = fmax3(sT[3],  sT[4],  sT[5]);
    float t2 = fmax3(sT[6],  sT[7],  sT[8]);
    float t3 = fmax3(sT[9],  sT[10], sT[11]);
    float t4 = fmax3(sT[12], sT[13], sT[14]);
    float rm = fmax3(fmax3(t0, t1, t2), fmax3(t3, t4, sT[15]), m_i);
    rm = fmaxf(rm, __shfl_xor(rm, 32));
    if (!__all(rm <= m_i + 11.544f)){
      float al = fexp2(m_i - rm);
      m_i = rm;
      l_i *= al; a_i *= al;
      #pragma unroll
      for (int db=0; db<2; ++db)
        #pragma unroll
        for (int r=0;r<16;++r) accT[db][r] *= al;
    }
    float psq[4] = {0.f,0.f,0.f,0.f};
    float pkq[4] = {0.f,0.f,0.f,0.f};
    #pragma unroll
    for (int r=0;r<16;++r){
      float p = fexp2(sT[r] - m_i);
      sT[r] = p;
      psq[r&3] += p;
      pkq[r&3] = fmaf(p, kq[r>>2][r&3], pkq[r&3]);
    }
    float ps = (psq[0]+psq[1]) + (psq[2]+psq[3]);
    float pk = (pkq[0]+pkq[1]) + (pkq[2]+pkq[3]);
    ps += __shfl_xor(ps, 32);
    pk += __shfl_xor(pk, 32);
    l_i += ps; a_i += pk;
    union PW { unsigned int u[4]; bf16x8 v; } pa[2];
    {
      unsigned int w0 = cvtpk_bf16(sT[0],  sT[1]);
      unsigned int w1 = cvtpk_bf16(sT[2],  sT[3]);
      unsigned int w2 = cvtpk_bf16(sT[4],  sT[5]);
      unsigned int w3 = cvtpk_bf16(sT[6],  sT[7]);
      unsigned int w4 = cvtpk_bf16(sT[8],  sT[9]);
      unsigned int w5 = cvtpk_bf16(sT[10], sT[11]);
      unsigned int w6 = cvtpk_bf16(sT[12], sT[13]);
      unsigned int w7 = cvtpk_bf16(sT[14], sT[15]);
      plane32_swap(w0, w2);
      plane32_swap(w1, w3);
      plane32_swap(w4, w6);
      plane32_swap(w5, w7);
      pa[0].u[0]=w0; pa[0].u[1]=w1; pa[0].u[2]=w2; pa[0].u[3]=w3;
      pa[1].u[0]=w4; pa[1].u[1]=w5; pa[1].u[2]=w6; pa[1].u[3]=w7;
    }
    __builtin_amdgcn_s_setprio(1);
    #pragma unroll
    for (int c2=0; c2<2; ++c2){
      #pragma unroll
      for (int db=0; db<2; ++db)
        accT[db] = __builtin_amdgcn_mfma_f32_32x32x16_bf16(vf[c2][db], pa[c2].v, accT[db], 0,0,0);
    }
    __builtin_amdgcn_s_setprio(0);
  };

  STAGE(0);
  __syncthreads();

  f32x16 sT0, sT1;
  f32x4 kq0[4], kq1[4];
  bf16x8 vf0[2][2], vf1[2][2];

  STAGE(1);
  __builtin_amdgcn_sched_barrier(0);
  LOADREGS(0, kq0, vf0);
  QKT(0, sT0);
  __syncthreads();

  for (int t = 1; t < 64; t += 2){
    STAGE(t+1);
    __builtin_amdgcn_sched_barrier(0);
    LOADREGS(1, kq1, vf1);
    QKT(1, sT1);
    FINISH(sT0, kq0, vf0);
    __syncthreads();
    if (t+1 < 64){
      STAGE(t+2);
      __builtin_amdgcn_sched_barrier(0);
      LOADREGS(0, kq0, vf0);
      QKT(0, sT0);
    }
    FINISH(sT1, kq1, vf1);
    __syncthreads();
  }

  // epilogue: residual + value-bias, then fused LN0
  float inv = 1.0f / l_i;
  float aw  = a_i * inv;
  float s = 0.f, sq = 0.f;
  #pragma unroll
  for (int db=0; db<2; ++db){
    #pragma unroll
    for (int a2=0; a2<4; ++a2){
      int d0 = db*32 + a2*8 + hi*4;
      f32x4 vpv = *(const f32x4*)(vp + d0);
      ushort4 qh = *(const ushort4*)(Qrowp + d0);
      float o0 = fmaf(accT[db][a2*4+0], inv, bf2f(qh.x) + aw*vpv[0]);
      float o1 = fmaf(accT[db][a2*4+1], inv, bf2f(qh.y) + aw*vpv[1]);
      float o2 = fmaf(accT[db][a2*4+2], inv, bf2f(qh.z) + aw*vpv[2]);
      float o3 = fmaf(accT[db][a2*4+3], inv, bf2f(qh.w) + aw*vpv[3]);
      accT[db][a2*4+0]=o0; accT[db][a2*4+1]=o1;
      accT[db][a2*4+2]=o2; accT[db][a2*4+3]=o3;
      s += (o0+o1)+(o2+o3);
      sq = fmaf(o0,o0, fmaf(o1,o1, fmaf(o2,o2, fmaf(o3,o3, sq))));
    }
  }
  s  += __shfl_xor(s, 32);
  sq += __shfl_xor(sq, 32);
  float* lnred = (float*)pool;
  if (hi == 0){
    lnred[(q32*8 + w)*2 + 0] = s;
    lnred[(q32*8 + w)*2 + 1] = sq;
  }
  __syncthreads();
  float S = 0.f, SQ = 0.f;
  #pragma unroll
  for (int h2=0; h2<8; ++h2){
    S  += lnred[(q32*8 + h2)*2 + 0];
    SQ += lnred[(q32*8 + h2)*2 + 1];
  }
  float mean = S*(1.0f/512.0f);
  float var  = SQ*(1.0f/512.0f) - mean*mean;
  float rstd = rsqrtf(var + 1e-5f);
  unsigned short* Orow = O0b + ((size_t)(b*NQx + q0 + q32))*Dx + h*64;
  #pragma unroll
  for (int db=0; db<2; ++db){
    #pragma unroll
    for (int a2=0; a2<4; ++a2){
      int d0 = db*32 + a2*8 + hi*4;
      f32x4 gg = *(const f32x4*)(g0  + h*64 + d0);
      f32x4 bb = *(const f32x4*)(be0 + h*64 + d0);
      float y0 = (accT[db][a2*4+0]-mean)*rstd*gg[0] + bb[0];
      float y1 = (accT[db][a2*4+1]-mean)*rstd*gg[1] + bb[1];
      float y2 = (accT[db][a2*4+2]-mean)*rstd*gg[2] + bb[2];
      float y3 = (accT[db][a2*4+3]-mean)*rstd*gg[3] + bb[3];
      uint2 pk2;
      pk2.x = cvtpk_bf16(y0, y1);
      pk2.y = cvtpk_bf16(y2, y3);
      *(uint2*)(Orow + d0) = pk2;
    }
  }
}

// ---------------------------------------------------------------------------
// Final LayerNorm over 512, bf16 input -> f32 output.
// ---------------------------------------------------------------------------
__global__ __launch_bounds__(256) void mab_ln2b(
    const unsigned short* __restrict__ Xin, const float* __restrict__ g,
    const float* __restrict__ be, float* __restrict__ Yf)
{
  const int row = blockIdx.x;
  const int tid = threadIdx.x;
  ushort2 v2 = *(const ushort2*)(Xin + (size_t)row*Dx + tid*2);
  float vx = bf2f(v2.x), vy = bf2f(v2.y);
  float s  = vx + vy;
  float sq = fmaf(vx,vx, vy*vy);
  #pragma unroll
  for (int m=1; m<64; m<<=1){ s += __shfl_xor(s,m); sq += __shfl_xor(sq,m); }
  __shared__ float red[2][4];
  const int wid = tid>>6, lane = tid&63;
  if (lane==0){ red[0][wid]=s; red[1][wid]=sq; }
  __syncthreads();
  s  = red[0][0]+red[0][1]+red[0][2]+red[0][3];
  sq = red[1][0]+red[1][1]+red[1][2]+red[1][3];
  float mean = s*(1.0f/Dx);
  float var  = sq*(1.0f/Dx) - mean*mean;
  float rstd = rsqrtf(var + 1e-5f);
  float2 gg = *(const float2*)(g  + tid*2);
  float2 bb = *(const float2*)(be + tid*2);
  float2 o;
  o.x = (vx-mean)*rstd*gg.x + bb.x;
  o.y = (vy-mean)*rstd*gg.y + bb.y;
  *(float2*)(Yf + (size_t)row*Dx + tid*2) = o;
}

// ---------------------------------------------------------------------------
extern "C" void kernel_launch(void* const* d_in, const int* in_sizes, int n_in,
                              void* d_out, int out_size, void* d_ws, size_t ws_size,
                              hipStream_t stream)
{
  const float* Q    = (const float*)d_in[0];
  const float* K    = (const float*)d_in[1];
  const float* Kpos = (const float*)d_in[2];
  const float* Wq   = (const float*)d_in[3];
  const float* bq   = (const float*)d_in[4];
  const float* Wk   = (const float*)d_in[5];
  const float* bk   = (const float*)d_in[6];
  const float* Wv   = (const float*)d_in[7];
  const float* bv   = (const float*)d_in[8];
  const float* kp   = (const float*)d_in[9];
  const float* vp   = (const float*)d_in[10];
  const float* W0   = (const float*)d_in[11];
  const float* b0   = (const float*)d_in[12];
  const float* W1   = (const float*)d_in[13];
  const float* b1   = (const float*)d_in[14];
  const float* g0   = (const float*)d_in[15];
  const float* be0  = (const float*)d_in[16];
  const float* g1   = (const float*)d_in[17];
  const float* be1  = (const float*)d_in[18];
  float* out = (float*)d_out;
  char* wsb  = (char*)d_ws;

  const size_t MB = 1024*1024;
  unsigned short* Qp  = (unsigned short*)(wsb);          // 8 MiB bf16 [8192][512]
  unsigned short* Kp  = (unsigned short*)(wsb + 8*MB);   // pre-scaled (log2e/sqrt512)
  unsigned short* Vp  = (unsigned short*)(wsb + 16*MB);  // -> T1 after vt
  unsigned short* Vpt = (unsigned short*)(wsb + 24*MB);  // 8 MiB
  unsigned short* O0b = (unsigned short*)(wsb + 32*MB);  // 8 MiB bf16 post-LN0
  unsigned short* Wt  = (unsigned short*)(wsb + 40*MB);  // 2.5 MiB [5][512][512]
  unsigned short* T2b = (unsigned short*)(wsb + 48*MB);  // 8 MiB bf16 pre-LN1
  unsigned short* T1  = Vp;                              // reuse (vt done)

  const float kscale = 0.044194173824159216f * 1.4426950408889634f; // log2e/sqrt(512)

  // weight transposes (Wq,Wk,Wv,W0,W1)
  mab_wt<<<dim3(8,8,5), 256, 0, stream>>>(Wq, Wk, Wv, W0, W1, Wt);
  // fused Q/K/V projections from f32 inputs (z=0,1,2)
  mab_gemm_proj<<<dim3(4,64,3), 256, 0, stream>>>(Q, K, Wt, bq, bk, bv, Qp, kscale);
  // V transpose to d-major
  mab_vt<<<dim3(32,8,4), 256, 0, stream>>>(Vp, Vpt);
  // fused attention v8 (pipelined, all-heads block, fused LN0) -> O0b bf16
  mab_attn8<<<dim3(64,4), 512, 0, stream>>>(Qp, Kp, Vpt, Kpos, kp, vp, g0, be0, O0b);
  // T1 = relu(O0b @ W0 + b0)  (bf16 out), 64x64 tiles (4 waves/SIMD)
  mab_gemm_mlp<<<dim3(8,128), 256, 0, stream>>>(
      O0b, Wt + (size_t)3*512*512, b0, nullptr, T1, 1);
  // T2b = O0b + relu(T1 @ W1 + b1)  (bf16 out)
  mab_gemm_mlp<<<dim3(8,128), 256, 0, stream>>>(
      T1, Wt + (size_t)4*512*512, b1, O0b, T2b, 1);
  // final LN: bf16 in -> f32 out
  mab_ln2b<<<8192, 256, 0, stream>>>(T2b, g1, be1, out);
}

// Round 16
// 179.008 us; speedup vs baseline: 1.5634x; 1.0272x over previous
//
#include <hip/hip_runtime.h>
#include <math.h>

// Problem constants (MAB_50921132261692)
#define Bx  4
#define NQx 2048
#define NKx 2048
#define Dx  512
#define Hx  8

typedef __attribute__((ext_vector_type(8))) __bf16 bf16x8;
typedef __attribute__((ext_vector_type(4))) float f32x4;
typedef __attribute__((ext_vector_type(16))) float f32x16;

typedef const __attribute__((address_space(1))) unsigned int* gas_ptr;
typedef __attribute__((address_space(3))) unsigned int* lds_ptr;

__device__ __forceinline__ void gload16(const void* g, void* l){
  __builtin_amdgcn_global_load_lds((gas_ptr)g, (lds_ptr)l, 16, 0, 0);
}

__device__ __forceinline__ unsigned short f2bf(float f){
  union { float f; unsigned int u; } v; v.f = f;
  unsigned int r = (v.u + 0x7FFFu + ((v.u >> 16) & 1u)) >> 16;
  return (unsigned short)r;
}
__device__ __forceinline__ float bf2f(unsigned short u){
  union { unsigned int u; float f; } v; v.u = ((unsigned int)u) << 16; return v.f;
}
__device__ __forceinline__ unsigned int cvtpk_bf16(float a, float b){
  unsigned int d;
  asm("v_cvt_pk_bf16_f32 %0, %1, %2" : "=v"(d) : "v"(a), "v"(b));
  return d;
}
__device__ __forceinline__ void plane32_swap(unsigned int& a, unsigned int& b){
  asm("v_permlane32_swap_b32 %0, %1" : "+v"(a), "+v"(b));
}
__device__ __forceinline__ float fexp2(float x){           // D = 2^x
  float d; asm("v_exp_f32 %0, %1" : "=v"(d) : "v"(x)); return d;
}
__device__ __forceinline__ float fmax3(float a, float b, float c){
  float d; asm("v_max3_f32 %0, %1, %2, %3" : "=v"(d) : "v"(a), "v"(b), "v"(c)); return d;
}

// ---------------------------------------------------------------------------
// Transpose + convert 5 weights [512][512] f32 -> Wt bf16 [z][N=512][K=512].
// ---------------------------------------------------------------------------
__global__ __launch_bounds__(256) void mab_wt(
    const float* __restrict__ Wq, const float* __restrict__ Wk, const float* __restrict__ Wv,
    const float* __restrict__ W0, const float* __restrict__ W1,
    unsigned short* __restrict__ Wt)
{
  __shared__ unsigned short T[64][72];
  const int z = blockIdx.z;
  const float* W = (z==0)?Wq:(z==1)?Wk:(z==2)?Wv:(z==3)?W0:W1;
  unsigned short* O = Wt + (size_t)z*512*512;
  const int k0 = blockIdx.x*64, n0 = blockIdx.y*64;
  const int tid = threadIdx.x;
  #pragma unroll
  for (int i=0;i<4;++i){
    int id = tid + i*256;          // 1024 = 64 rows x 16 float4
    int r = id>>4, c4 = id&15;
    float4 v = *(const float4*)(W + (size_t)(k0+r)*512 + n0 + c4*4);
    ushort4 o; o.x=f2bf(v.x); o.y=f2bf(v.y); o.z=f2bf(v.z); o.w=f2bf(v.w);
    *(ushort4*)&T[r][c4*4] = o;
  }
  __syncthreads();
  #pragma unroll
  for (int i=0;i<2;++i){
    int id = tid + i*256;          // 512 = 64 out-rows x 8 chunks
    int c = id>>3, r8 = id&7;
    union { unsigned short u[8]; uint4 v; } o;
    #pragma unroll
    for (int j=0;j<8;++j) o.u[j] = T[r8*8+j][c];
    *(uint4*)(O + (size_t)(n0+c)*512 + k0 + r8*8) = o.v;
  }
}

// ---------------------------------------------------------------------------
// QKV projection GEMM with fused f32->bf16 A conversion. 128x128 tile.
// z==2 (V) writes DIRECTLY to Vpt [B][512 d][2048 k] (transposed) — the
// separate mab_vt transpose kernel is eliminated. 4 consecutive rows per
// acc quad = 4 consecutive k in Vpt = one 8B uint2 store.
// ---------------------------------------------------------------------------
__global__ __launch_bounds__(256) void mab_gemm_proj(
    const float* __restrict__ Qf, const float* __restrict__ Kf,
    const unsigned short* __restrict__ Wt,
    const float* __restrict__ bq, const float* __restrict__ bk, const float* __restrict__ bv,
    unsigned short* __restrict__ Cb, unsigned short* __restrict__ Vpt, float kscale)
{
  __shared__ unsigned short As[128][64];
  __shared__ unsigned short Bs[128][64];
  const int z = blockIdx.z;
  const float* A = (z==0) ? Qf : Kf;
  const unsigned short* W = Wt + (size_t)z*512*512;
  const float* bias = (z==0)?bq:((z==1)?bk:bv);
  const float sc = (z==1) ? kscale : 1.0f;
  const int m0 = blockIdx.y*128, n0 = blockIdx.x*128;
  const int tid = threadIdx.x, w = tid>>6, lane = tid&63, g = lane>>4, q16 = lane&15;
  const int wr = w>>1, wc = w&1;

  f32x4 acc[4][4];
  #pragma unroll
  for (int m=0;m<4;++m)
    #pragma unroll
    for (int n=0;n<4;++n) acc[m][n] = (f32x4){0.f,0.f,0.f,0.f};

  float4 areg[8];
  #pragma unroll
  for (int i=0;i<8;++i){
    int id = i*256 + tid, row = id>>4, qc = id&15;
    areg[i] = *(const float4*)(A + (size_t)(m0+row)*512 + qc*4);
  }

  for (int k0 = 0; k0 < 512; k0 += 64){
    __syncthreads();
    #pragma unroll
    for (int i=0;i<8;++i){
      int id = i*256 + tid, row = id>>4, qc = id&15;
      unsigned int lo = cvtpk_bf16(areg[i].x, areg[i].y);
      unsigned int hi = cvtpk_bf16(areg[i].z, areg[i].w);
      unsigned int* dst = (unsigned int*)((char*)&As[0][0] + row*128
                          + ((qc>>1) ^ (row&7))*16 + (qc&1)*8);
      dst[0] = lo; dst[1] = hi;
    }
    #pragma unroll
    for (int i=0;i<4;++i){
      int o   = (w*4 + i)*1024 + lane*16;
      int row = o >> 7;
      int c   = (o >> 4) & 7;
      int cs  = c ^ (row & 7);
      gload16(W + (size_t)(n0+row)*512 + k0 + cs*8, (char*)&Bs[0][0] + (w*4+i)*1024);
    }
    __syncthreads();
    if (k0 + 64 < 512){
      #pragma unroll
      for (int i=0;i<8;++i){
        int id = i*256 + tid, row = id>>4, qc = id&15;
        areg[i] = *(const float4*)(A + (size_t)(m0+row)*512 + (k0+64) + qc*4);
      }
    }
    #pragma unroll
    for (int ks=0;ks<2;++ks){
      bf16x8 af[4], bfr[4];
      #pragma unroll
      for (int m=0;m<4;++m){
        int row = wr*64 + m*16 + q16;
        int c   = (ks*4 + g) ^ (row & 7);
        af[m] = *(const bf16x8*)((const char*)&As[0][0] + row*128 + c*16);
      }
      #pragma unroll
      for (int n=0;n<4;++n){
        int row = wc*64 + n*16 + q16;
        int c   = (ks*4 + g) ^ (row & 7);
        bfr[n] = *(const bf16x8*)((const char*)&Bs[0][0] + row*128 + c*16);
      }
      #pragma unroll
      for (int m=0;m<4;++m)
        #pragma unroll
        for (int n=0;n<4;++n)
          acc[m][n] = __builtin_amdgcn_mfma_f32_16x16x32_bf16(af[m], bfr[n], acc[m][n], 0,0,0);
    }
  }

  const size_t ZS = (size_t)8192*512;
  #pragma unroll
  for (int m=0;m<4;++m){
    const int rowl = wr*64 + m*16 + g*4;
    #pragma unroll
    for (int n=0;n<4;++n){
      const int col = n0 + wc*64 + n*16 + q16;
      const float bv2 = bias[col];
      float vv[4];
      #pragma unroll
      for (int r=0;r<4;++r) vv[r] = (acc[m][n][r] + bv2) * sc;
      if (z == 2){
        int rowg0 = m0 + rowl;
        int bb2 = rowg0 >> 11, kk = rowg0 & 2047;
        uint2 p2;
        p2.x = cvtpk_bf16(vv[0], vv[1]);
        p2.y = cvtpk_bf16(vv[2], vv[3]);
        *(uint2*)(Vpt + ((size_t)(bb2*512) + col)*2048 + kk) = p2;
      } else {
        #pragma unroll
        for (int r=0;r<4;++r)
          Cb[(size_t)z*ZS + (size_t)(m0 + rowl + r)*512 + col] = f2bf(vv[r]);
      }
    }
  }
}

// ---------------------------------------------------------------------------
// MLP GEMM, 64x64 tile. C = op(A @ W^T + bias) (+ bf16 res), bf16 out.
// ---------------------------------------------------------------------------
__global__ __launch_bounds__(256) void mab_gemm_mlp(
    const unsigned short* __restrict__ A, const unsigned short* __restrict__ W,
    const float* __restrict__ bias, const unsigned short* __restrict__ resb,
    unsigned short* __restrict__ Cb, int relu)
{
  __shared__ unsigned short As[64][64];
  __shared__ unsigned short Bs[64][64];
  const int m0 = blockIdx.y*64, n0 = blockIdx.x*64;
  const int tid = threadIdx.x, w = tid>>6, lane = tid&63, g = lane>>4, q16 = lane&15;
  const int wr = w>>1, wc = w&1;

  f32x4 acc[2][2];
  #pragma unroll
  for (int m=0;m<2;++m)
    #pragma unroll
    for (int n=0;n<2;++n) acc[m][n] = (f32x4){0.f,0.f,0.f,0.f};

  for (int k0 = 0; k0 < 512; k0 += 64){
    __syncthreads();
    #pragma unroll
    for (int i=0;i<2;++i){
      int o   = w*2048 + i*1024 + lane*16;
      int row = o >> 7;
      int c   = (o >> 4) & 7;
      int cs  = c ^ (row & 7);
      gload16(A + (size_t)(m0+row)*512 + k0 + cs*8, (char*)&As[0][0] + w*2048 + i*1024);
      gload16(W + (size_t)(n0+row)*512 + k0 + cs*8, (char*)&Bs[0][0] + w*2048 + i*1024);
    }
    __syncthreads();
    #pragma unroll
    for (int ks=0;ks<2;++ks){
      bf16x8 af[2], bfr[2];
      #pragma unroll
      for (int m=0;m<2;++m){
        int row = wr*32 + m*16 + q16;
        int c   = (ks*4 + g) ^ (row & 7);
        af[m] = *(const bf16x8*)((const char*)&As[0][0] + row*128 + c*16);
      }
      #pragma unroll
      for (int n=0;n<2;++n){
        int row = wc*32 + n*16 + q16;
        int c   = (ks*4 + g) ^ (row & 7);
        bfr[n] = *(const bf16x8*)((const char*)&Bs[0][0] + row*128 + c*16);
      }
      #pragma unroll
      for (int m=0;m<2;++m)
        #pragma unroll
        for (int n=0;n<2;++n)
          acc[m][n] = __builtin_amdgcn_mfma_f32_16x16x32_bf16(af[m], bfr[n], acc[m][n], 0,0,0);
    }
  }

  #pragma unroll
  for (int m=0;m<2;++m){
    const int rowl = wr*32 + m*16 + g*4;
    #pragma unroll
    for (int n=0;n<2;++n){
      const int col = n0 + wc*32 + n*16 + q16;
      const float bv = bias[col];
      #pragma unroll
      for (int r=0;r<4;++r){
        float v = acc[m][n][r] + bv;
        if (relu) v = fmaxf(v, 0.f);
        size_t off = (size_t)(m0 + rowl + r)*512 + col;
        if (resb) v += bf2f(resb[off]);
        Cb[off] = f2bf(v);
      }
    }
  }
}

// ---------------------------------------------------------------------------
// MFMA flash attention v9: all-heads block + K-SPLIT x2 ACROSS BLOCKS +
// SINGLE-BUFFERED LDS (2 blocks/CU -> 4 waves/SIMD; CU-level overlap of one
// block's stage-drain with the other block's compute replaces LDS dbuf).
// Grid (NQ/32=64, 2 k-halves, B=4) = 512 blocks x 8 waves. Wave w = head w,
// all waves share q-rows q0..q0+31; block processes k in [ks*1024, +1024)
// (32 tiles of KVBLK=32). Kpos: each (q,k) element read by EXACTLY ONE block
// (67 MB logical, L3-fit — no R12-style thrash). LDS = 8x(4K+4V) + 4 Kpos
// = 68 KB <= 80 -> 2 blocks/CU. launch_bounds(512,4) caps VGPR at 128.
// Per-tile body = R13-verified. Epilogue writes RAW partials (bf16 accT +
// m/l/a), merged by mab_merge_ln (R12-verified).
// Kp pre-scaled by log2e/sqrt(512). Vpt d-major [B][512][NK].
// ---------------------------------------------------------------------------
__global__ __launch_bounds__(512, 4) void mab_attn9(
    const unsigned short* __restrict__ Qp, const unsigned short* __restrict__ Kp,
    const unsigned short* __restrict__ Vpt,
    const float* __restrict__ Kpos, const float* __restrict__ kp,
    unsigned short* __restrict__ OP, float4* __restrict__ MLA)
{
  __shared__ __align__(16) char pool[69632];
  // [0,32768):      K per wave: w*4096   (32 k x 64 d bf16, swz)
  // [32768,65536):  V per wave: w*4096   (64 d x 32 k bf16, swz)
  // [65536,69632):  Kpos                 (32 q x 32 k f32, swz)

  const int qt = blockIdx.x;
  const int ks = blockIdx.y;
  const int b  = blockIdx.z;
  const int q0 = qt*32;
  const int kbase = ks*1024;
  const int tid = threadIdx.x, w = tid>>6, lane = tid&63;
  const int q32 = lane & 31, hi = lane >> 5;
  const int h = w;

  char* Kbase = pool + w*4096;
  char* Vbase = pool + 32768 + w*4096;
  char* KQb   = pool + 65536;

  const unsigned short* Kg = Kp + ((size_t)b*NKx)*Dx + h*64;
  const unsigned short* Vg = Vpt + ((size_t)(b*512) + h*64)*NKx;
  const float* KPg = Kpos + (size_t)b*NQx*NKx + (size_t)q0*NKx;

  const int sr8 = lane>>3, sc8 = lane&7;   // K/Kpos staging: 8 rows x 8 chunks
  const int sr4 = lane>>2, sc4 = lane&3;   // V staging: 16 rows x 4 chunks

  auto STAGE = [&](int t){
    const int k1 = kbase + t*32;
    #pragma unroll
    for (int i=0;i<4;++i){
      int kr = i*8 + sr8, kcs = sc8 ^ (kr & 7);
      gload16(Kg + (size_t)(k1 + kr)*Dx + kcs*8, Kbase + i*1024);
      int vr = i*16 + sr4, vcs = sc4 ^ ((vr>>1) & 3);
      gload16(Vg + (size_t)vr*NKx + k1 + vcs*8, Vbase + i*1024);
    }
    if (w < 4){
      int pr = w*8 + sr8, pcs = sc8 ^ (pr & 7);
      gload16(KPg + (size_t)pr*NKx + k1 + pcs*4, KQb + w*1024);
    }
  };

  // Q frags direct from global (L2-resident)
  const unsigned short* Qrowp = Qp + ((size_t)(b*NQx + q0 + q32))*Dx + h*64;
  bf16x8 qf[4];
  #pragma unroll
  for (int ds=0; ds<4; ++ds)
    qf[ds] = *(const bf16x8*)(Qrowp + ds*16 + hi*8);

  // qkp = (Qh . kp) * log2e for own q-row
  float qkp = 0.f;
  #pragma unroll
  for (int ds=0; ds<4; ++ds){
    union { bf16x8 v; unsigned short u[8]; } qa; qa.v = qf[ds];
    #pragma unroll
    for (int j=0;j<8;++j)
      qkp = fmaf(bf2f(qa.u[j]), kp[ds*16 + hi*8 + j], qkp);
  }
  qkp += __shfl_xor(qkp, 32);
  qkp *= 1.4426950408889634f;

  float m_i = -1e30f, l_i = 0.f, a_i = 0.f;
  f32x16 accT[2];
  #pragma unroll
  for (int db=0; db<2; ++db)
    #pragma unroll
    for (int r=0;r<16;++r) accT[db][r] = 0.f;

  STAGE(0);
  __syncthreads();   // stage 0 landed (vmcnt drained by syncthreads)

  // ---- main loop: 32 tiles of 32 k (this k-half), single-buffered ----
  for (int t = 0; t < 32; ++t){
    // S^T = K . Q^T (log2 domain); k' = (r&3)+8*(r>>2)+4*hi
    f32x16 sT;
    #pragma unroll
    for (int r=0;r<16;++r) sT[r] = 0.f;
    __builtin_amdgcn_s_setprio(1);
    #pragma unroll
    for (int ds=0; ds<4; ++ds){
      int cc = (ds*2 + hi) ^ (q32 & 7);
      bf16x8 kf = *(const bf16x8*)(Kbase + q32*128 + cc*16);
      sT = __builtin_amdgcn_mfma_f32_32x32x16_bf16(kf, qf[ds], sT, 0,0,0);
    }
    __builtin_amdgcn_s_setprio(0);

    // kq from shared Kpos LDS
    f32x4 kq[4];
    #pragma unroll
    for (int a=0;a<4;++a){
      int cc = (a*2 + hi) ^ (q32 & 7);
      kq[a] = *(const f32x4*)(KQb + q32*128 + cc*16);
    }

    // + Kpos * qkp (log2 domain)
    #pragma unroll
    for (int r=0;r<16;++r)
      sT[r] = fmaf(kq[r>>2][r&3], qkp, sT[r]);

    // max tree via v_max3
    float t0 = fmax3(sT[0],  sT[1],  sT[2]);
    float t1 = fmax3(sT[3],  sT[4],  sT[5]);
    float t2 = fmax3(sT[6],  sT[7],  sT[8]);
    float t3 = fmax3(sT[9],  sT[10], sT[11]);
    float t4 = fmax3(sT[12], sT[13], sT[14]);
    float rm = fmax3(fmax3(t0, t1, t2), fmax3(t3, t4, sT[15]), m_i);
    rm = fmaxf(rm, __shfl_xor(rm, 32));

    if (!__all(rm <= m_i + 11.544f)){      // 2^11.544 = e^8 bound
      float al = fexp2(m_i - rm);
      m_i = rm;
      l_i *= al; a_i *= al;
      #pragma unroll
      for (int db=0; db<2; ++db)
        #pragma unroll
        for (int r=0;r<16;++r) accT[db][r] *= al;
    }

    // exp + tree-reduced row-sum and Kpos-weighted sum
    float psq[4] = {0.f,0.f,0.f,0.f};
    float pkq[4] = {0.f,0.f,0.f,0.f};
    #pragma unroll
    for (int r=0;r<16;++r){
      float p = fexp2(sT[r] - m_i);
      sT[r] = p;
      psq[r&3] += p;
      pkq[r&3] = fmaf(p, kq[r>>2][r&3], pkq[r&3]);
    }
    float ps = (psq[0]+psq[1]) + (psq[2]+psq[3]);
    float pk = (pkq[0]+pkq[1]) + (pkq[2]+pkq[3]);
    ps += __shfl_xor(ps, 32);
    pk += __shfl_xor(pk, 32);
    l_i += ps; a_i += pk;

    // pack P to bf16 frags in-register (cvt_pk + permlane32_swap)
    union PW { unsigned int u[4]; bf16x8 v; } pa[2];
    {
      unsigned int w0 = cvtpk_bf16(sT[0],  sT[1]);
      unsigned int w1 = cvtpk_bf16(sT[2],  sT[3]);
      unsigned int w2 = cvtpk_bf16(sT[4],  sT[5]);
      unsigned int w3 = cvtpk_bf16(sT[6],  sT[7]);
      unsigned int w4 = cvtpk_bf16(sT[8],  sT[9]);
      unsigned int w5 = cvtpk_bf16(sT[10], sT[11]);
      unsigned int w6 = cvtpk_bf16(sT[12], sT[13]);
      unsigned int w7 = cvtpk_bf16(sT[14], sT[15]);
      plane32_swap(w0, w2);
      plane32_swap(w1, w3);
      plane32_swap(w4, w6);
      plane32_swap(w5, w7);
      pa[0].u[0]=w0; pa[0].u[1]=w1; pa[0].u[2]=w2; pa[0].u[3]=w3;
      pa[1].u[0]=w4; pa[1].u[1]=w5; pa[1].u[2]=w6; pa[1].u[3]=w7;
    }

    // O^T += V . P
    __builtin_amdgcn_s_setprio(1);
    #pragma unroll
    for (int c2=0; c2<2; ++c2){
      #pragma unroll
      for (int db=0; db<2; ++db){
        int row = db*32 + q32;
        int cc  = (c2*2 + hi) ^ ((row>>1) & 3);
        bf16x8 vf = *(const bf16x8*)(Vbase + row*64 + cc*16);
        accT[db] = __builtin_amdgcn_mfma_f32_32x32x16_bf16(vf, pa[c2].v, accT[db], 0,0,0);
      }
    }
    __builtin_amdgcn_s_setprio(0);

    __syncthreads();                 // all waves done READING this tile
    if (t+1 < 32) STAGE(t+1);        // overwrite single buffer
    __syncthreads();                 // staged data landed (vmcnt drained)
  }

  // ---- epilogue: write RAW partials ----
  const size_t rowg = (size_t)(b*NQx + q0 + q32);
  const size_t R = (size_t)8192*512;
  unsigned short* Orow = OP + (size_t)ks*R + rowg*Dx + h*64;
  #pragma unroll
  for (int db=0; db<2; ++db){
    #pragma unroll
    for (int a2=0; a2<4; ++a2){
      int d0 = db*32 + a2*8 + hi*4;
      uint2 pk2;
      pk2.x = cvtpk_bf16(accT[db][a2*4+0], accT[db][a2*4+1]);
      pk2.y = cvtpk_bf16(accT[db][a2*4+2], accT[db][a2*4+3]);
      *(uint2*)(Orow + d0) = pk2;
    }
  }
  if (hi == 0){
    float4 mla; mla.x = m_i; mla.y = l_i; mla.z = a_i; mla.w = 0.f;
    MLA[(size_t)ks*65536 + rowg*8 + h] = mla;
  }
}

// ---------------------------------------------------------------------------
// Merge the two k-half partials + attention residual (Qh, vp) + LayerNorm0.
// One block per row (8192). Writes bf16 O0b (MLP input AND residual).
// ---------------------------------------------------------------------------
__global__ __launch_bounds__(256) void mab_merge_ln(
    const unsigned short* __restrict__ OP, const float4* __restrict__ MLA,
    const unsigned short* __restrict__ Qp, const float* __restrict__ vp,
    const float* __restrict__ g, const float* __restrict__ be,
    unsigned short* __restrict__ Yb)
{
  const int row = blockIdx.x;
  const int tid = threadIdx.x;
  const int h = tid >> 5;                     // d = tid*2 -> head = d/64
  const size_t R = (size_t)8192*512;

  float4 A0 = MLA[(size_t)row*8 + h];
  float4 A1 = MLA[65536 + (size_t)row*8 + h];
  float mM  = fmaxf(A0.x, A1.x);
  float al0 = fexp2(A0.x - mM), al1 = fexp2(A1.x - mM);
  float l   = fmaf(al0, A0.y, al1*A1.y);
  float inv = 1.0f / l;
  float aw  = fmaf(al0, A0.z, al1*A1.z) * inv;

  const int d = tid*2;
  ushort2 o0 = *(const ushort2*)(OP + (size_t)row*Dx + d);
  ushort2 o1 = *(const ushort2*)(OP + R + (size_t)row*Dx + d);
  ushort2 qh = *(const ushort2*)(Qp + (size_t)row*Dx + d);
  float2 vv  = *(const float2*)(vp + (d & 63));
  float2 v;
  v.x = fmaf(fmaf(al0, bf2f(o0.x), al1*bf2f(o1.x)), inv, bf2f(qh.x) + aw*vv.x);
  v.y = fmaf(fmaf(al0, bf2f(o0.y), al1*bf2f(o1.y)), inv, bf2f(qh.y) + aw*vv.y);

  // LayerNorm over 512
  float s  = v.x + v.y;
  float sq = fmaf(v.x,v.x, v.y*v.y);
  #pragma unroll
  for (int m=1; m<64; m<<=1){ s += __shfl_xor(s,m); sq += __shfl_xor(sq,m); }
  __shared__ float red[2][4];
  const int wid = tid>>6, lane = tid&63;
  if (lane==0){ red[0][wid]=s; red[1][wid]=sq; }
  __syncthreads();
  s  = red[0][0]+red[0][1]+red[0][2]+red[0][3];
  sq = red[1][0]+red[1][1]+red[1][2]+red[1][3];
  float mean = s*(1.0f/Dx);
  float var  = sq*(1.0f/Dx) - mean*mean;
  float rstd = rsqrtf(var + 1e-5f);
  float2 gg = *(const float2*)(g  + d);
  float2 bb = *(const float2*)(be + d);
  ushort2 ob;
  ob.x = f2bf((v.x-mean)*rstd*gg.x + bb.x);
  ob.y = f2bf((v.y-mean)*rstd*gg.y + bb.y);
  *(ushort2*)(Yb + (size_t)row*Dx + d) = ob;
}

// ---------------------------------------------------------------------------
// Final LayerNorm over 512, bf16 input -> f32 output.
// ---------------------------------------------------------------------------
__global__ __launch_bounds__(256) void mab_ln2b(
    const unsigned short* __restrict__ Xin, const float* __restrict__ g,
    const float* __restrict__ be, float* __restrict__ Yf)
{
  const int row = blockIdx.x;
  const int tid = threadIdx.x;
  ushort2 v2 = *(const ushort2*)(Xin + (size_t)row*Dx + tid*2);
  float vx = bf2f(v2.x), vy = bf2f(v2.y);
  float s  = vx + vy;
  float sq = fmaf(vx,vx, vy*vy);
  #pragma unroll
  for (int m=1; m<64; m<<=1){ s += __shfl_xor(s,m); sq += __shfl_xor(sq,m); }
  __shared__ float red[2][4];
  const int wid = tid>>6, lane = tid&63;
  if (lane==0){ red[0][wid]=s; red[1][wid]=sq; }
  __syncthreads();
  s  = red[0][0]+red[0][1]+red[0][2]+red[0][3];
  sq = red[1][0]+red[1][1]+red[1][2]+red[1][3];
  float mean = s*(1.0f/Dx);
  float var  = sq*(1.0f/Dx) - mean*mean;
  float rstd = rsqrtf(var + 1e-5f);
  float2 gg = *(const float2*)(g  + tid*2);
  float2 bb = *(const float2*)(be + tid*2);
  float2 o;
  o.x = (vx-mean)*rstd*gg.x + bb.x;
  o.y = (vy-mean)*rstd*gg.y + bb.y;
  *(float2*)(Yf + (size_t)row*Dx + tid*2) = o;
}

// ---------------------------------------------------------------------------
extern "C" void kernel_launch(void* const* d_in, const int* in_sizes, int n_in,
                              void* d_out, int out_size, void* d_ws, size_t ws_size,
                              hipStream_t stream)
{
  const float* Q    = (const float*)d_in[0];
  const float* K    = (const float*)d_in[1];
  const float* Kpos = (const float*)d_in[2];
  const float* Wq   = (const float*)d_in[3];
  const float* bq   = (const float*)d_in[4];
  const float* Wk   = (const float*)d_in[5];
  const float* bk   = (const float*)d_in[6];
  const float* Wv   = (const float*)d_in[7];
  const float* bv   = (const float*)d_in[8];
  const float* kp   = (const float*)d_in[9];
  const float* vp   = (const float*)d_in[10];
  const float* W0   = (const float*)d_in[11];
  const float* b0   = (const float*)d_in[12];
  const float* W1   = (const float*)d_in[13];
  const float* b1   = (const float*)d_in[14];
  const float* g0   = (const float*)d_in[15];
  const float* be0  = (const float*)d_in[16];
  const float* g1   = (const float*)d_in[17];
  const float* be1  = (const float*)d_in[18];
  float* out = (float*)d_out;
  char* wsb  = (char*)d_ws;

  const size_t MB = 1024*1024;
  unsigned short* Qp  = (unsigned short*)(wsb);            // 8 MiB bf16
  unsigned short* Kp  = (unsigned short*)(wsb + 8*MB);     // pre-scaled
  unsigned short* Vpt = (unsigned short*)(wsb + 16*MB);    // 8 MiB d-major
  unsigned short* Wt  = (unsigned short*)(wsb + 24*MB);    // 2.5 MiB
  unsigned short* OP  = (unsigned short*)(wsb + 27*MB);    // 16 MiB (2 partial halves)
  float4*         MLA = (float4*)        (wsb + 43*MB);    // 2 MiB
  unsigned short* O0b = (unsigned short*)(wsb + 45*MB);    // 8 MiB post-LN0
  unsigned short* T1  = OP;                                // reuse (OP dead after merge)
  unsigned short* T2b = (unsigned short*)(wsb + 35*MB);    // reuse OP+8MB

  const float kscale = 0.044194173824159216f * 1.4426950408889634f; // log2e/sqrt(512)

  // weight transposes (Wq,Wk,Wv,W0,W1)
  mab_wt<<<dim3(8,8,5), 256, 0, stream>>>(Wq, Wk, Wv, W0, W1, Wt);
  // fused Q/K/V projections; V written transposed to Vpt directly
  mab_gemm_proj<<<dim3(4,64,3), 256, 0, stream>>>(Q, K, Wt, bq, bk, bv, Qp, Vpt, kscale);
  // fused attention v9 (all-heads, k-split x2 across blocks, single-buffer)
  mab_attn9<<<dim3(64,2,4), 512, 0, stream>>>(Qp, Kp, Vpt, Kpos, kp, OP, MLA);
  // merge partials + residual + LN0 -> O0b (bf16)
  mab_merge_ln<<<8192, 256, 0, stream>>>(OP, MLA, Qp, vp, g0, be0, O0b);
  // T1 = relu(O0b @ W0 + b0)  (bf16 out)
  mab_gemm_mlp<<<dim3(8,128), 256, 0, stream>>>(
      O0b, Wt + (size_t)3*512*512, b0, nullptr, T1, 1);
  // T2b = O0b + relu(T1 @ W1 + b1)  (bf16 out)
  mab_gemm_mlp<<<dim3(8,128), 256, 0, stream>>>(
      T1, Wt + (size_t)4*512*512, b1, O0b, T2b, 1);
  // final LN: bf16 in -> f32 out
  mab_ln2b<<<8192, 256, 0, stream>>>(T2b, g1, be1, out);
}